// Round 12
// baseline (519.186 us; speedup 1.0000x reference)
//
#include <hip/hip_runtime.h>
#include <hip/hip_bf16.h>

using bf16 = __hip_bfloat16;
typedef __attribute__((ext_vector_type(8))) short short8;
typedef __attribute__((ext_vector_type(4))) float f32x4;

static __device__ __forceinline__ float b2f(bf16 v) { return __bfloat162float(v); }
static __device__ __forceinline__ bf16  f2b(float v) { return __float2bfloat16(v); }
static __device__ __forceinline__ short f2bs(float x) {
    union { float f; unsigned u; } c; c.f = x;
    unsigned r = (c.u + 0x7FFFu + ((c.u >> 16) & 1u)) >> 16;
    return (short)r;
}
static __device__ __forceinline__ float bs2f(short s) {
    union { unsigned u; float f; } c; c.u = ((unsigned)(unsigned short)s) << 16;
    return c.f;
}
// async global->LDS, 16B per lane; LDS dst = wave-uniform base + lane*16
static __device__ __forceinline__ void gload16(const short* g, short* l) {
    __builtin_amdgcn_global_load_lds(
        (const __attribute__((address_space(1))) void*)g,
        (__attribute__((address_space(3))) void*)l, 16, 0, 0);
}

constexpr int kD   = 512;
constexpr int kT   = 1024;
constexpr int kN   = 4;
constexpr int kH   = 8;
constexpr int kDH  = 64;
constexpr int kFFN = 2048;
constexpr int kROWS = kN * kT;        // 4096
constexpr int kP    = 2 * kT - 1;     // 2047

#define ACT_NONE 0
#define ACT_SILU 1

// ---------------------------------------------------------------- fallback stamp
__global__ __launch_bounds__(256) void stamp_kernel(float* __restrict__ out, int n, float val) {
    int i = blockIdx.x * 256 + threadIdx.x;
    if (i < n) out[i] = (i == 0 ? val : 0.f);
}

// ---------------------------------------------------------------- copy (slow path only)
__global__ __launch_bounds__(256) void cvt_kernel(const float* __restrict__ in,
                                                  float* __restrict__ out, int n4) {
    int i = blockIdx.x * 256 + threadIdx.x;
    if (i < n4) ((f32x4*)out)[i] = ((const f32x4*)in)[i];
}

// ---------------------------------------------------------------- fused weight transpose
struct WtDesc { const float* src; short* dst; int K; int N; int tstart; };
struct WtArgs { WtDesc d[11]; };

__global__ __launch_bounds__(256) void wt_all_kernel(WtArgs a) {
    __shared__ float t[32][33];
    int bid = blockIdx.x;
    int i = 0;
#pragma unroll
    for (int j = 1; j < 11; ++j) if (bid >= a.d[j].tstart) i = j;
    const float* W = a.d[i].src;
    short* Wt = a.d[i].dst;
    int Kd = a.d[i].K, Nd = a.d[i].N;
    int lt = bid - a.d[i].tstart;
    int nx = Nd >> 5;
    int n0 = (lt % nx) * 32, k0 = (lt / nx) * 32;
    int tx = threadIdx.x & 31, ty = threadIdx.x >> 5;
#pragma unroll
    for (int it = 0; it < 4; ++it)
        t[ty + it * 8][tx] = W[(size_t)(k0 + ty + it * 8) * Nd + n0 + tx];
    __syncthreads();
#pragma unroll
    for (int it = 0; it < 4; ++it)
        Wt[(size_t)(n0 + ty + it * 8) * Kd + k0 + tx] = f2bs(t[tx][ty + it * 8]);
}

// ---------------------------------------------------------------- V transpose per (n,h)
__global__ __launch_bounds__(256) void vtrans_kernel(const bf16* __restrict__ V,
                                                     bf16* __restrict__ Vt) {
    __shared__ short ts[64][72];
    int tt = blockIdx.x, h = blockIdx.y, n = blockIdx.z;
    int tid = threadIdx.x;
    int r = tid >> 3, cg = (tid & 7) * 8;
#pragma unroll
    for (int it = 0; it < 2; ++it) {
        int row = it * 32 + r;
        *(short8*)&ts[row][cg] =
            *(const short8*)((const short*)V + ((size_t)n * kT + tt * 64 + row) * 512 + h * 64 + cg);
    }
    __syncthreads();
#pragma unroll
    for (int it = 0; it < 2; ++it) {
        int d = it * 32 + r;
        short8 o;
#pragma unroll
        for (int i = 0; i < 8; ++i) o[i] = ts[cg + i][d];
        *(short8*)((short*)Vt + ((size_t)(n * 8 + h) * 64 + d) * 1024 + tt * 64 + cg) = o;
    }
}

// ---------------------------------------------------------------- depthwise weight prep (fold BN)
__global__ __launch_bounds__(256) void dwt_kernel(const float* __restrict__ dw_w,
                                                  const float* __restrict__ dw_b,
                                                  const float* __restrict__ bn_g,
                                                  const float* __restrict__ bn_b,
                                                  float* __restrict__ wt,
                                                  float* __restrict__ beff) {
    int idx = blockIdx.x * 256 + threadIdx.x;
    if (idx < 31 * kD) {
        int d = idx & 511, k = idx >> 9;
        wt[k * kD + d] = dw_w[d * 31 + k] * bn_g[d];
    }
    if (idx < kD) beff[idx] = dw_b[idx] * bn_g[idx] + bn_b[idx];
}

// ---------------------------------------------------------------- layernorm (fp32 in)
__global__ __launch_bounds__(256) void ln_kernel(const float* __restrict__ xin,
                                                 const float* __restrict__ g,
                                                 const float* __restrict__ b,
                                                 void* __restrict__ outp, int out_f32) {
    int row = blockIdx.x;
    const float* xr = xin + (size_t)row * kD;
    int tid = threadIdx.x;
    float v0 = xr[tid], v1 = xr[tid + 256];
    float s = v0 + v1, sq = v0 * v0 + v1 * v1;
    for (int off = 32; off; off >>= 1) {
        s  += __shfl_down(s, off);
        sq += __shfl_down(sq, off);
    }
    __shared__ float ss[4], ssq[4];
    __shared__ float mean_s, rstd_s;
    int wid = tid >> 6, lane = tid & 63;
    if (lane == 0) { ss[wid] = s; ssq[wid] = sq; }
    __syncthreads();
    if (tid == 0) {
        float S  = ss[0] + ss[1] + ss[2] + ss[3];
        float SQ = ssq[0] + ssq[1] + ssq[2] + ssq[3];
        float m = S / (float)kD;
        float var = SQ / (float)kD - m * m;
        mean_s = m;
        rstd_s = rsqrtf(fmaxf(var, 0.f) + 1e-5f);
    }
    __syncthreads();
    float m = mean_s, rs = rstd_s;
    float o0 = (v0 - m) * rs * g[tid]       + b[tid];
    float o1 = (v1 - m) * rs * g[tid + 256] + b[tid + 256];
    size_t i0 = (size_t)row * kD + tid, i1 = i0 + 256;
    if (out_f32) {
        ((float*)outp)[i0] = o0; ((float*)outp)[i1] = o1;
    } else {
        ((bf16*)outp)[i0] = f2b(o0); ((bf16*)outp)[i1] = f2b(o1);
    }
}

// ---------------------------------------------------------------- MFMA GEMM, 64x64 tile (dbuf async)
__global__ __launch_bounds__(256, 4) void gemm_mfma64(
    const void* __restrict__ A, const short* __restrict__ Bt,
    const float* __restrict__ bias, const float* __restrict__ residual,
    float* __restrict__ outf, bf16* __restrict__ outb,
    int M, int N, int K, int act, float scale, int a_f32) {
    __shared__ short As[2][4096];
    __shared__ short Bs[2][4096];
    int tid = threadIdx.x;
    int m0 = blockIdx.y * 64, n0 = blockIdx.x * 64;
    int wid = tid >> 6, lane = tid & 63;
    int wm = (wid >> 1) * 32, wn = (wid & 1) * 32;
    int q = lane >> 4, c16 = lane & 15;

    f32x4 zero4 = {0.f, 0.f, 0.f, 0.f};
    f32x4 acc[2][2] = {{zero4, zero4}, {zero4, zero4}};

    int arow = lane >> 3;
    int aseg = (lane & 7) ^ arow;

    auto issueA = [&](int buf, int k0) {
        if (!a_f32) {
#pragma unroll
            for (int it = 0; it < 2; ++it) {
                int rbase = (wid * 2 + it) * 8;
                gload16((const short*)A + (size_t)(m0 + rbase + arow) * K + k0 + aseg * 8,
                        &As[buf][(wid * 2 + it) * 512]);
            }
        } else {
            int srow = tid >> 3, sseg = tid & 7;
#pragma unroll
            for (int it = 0; it < 2; ++it) {
                int row = it * 32 + srow;
                int rr = m0 + row;
                short8 v = {0, 0, 0, 0, 0, 0, 0, 0};
                if (rr < M) {
                    const float* ap = (const float*)A + (size_t)rr * K + k0 + sseg * 8;
                    f32x4 x0 = *(const f32x4*)ap;
                    f32x4 x1 = *(const f32x4*)(ap + 4);
                    v[0] = f2bs(x0[0]); v[1] = f2bs(x0[1]); v[2] = f2bs(x0[2]); v[3] = f2bs(x0[3]);
                    v[4] = f2bs(x1[0]); v[5] = f2bs(x1[1]); v[6] = f2bs(x1[2]); v[7] = f2bs(x1[3]);
                }
                *(short8*)&As[buf][(row * 8 + (sseg ^ (row & 7))) * 8] = v;
            }
        }
    };
    auto issueB = [&](int buf, int k0) {
#pragma unroll
        for (int it = 0; it < 2; ++it) {
            int rbase = (wid * 2 + it) * 8;
            gload16(Bt + (size_t)(n0 + rbase + arow) * K + k0 + aseg * 8,
                    &Bs[buf][(wid * 2 + it) * 512]);
        }
    };

    issueA(0, 0);
    issueB(0, 0);
    int cur = 0;
    for (int k0 = 0; k0 < K; k0 += 64) {
        __syncthreads();
        if (k0 + 64 < K) {
            issueA(cur ^ 1, k0 + 64);
            issueB(cur ^ 1, k0 + 64);
        }
#pragma unroll
        for (int ks = 0; ks < 2; ++ks) {
            int p = c16 & 7;
            short8 af[2], bfr[2];
#pragma unroll
            for (int mt = 0; mt < 2; ++mt) {
                int row = wm + mt * 16 + c16;
                af[mt] = *(const short8*)&As[cur][(row * 8 + ((ks * 4 + q) ^ p)) * 8];
            }
#pragma unroll
            for (int nt = 0; nt < 2; ++nt) {
                int row = wn + nt * 16 + c16;
                bfr[nt] = *(const short8*)&Bs[cur][(row * 8 + ((ks * 4 + q) ^ p)) * 8];
            }
#pragma unroll
            for (int mt = 0; mt < 2; ++mt)
#pragma unroll
                for (int nt = 0; nt < 2; ++nt)
                    acc[mt][nt] = __builtin_amdgcn_mfma_f32_16x16x32_bf16(
                        af[mt], bfr[nt], acc[mt][nt], 0, 0, 0);
        }
        cur ^= 1;
    }
#pragma unroll
    for (int mt = 0; mt < 2; ++mt) {
#pragma unroll
        for (int reg = 0; reg < 4; ++reg) {
            int r = m0 + wm + mt * 16 + q * 4 + reg;
            if (r >= M) continue;
#pragma unroll
            for (int nt = 0; nt < 2; ++nt) {
                int c = n0 + wn + nt * 16 + c16;
                float h = acc[mt][nt][reg];
                if (bias) h += bias[c];
                if (act == ACT_SILU) h = h / (1.f + __expf(-h));
                h *= scale;
                size_t idx = (size_t)r * N + c;
                if (residual) h += residual[idx];
                if (outf) outf[idx] = h;
                if (outb) outb[idx] = f2b(h);
            }
        }
    }
}

// ---------------------------------------------------------------- MFMA GEMM, 128x64 tile (dbuf async)
// For large-M, large-N GEMMs (FF up-proj): 16 MFMAs per wave per K-iter,
// 42.7 FLOP per staged byte (vs 32 for 64x64). 48 KB LDS -> 3 blocks/CU.
__global__ __launch_bounds__(256, 3) void gemm_mfma128(
    const bf16* __restrict__ A, const short* __restrict__ Bt,
    const float* __restrict__ bias, const float* __restrict__ residual,
    float* __restrict__ outf, bf16* __restrict__ outb,
    int M, int N, int K, int act, float scale) {
    __shared__ short As[2][8192];   // 128 rows x 64 cols, swizzled
    __shared__ short Bs[2][4096];   // 64 rows x 64 cols
    int tid = threadIdx.x;
    int m0 = blockIdx.y * 128, n0 = blockIdx.x * 64;
    int wid = tid >> 6, lane = tid & 63;
    int wm = (wid >> 1) * 64, wn = (wid & 1) * 32;
    int q = lane >> 4, c16 = lane & 15;

    f32x4 zero4 = {0.f, 0.f, 0.f, 0.f};
    f32x4 acc[4][2];
#pragma unroll
    for (int i = 0; i < 4; ++i) { acc[i][0] = zero4; acc[i][1] = zero4; }

    int arow = lane >> 3;
    int aseg = (lane & 7) ^ arow;

    auto issue = [&](int buf, int k0) {
#pragma unroll
        for (int it = 0; it < 4; ++it) {          // A: 16 instr-groups of 8 rows
            int gidx = wid * 4 + it;
            gload16((const short*)A + (size_t)(m0 + gidx * 8 + arow) * K + k0 + aseg * 8,
                    &As[buf][gidx * 512]);
        }
#pragma unroll
        for (int it = 0; it < 2; ++it) {          // B: 8 instr-groups
            int gidx = wid * 2 + it;
            gload16(Bt + (size_t)(n0 + gidx * 8 + arow) * K + k0 + aseg * 8,
                    &Bs[buf][gidx * 512]);
        }
    };

    issue(0, 0);
    int cur = 0;
    for (int k0 = 0; k0 < K; k0 += 64) {
        __syncthreads();
        if (k0 + 64 < K) issue(cur ^ 1, k0 + 64);
#pragma unroll
        for (int ks = 0; ks < 2; ++ks) {
            int p = c16 & 7;
            short8 af[4], bfr[2];
#pragma unroll
            for (int mt = 0; mt < 4; ++mt) {
                int row = wm + mt * 16 + c16;
                af[mt] = *(const short8*)&As[cur][(row * 8 + ((ks * 4 + q) ^ p)) * 8];
            }
#pragma unroll
            for (int nt = 0; nt < 2; ++nt) {
                int row = wn + nt * 16 + c16;
                bfr[nt] = *(const short8*)&Bs[cur][(row * 8 + ((ks * 4 + q) ^ p)) * 8];
            }
#pragma unroll
            for (int mt = 0; mt < 4; ++mt)
#pragma unroll
                for (int nt = 0; nt < 2; ++nt)
                    acc[mt][nt] = __builtin_amdgcn_mfma_f32_16x16x32_bf16(
                        af[mt], bfr[nt], acc[mt][nt], 0, 0, 0);
        }
        cur ^= 1;
    }
#pragma unroll
    for (int mt = 0; mt < 4; ++mt) {
#pragma unroll
        for (int reg = 0; reg < 4; ++reg) {
            int r = m0 + wm + mt * 16 + q * 4 + reg;
#pragma unroll
            for (int nt = 0; nt < 2; ++nt) {
                int c = n0 + wn + nt * 16 + c16;
                float h = acc[mt][nt][reg];
                if (bias) h += bias[c];
                if (act == ACT_SILU) h = h / (1.f + __expf(-h));
                h *= scale;
                size_t idx = (size_t)r * N + c;
                if (residual) h += residual[idx];
                if (outf) outf[idx] = h;
                if (outb) outb[idx] = f2b(h);
            }
        }
    }
}

// ---------------------------------------------------------------- fused QKV GEMM (dbuf async)
__global__ __launch_bounds__(256, 4) void gemm_qkv(
    const bf16* __restrict__ A, const short* __restrict__ Bt,
    const float* __restrict__ bq, const float* __restrict__ bk,
    const float* __restrict__ bv,
    bf16* __restrict__ Qb, bf16* __restrict__ Kb, bf16* __restrict__ Vb) {
    const int K = kD;
    __shared__ short As[2][4096];
    __shared__ short Bs[2][4096];
    int tid = threadIdx.x;
    int m0 = blockIdx.y * 64, n0 = blockIdx.x * 64;
    int seg = blockIdx.x >> 3;
    const float* bias = seg == 0 ? bq : (seg == 1 ? bk : bv);
    bf16* outb = seg == 0 ? Qb : (seg == 1 ? Kb : Vb);
    int ns0 = n0 & 511;
    int wid = tid >> 6, lane = tid & 63;
    int wm = (wid >> 1) * 32, wn = (wid & 1) * 32;
    int q = lane >> 4, c16 = lane & 15;

    f32x4 zero4 = {0.f, 0.f, 0.f, 0.f};
    f32x4 acc[2][2] = {{zero4, zero4}, {zero4, zero4}};
    int arow = lane >> 3;
    int aseg = (lane & 7) ^ arow;

    auto issue = [&](int buf, int k0) {
#pragma unroll
        for (int it = 0; it < 2; ++it) {
            int rbase = (wid * 2 + it) * 8;
            gload16((const short*)A + (size_t)(m0 + rbase + arow) * K + k0 + aseg * 8,
                    &As[buf][(wid * 2 + it) * 512]);
            gload16(Bt + (size_t)(n0 + rbase + arow) * K + k0 + aseg * 8,
                    &Bs[buf][(wid * 2 + it) * 512]);
        }
    };

    issue(0, 0);
    int cur = 0;
    for (int k0 = 0; k0 < K; k0 += 64) {
        __syncthreads();
        if (k0 + 64 < K) issue(cur ^ 1, k0 + 64);
#pragma unroll
        for (int ks = 0; ks < 2; ++ks) {
            int p = c16 & 7;
            short8 af[2], bfr[2];
#pragma unroll
            for (int mt = 0; mt < 2; ++mt) {
                int row = wm + mt * 16 + c16;
                af[mt] = *(const short8*)&As[cur][(row * 8 + ((ks * 4 + q) ^ p)) * 8];
            }
#pragma unroll
            for (int nt = 0; nt < 2; ++nt) {
                int row = wn + nt * 16 + c16;
                bfr[nt] = *(const short8*)&Bs[cur][(row * 8 + ((ks * 4 + q) ^ p)) * 8];
            }
#pragma unroll
            for (int mt = 0; mt < 2; ++mt)
#pragma unroll
                for (int nt = 0; nt < 2; ++nt)
                    acc[mt][nt] = __builtin_amdgcn_mfma_f32_16x16x32_bf16(
                        af[mt], bfr[nt], acc[mt][nt], 0, 0, 0);
        }
        cur ^= 1;
    }
#pragma unroll
    for (int mt = 0; mt < 2; ++mt)
#pragma unroll
        for (int reg = 0; reg < 4; ++reg) {
            int r = m0 + wm + mt * 16 + q * 4 + reg;
#pragma unroll
            for (int nt = 0; nt < 2; ++nt) {
                int c = ns0 + wn + nt * 16 + c16;
                outb[(size_t)r * 512 + c] = f2b(acc[mt][nt][reg] + bias[c]);
            }
        }
}

// ---------------------------------------------------------------- scalar GEMM (slow fallback)
__global__ __launch_bounds__(256) void gemm_scalar(
    const void* __restrict__ A, const float* __restrict__ W,
    const float* __restrict__ bias, const float* __restrict__ residual,
    float* __restrict__ outf, bf16* __restrict__ outb,
    int M, int N, int K, int act, float scale, int a_f32) {
    __shared__ float As[16][65];
    __shared__ float Bs[16][65];
    int tid = threadIdx.x;
    int tx = tid & 15, ty = tid >> 4;
    int row0 = blockIdx.y * 64, col0 = blockIdx.x * 64;
    float acc[4][4] = {};
    for (int k0 = 0; k0 < K; k0 += 16) {
        for (int i = tid; i < 64 * 16; i += 256) {
            int r = i >> 4, c = i & 15;
            int rr = row0 + r;
            float v = 0.f;
            if (rr < M) {
                size_t idx = (size_t)rr * K + k0 + c;
                v = a_f32 ? ((const float*)A)[idx] : b2f(((const bf16*)A)[idx]);
            }
            As[c][r] = v;
        }
        for (int i = tid; i < 16 * 64; i += 256) {
            int r = i >> 6, c = i & 63;
            Bs[r][c] = W[(size_t)(k0 + r) * N + col0 + c];
        }
        __syncthreads();
#pragma unroll
        for (int kk = 0; kk < 16; ++kk) {
            float a[4], b[4];
#pragma unroll
            for (int i = 0; i < 4; ++i) a[i] = As[kk][ty * 4 + i];
#pragma unroll
            for (int j = 0; j < 4; ++j) b[j] = Bs[kk][tx * 4 + j];
#pragma unroll
            for (int i = 0; i < 4; ++i)
#pragma unroll
                for (int j = 0; j < 4; ++j) acc[i][j] += a[i] * b[j];
        }
        __syncthreads();
    }
#pragma unroll
    for (int i = 0; i < 4; ++i) {
        int r = row0 + ty * 4 + i;
        if (r >= M) continue;
#pragma unroll
        for (int j = 0; j < 4; ++j) {
            int c = col0 + tx * 4 + j;
            float h = acc[i][j];
            if (bias) h += bias[c];
            if (act == ACT_SILU) h = h / (1.f + __expf(-h));
            h *= scale;
            size_t idx = (size_t)r * N + c;
            if (residual) h += residual[idx];
            if (outf) outf[idx] = h;
            if (outb) outb[idx] = f2b(h);
        }
    }
}

// ---------------------------------------------------------------- MFMA RPE attention
// B-trim: wave w only gathers j in [wm, wm+78] -> compute only 5 jt-groups at
// row offset wm + jt*16 (values identical to full 8-group version).
__global__ __launch_bounds__(256, 2) void attn_mfma(
    const bf16* __restrict__ Qg, const bf16* __restrict__ Kg,
    const bf16* __restrict__ Vtg, const bf16* __restrict__ Rg,
    const float* __restrict__ uu, const float* __restrict__ vvp,
    bf16* __restrict__ outb) {
    __shared__ short Qu[64][72];
    __shared__ short Qv[64][72];
    __shared__ short Ks[64][72];
    __shared__ short Vt[64][72];
    __shared__ short Rw[128][72];
    __shared__ short Bp[64][136];

    int tid = threadIdx.x;
    int qb = blockIdx.x, h = blockIdx.y, n = blockIdx.z;
    int t0 = qb * 64;
    size_t baseq = ((size_t)n * kT) * 512 + (size_t)h * kDH;
    size_t basev = ((size_t)(n * 8 + h) * 64) * 1024;
    size_t baseo = ((size_t)n * kT) * kD + (size_t)h * kDH;

    int wid = tid >> 6, lane = tid & 63;
    int q = lane >> 4, c16 = lane & 15;
    int wm = wid * 16;
    int trow = wm + q * 4;

    {
        int t = tid >> 2, dg = (tid & 3) * 16;
        const short* qp = (const short*)Qg + baseq + (size_t)(t0 + t) * 512 + dg;
        short8 q0 = *(const short8*)qp;
        short8 q1 = *(const short8*)(qp + 8);
#pragma unroll
        for (int i = 0; i < 8; ++i) {
            float qv = bs2f(q0[i]);
            Qu[t][dg + i] = f2bs(qv + uu[h * 64 + dg + i]);
            Qv[t][dg + i] = f2bs(qv + vvp[h * 64 + dg + i]);
        }
#pragma unroll
        for (int i = 0; i < 8; ++i) {
            float qv = bs2f(q1[i]);
            Qu[t][dg + 8 + i] = f2bs(qv + uu[h * 64 + dg + 8 + i]);
            Qv[t][dg + 8 + i] = f2bs(qv + vvp[h * 64 + dg + 8 + i]);
        }
    }

    f32x4 zero4 = {0.f, 0.f, 0.f, 0.f};
    f32x4 acc_o[4] = {zero4, zero4, zero4, zero4};
    float m_i[4] = {-1e30f, -1e30f, -1e30f, -1e30f};
    float l_i[4] = {0.f, 0.f, 0.f, 0.f};

    for (int kt = 0; kt < 16; ++kt) {
        int s0 = kt * 64;
        __syncthreads();
        {
            int s = tid >> 2, dg = (tid & 3) * 16;
            const short* kp = (const short*)Kg + baseq + (size_t)(s0 + s) * 512 + dg;
            *(short8*)&Ks[s][dg]     = *(const short8*)kp;
            *(short8*)&Ks[s][dg + 8] = *(const short8*)(kp + 8);
            const short* vp = (const short*)Vtg + basev + (size_t)s * 1024 + s0 + dg;
            *(short8*)&Vt[s][dg]     = *(const short8*)vp;
            *(short8*)&Vt[s][dg + 8] = *(const short8*)(vp + 8);
        }
        int p_base = t0 - s0 + 960;
#pragma unroll
        for (int it = 0; it < 4; ++it) {
            int i = tid + it * 256;
            int j = i >> 3, dg2 = (i & 7) * 8;
            int p = p_base + j;
            p = p < 0 ? 0 : (p > 2046 ? 2046 : p);
            *(short8*)&Rw[j][dg2] =
                *(const short8*)((const short*)Rg + (size_t)p * kD + h * kDH + dg2);
        }
        __syncthreads();

        f32x4 acc_s[4] = {zero4, zero4, zero4, zero4};
        f32x4 acc_b[5] = {zero4, zero4, zero4, zero4, zero4};
#pragma unroll
        for (int ks = 0; ks < 2; ++ks) {
            short8 au = *(const short8*)&Qu[wm + c16][ks * 32 + q * 8];
            short8 av = *(const short8*)&Qv[wm + c16][ks * 32 + q * 8];
#pragma unroll
            for (int nt = 0; nt < 4; ++nt) {
                short8 bk_ = *(const short8*)&Ks[nt * 16 + c16][ks * 32 + q * 8];
                acc_s[nt] = __builtin_amdgcn_mfma_f32_16x16x32_bf16(au, bk_, acc_s[nt], 0, 0, 0);
            }
#pragma unroll
            for (int jt = 0; jt < 5; ++jt) {
                short8 br_ = *(const short8*)&Rw[wm + jt * 16 + c16][ks * 32 + q * 8];
                acc_b[jt] = __builtin_amdgcn_mfma_f32_16x16x32_bf16(av, br_, acc_b[jt], 0, 0, 0);
            }
        }
#pragma unroll
        for (int jt = 0; jt < 5; ++jt)
#pragma unroll
            for (int reg = 0; reg < 4; ++reg)
                Bp[trow + reg][wm + jt * 16 + c16] = f2bs(acc_b[jt][reg]);

        float pmat[4][4];
        float alpha[4];
#pragma unroll
        for (int reg = 0; reg < 4; ++reg) {
            int t = trow + reg;
            float mrow = -1e30f;
#pragma unroll
            for (int nt = 0; nt < 4; ++nt) {
                int s = nt * 16 + c16;
                int j = t - s + 63;
                float sv = (acc_s[nt][reg] + bs2f(Bp[t][j])) * 0.125f;
                pmat[nt][reg] = sv;
                mrow = fmaxf(mrow, sv);
            }
            mrow = fmaxf(mrow, __shfl_xor(mrow, 1));
            mrow = fmaxf(mrow, __shfl_xor(mrow, 2));
            mrow = fmaxf(mrow, __shfl_xor(mrow, 4));
            mrow = fmaxf(mrow, __shfl_xor(mrow, 8));
            float m_new = fmaxf(m_i[reg], mrow);
            alpha[reg] = __expf(m_i[reg] - m_new);
            float ps = 0.f;
#pragma unroll
            for (int nt = 0; nt < 4; ++nt) {
                float pe = __expf(pmat[nt][reg] - m_new);
                pmat[nt][reg] = pe;
                ps += pe;
            }
            ps += __shfl_xor(ps, 1);
            ps += __shfl_xor(ps, 2);
            ps += __shfl_xor(ps, 4);
            ps += __shfl_xor(ps, 8);
            l_i[reg] = l_i[reg] * alpha[reg] + ps;
            m_i[reg] = m_new;
        }
#pragma unroll
        for (int nt = 0; nt < 4; ++nt)
#pragma unroll
            for (int reg = 0; reg < 4; ++reg)
                Bp[trow + reg][nt * 16 + c16] = f2bs(pmat[nt][reg]);
#pragma unroll
        for (int dt = 0; dt < 4; ++dt)
#pragma unroll
            for (int reg = 0; reg < 4; ++reg)
                acc_o[dt][reg] *= alpha[reg];
#pragma unroll
        for (int ks = 0; ks < 2; ++ks) {
            short8 ap = *(const short8*)&Bp[wm + c16][ks * 32 + q * 8];
#pragma unroll
            for (int dt = 0; dt < 4; ++dt) {
                short8 bv_ = *(const short8*)&Vt[dt * 16 + c16][ks * 32 + q * 8];
                acc_o[dt] = __builtin_amdgcn_mfma_f32_16x16x32_bf16(ap, bv_, acc_o[dt], 0, 0, 0);
            }
        }
    }
#pragma unroll
    for (int reg = 0; reg < 4; ++reg) {
        float inv = 1.f / l_i[reg];
        int t = trow + reg;
#pragma unroll
        for (int dt = 0; dt < 4; ++dt)
            outb[baseo + (size_t)(t0 + t) * kD + dt * 16 + c16] = f2b(acc_o[dt][reg] * inv);
    }
}

// ---------------------------------------------------------------- scalar attention (slow path)
__global__ __launch_bounds__(256) void attn_kernel(
    const bf16* __restrict__ Qg, const bf16* __restrict__ Kg,
    const bf16* __restrict__ Vg, const bf16* __restrict__ Rg,
    const float* __restrict__ uu, const float* __restrict__ vvp,
    bf16* __restrict__ outb) {
    __shared__ float Qs[64][65];
    __shared__ bf16 Ps[64][66];
    __shared__ bf16 Ks[64][66];
    __shared__ bf16 Vs[64][66];
    __shared__ bf16 Rs[127][66];
    __shared__ float uf[64], vf[64];
    __shared__ float uK[64], vR[127];

    int tid = threadIdx.x;
    int qb = blockIdx.x, h = blockIdx.y, n = blockIdx.z;
    int t0 = qb * 64;
    size_t base = ((size_t)n * kT) * kD + (size_t)h * kDH;

    if (tid < 64) {
        uf[tid] = uu[h * 64 + tid];
        vf[tid] = vvp[h * 64 + tid];
    }
    for (int i = tid; i < 64 * 64; i += 256) {
        int r = i >> 6, d = i & 63;
        Qs[r][d] = b2f(Qg[base + (size_t)(t0 + r) * kD + d]);
    }
    int r = tid >> 2, seg = tid & 3;
    float m_i = -1e30f, l_i = 0.f;
    float Oa[16];
#pragma unroll
    for (int i = 0; i < 16; ++i) Oa[i] = 0.f;

    for (int kt = 0; kt < 16; ++kt) {
        int s0 = kt * 64;
        __syncthreads();
        for (int i = tid; i < 64 * 64; i += 256) {
            int s = i >> 6, d = i & 63;
            Ks[s][d] = Kg[base + (size_t)(s0 + s) * kD + d];
            Vs[s][d] = Vg[base + (size_t)(s0 + s) * kD + d];
        }
        int p_base = t0 - s0 + 960;
        for (int i = tid; i < 127 * 64; i += 256) {
            int j = i >> 6, d = i & 63;
            int p = p_base + j;
            p = p < 0 ? 0 : (p > 2046 ? 2046 : p);
            Rs[j][d] = Rg[(size_t)p * kD + h * kDH + d];
        }
        __syncthreads();
        if (tid < 64) {
            float s_ = 0.f;
            for (int d = 0; d < 64; ++d) s_ += uf[d] * b2f(Ks[tid][d]);
            uK[tid] = s_;
        } else if (tid < 64 + 127) {
            int j = tid - 64;
            float s_ = 0.f;
            for (int d = 0; d < 64; ++d) s_ += vf[d] * b2f(Rs[j][d]);
            vR[j] = s_;
        }
        __syncthreads();
        float sv[16];
        float smax = -1e30f;
#pragma unroll
        for (int jj = 0; jj < 16; ++jj) {
            int s = seg * 16 + jj;
            int j = r - s + 63;
            float acc = 0.f;
            for (int d = 0; d < 64; ++d)
                acc += Qs[r][d] * (b2f(Ks[s][d]) + b2f(Rs[j][d]));
            acc = (acc + uK[s] + vR[j]) * 0.125f;
            sv[jj] = acc;
            smax = fmaxf(smax, acc);
        }
        smax = fmaxf(smax, __shfl_xor(smax, 1));
        smax = fmaxf(smax, __shfl_xor(smax, 2));
        float m_new = fmaxf(m_i, smax);
        float alpha = __expf(m_i - m_new);
        float psum = 0.f;
#pragma unroll
        for (int jj = 0; jj < 16; ++jj) {
            float p = __expf(sv[jj] - m_new);
            Ps[r][seg * 16 + jj] = f2b(p);
            psum += p;
        }
        psum += __shfl_xor(psum, 1);
        psum += __shfl_xor(psum, 2);
        l_i = l_i * alpha + psum;
        m_i = m_new;
#pragma unroll
        for (int i = 0; i < 16; ++i) Oa[i] *= alpha;
        __syncthreads();
        for (int s = 0; s < 64; ++s) {
            float p = b2f(Ps[r][s]);
#pragma unroll
            for (int dd = 0; dd < 16; ++dd)
                Oa[dd] += p * b2f(Vs[s][seg * 16 + dd]);
        }
    }
    float inv = 1.f / l_i;
#pragma unroll
    for (int dd = 0; dd < 16; ++dd)
        outb[base + (size_t)(t0 + r) * kD + seg * 16 + dd] = f2b(Oa[dd] * inv);
}

// ---------------------------------------------------------------- GLU (slow path)
__global__ __launch_bounds__(256) void glu_kernel_v(const bf16* __restrict__ c,
                                                    bf16* __restrict__ out) {
    int i8 = (blockIdx.x * 256 + threadIdx.x) * 8;
    int row = i8 >> 9, d = i8 & 511;
    const short* cp = (const short*)c + (size_t)row * 1024;
    short8 a8 = *(const short8*)(cp + d);
    short8 g8 = *(const short8*)(cp + 512 + d);
    short8 o;
#pragma unroll
    for (int i = 0; i < 8; ++i) {
        float a = bs2f(a8[i]), g = bs2f(g8[i]);
        o[i] = f2bs(a / (1.f + __expf(-g)));
    }
    *(short8*)((short*)out + i8) = o;
}

// ---------------------------------------------------------------- fused GLU + depthwise conv + BN + SiLU
__global__ __launch_bounds__(256) void gluconv_kernel(
    const bf16* __restrict__ cbuf, const float* __restrict__ wt,
    const float* __restrict__ beff, bf16* __restrict__ outb) {
    __shared__ short gsm[94][72];
    __shared__ float wsm[31][64];
    __shared__ float bsm[64];
    int tid = threadIdx.x;
    int dg0 = blockIdx.x * 64;
    int t0  = blockIdx.y * 64;
    int n   = blockIdx.z;

#pragma unroll
    for (int it = 0; it < 3; ++it) {
        int idx = tid + it * 256;
        if (idx < 94 * 8) {
            int row = idx >> 3, cg = (idx & 7) * 8;
            int t = t0 - 15 + row;
            short8 o = {0, 0, 0, 0, 0, 0, 0, 0};
            if ((unsigned)t < (unsigned)kT) {
                const short* cp = (const short*)cbuf + ((size_t)n * kT + t) * 1024 + dg0 + cg;
                short8 a8 = *(const short8*)cp;
                short8 g8 = *(const short8*)(cp + 512);
#pragma unroll
                for (int i = 0; i < 8; ++i)
                    o[i] = f2bs(bs2f(a8[i]) / (1.f + __expf(-bs2f(g8[i]))));
            }
            *(short8*)&gsm[row][cg] = o;
        }
    }
#pragma unroll
    for (int it = 0; it < 8; ++it) {
        int i = tid + it * 256;
        if (i < 31 * 64) wsm[i >> 6][i & 63] = wt[(i >> 6) * kD + dg0 + (i & 63)];
    }
    if (tid < 64) bsm[tid] = beff[dg0 + tid];
    __syncthreads();

    int tl = tid >> 2, dgl = (tid & 3) * 16;
    float acc[16] = {};
#pragma unroll
    for (int k = 0; k < 31; ++k) {
        short8 g0 = *(const short8*)&gsm[tl + k][dgl];
        short8 g1 = *(const short8*)&gsm[tl + k][dgl + 8];
#pragma unroll
        for (int i = 0; i < 8; ++i) {
            acc[i]     += bs2f(g0[i]) * wsm[k][dgl + i];
            acc[8 + i] += bs2f(g1[i]) * wsm[k][dgl + 8 + i];
        }
    }
    short8 o0, o1;
#pragma unroll
    for (int i = 0; i < 8; ++i) {
        float h = acc[i] + bsm[dgl + i];
        o0[i] = f2bs(h / (1.f + __expf(-h)));
        h = acc[8 + i] + bsm[dgl + 8 + i];
        o1[i] = f2bs(h / (1.f + __expf(-h)));
    }
    short* op = (short*)outb + ((size_t)n * kT + t0 + tl) * kD + dg0 + dgl;
    *(short8*)op = o0;
    *(short8*)(op + 8) = o1;
}

// ---------------------------------------------------------------- scalar conv (slow path)
__global__ __launch_bounds__(256) void conv_kernel(
    const bf16* __restrict__ glu, const float* __restrict__ dw_w,
    const float* __restrict__ dw_b, const float* __restrict__ bn_g,
    const float* __restrict__ bn_b, bf16* __restrict__ outb) {
    int idx = blockIdx.x * 256 + threadIdx.x;
    int d = idx & 511;
    int t = (idx >> 9) & 1023;
    int n = idx >> 19;
    const bf16* gp = glu + ((size_t)n * kT) * kD + d;
    float acc = 0.f;
#pragma unroll
    for (int k = 0; k < 31; ++k) {
        int tt = t + k - 15;
        if ((unsigned)tt < (unsigned)kT)
            acc += b2f(gp[(size_t)tt * kD]) * dw_w[d * 31 + k];
    }
    acc += dw_b[d];
    acc = acc * bn_g[d] + bn_b[d];
    acc = acc / (1.f + __expf(-acc));
    outb[idx] = f2b(acc);
}

// ================================================================ launch
extern "C" void kernel_launch(void* const* d_in, const int* in_sizes, int n_in,
                              void* d_out, int out_size, void* d_ws, size_t ws_size,
                              hipStream_t stream) {
    const float* x      = (const float*)d_in[0];
    const float* rel_pe = (const float*)d_in[1];
    const float* ln1_g  = (const float*)d_in[2];
    const float* ln1_b  = (const float*)d_in[3];
    const float* ff1_w1 = (const float*)d_in[4];
    const float* ff1_b1 = (const float*)d_in[5];
    const float* ff1_w2 = (const float*)d_in[6];
    const float* ff1_b2 = (const float*)d_in[7];
    const float* an_g   = (const float*)d_in[8];
    const float* an_b   = (const float*)d_in[9];
    const float* wq = (const float*)d_in[10]; const float* bq = (const float*)d_in[11];
    const float* wk = (const float*)d_in[12]; const float* bk = (const float*)d_in[13];
    const float* wv = (const float*)d_in[14]; const float* bv = (const float*)d_in[15];
    const float* wo = (const float*)d_in[16]; const float* bo = (const float*)d_in[17];
    const float* pos_w = (const float*)d_in[18];
    const float* uu = (const float*)d_in[19]; const float* vvp = (const float*)d_in[20];
    const float* cn_g = (const float*)d_in[21]; const float* cn_b = (const float*)d_in[22];
    const float* pe_w = (const float*)d_in[23]; const float* pe_b = (const float*)d_in[24];
    const float* dw_w = (const float*)d_in[25]; const float* dw_b = (const float*)d_in[26];
    const float* bn_g = (const float*)d_in[27]; const float* bn_b = (const float*)d_in[28];
    const float* pc_w = (const float*)d_in[29]; const float* pc_b = (const float*)d_in[30];
    const float* ln2_g = (const float*)d_in[31]; const float* ln2_b = (const float*)d_in[32];
    const float* ff2_w1 = (const float*)d_in[33]; const float* ff2_b1 = (const float*)d_in[34];
    const float* ff2_w2 = (const float*)d_in[35]; const float* ff2_b2 = (const float*)d_in[36];
    const float* fn_g = (const float*)d_in[37]; const float* fn_b = (const float*)d_in[38];
    (void)n_in; (void)in_sizes;

    const int total = kROWS * kD;
    dim3 blk(256);
    const size_t MB = 1ull << 20;
    char* w = (char*)d_ws;

    if (ws_size >= 30 * MB) {
        // ================= FAST PATH (MFMA) =================
        float* xf      = (float*)(w);
        short* ff1_w1t = (short*)(w + 8 * MB);
        short* ff1_w2t = (short*)(w + 10 * MB);
        short* wqt     = (short*)(w + 12 * MB);
        short* wkt     = (short*)(w + 12 * MB + 512 * 1024);
        short* wvt     = (short*)(w + 13 * MB);
        short* wot     = (short*)(w + 13 * MB + 512 * 1024);
        short* poswt   = (short*)(w + 14 * MB);
        short* pewt    = (short*)(w + 14 * MB + 512 * 1024);
        short* pcwt    = (short*)(w + 15 * MB + 512 * 1024);
        short* ff2_w1t = (short*)(w + 16 * MB);
        short* ff2_w2t = (short*)(w + 18 * MB);
        char*  dyn     = w + 20 * MB;
        bf16* hchunk = (bf16*)dyn;
        bf16* Qb     = (bf16*)dyn;
        bf16* Kb     = (bf16*)(dyn + 4 * MB);
        bf16* Rb     = (bf16*)(dyn + 8 * MB);   // attention phase only
        bf16* cbuf   = (bf16*)dyn;
        float* dwt   = (float*)(dyn + 8 * MB);  // conv phase ONLY (aliases Rb!)
        float* beff  = (float*)(dyn + 8 * MB + 256 * 1024);
        bf16* nb     = (bf16*)d_out;                               // lo 4 MB
        bf16* Vtg    = (bf16*)d_out;                               // lo 4 MB (after qkv; nb dead)
        bf16* convb  = (bf16*)d_out;
        bf16* Vb     = (bf16*)d_out + (size_t)kROWS * kD;          // hi 4 MB
        bf16* attnb  = Vb;                                         // hi 4 MB (after vtrans)

        // ---- all weight transposes in ONE launch
        WtArgs wa;
        const float* srcs[11] = {ff1_w1, ff1_w2, wq, wk, wv, wo, pos_w, pe_w, pc_w, ff2_w1, ff2_w2};
        short* dsts[11] = {ff1_w1t, ff1_w2t, wqt, wkt, wvt, wot, poswt, pewt, pcwt, ff2_w1t, ff2_w2t};
        int Ks_[11] = {512, 2048, 512, 512, 512, 512, 512, 512, 512, 512, 2048};
        int Ns_[11] = {2048, 512, 512, 512, 512, 512, 512, 1024, 512, 2048, 512};
        int cum = 0;
        for (int i = 0; i < 11; ++i) {
            wa.d[i].src = srcs[i]; wa.d[i].dst = dsts[i];
            wa.d[i].K = Ks_[i]; wa.d[i].N = Ns_[i]; wa.d[i].tstart = cum;
            cum += (Ns_[i] / 32) * (Ks_[i] / 32);
        }
        wt_all_kernel<<<cum, blk, 0, stream>>>(wa);

        // ---- macaron FF1 (ln reads x; down-proj residual = x, writes xf)
        ln_kernel<<<kROWS, blk, 0, stream>>>(x, ln1_g, ln1_b, nb, 0);
        for (int c = 0; c < 2; ++c) {
            size_t off = (size_t)c * 2048 * kD;
            gemm_mfma128<<<dim3(kFFN / 64, 2048 / 128), blk, 0, stream>>>(
                nb + off, ff1_w1t, ff1_b1, nullptr, nullptr, hchunk,
                2048, kFFN, kD, ACT_SILU, 1.f);
            gemm_mfma64<<<dim3(kD / 64, 2048 / 64), blk, 0, stream>>>(
                hchunk, ff1_w2t, ff1_b2, x + off, xf + off, nullptr,
                2048, kD, kFFN, ACT_NONE, 0.5f, 0);
        }

        // ---- RPE attention
        ln_kernel<<<kROWS, blk, 0, stream>>>(xf, an_g, an_b, nb, 0);
        gemm_qkv<<<dim3(24, kROWS / 64), blk, 0, stream>>>(
            nb, wqt, bq, bk, bv, Qb, Kb, Vb);
        vtrans_kernel<<<dim3(16, 8, 4), blk, 0, stream>>>(Vb, Vtg);
        gemm_mfma64<<<dim3(kD / 64, (kP + 63) / 64), blk, 0, stream>>>(
            rel_pe, poswt, nullptr, nullptr, nullptr, Rb, kP, kD, kD, ACT_NONE, 1.f, 1);
        attn_mfma<<<dim3(kT / 64, kH, kN), blk, 0, stream>>>(Qb, Kb, Vtg, Rb, uu, vvp, attnb);
        gemm_mfma64<<<dim3(kD / 64, kROWS / 64), blk, 0, stream>>>(
            attnb, wot, bo, xf, xf, nullptr, kROWS, kD, kD, ACT_NONE, 1.f, 0);

        // ---- conv module (dwt MUST run after attention: dwt/beff alias Rb)
        dwt_kernel<<<62, blk, 0, stream>>>(dw_w, dw_b, bn_g, bn_b, dwt, beff);
        ln_kernel<<<kROWS, blk, 0, stream>>>(xf, cn_g, cn_b, nb, 0);
        gemm_mfma64<<<dim3(2 * kD / 64, kROWS / 64), blk, 0, stream>>>(
            nb, pewt, pe_b, nullptr, nullptr, cbuf, kROWS, 2 * kD, kD, ACT_NONE, 1.f, 0);
        gluconv_kernel<<<dim3(8, 16, 4), blk, 0, stream>>>(cbuf, dwt, beff, convb);
        gemm_mfma64<<<dim3(kD / 64, kROWS / 64), blk, 0, stream>>>(
            convb, pcwt, pc_b, xf, xf, nullptr, kROWS, kD, kD, ACT_NONE, 1.f, 0);

        // ---- macaron FF2
        ln_kernel<<<kROWS, blk, 0, stream>>>(xf, ln2_g, ln2_b, nb, 0);
        for (int c = 0; c < 2; ++c) {
            size_t off = (size_t)c * 2048 * kD;
            gemm_mfma128<<<dim3(kFFN / 64, 2048 / 128), blk, 0, stream>>>(
                nb + off, ff2_w1t, ff2_b1, nullptr, nullptr, hchunk,
                2048, kFFN, kD, ACT_SILU, 1.f);
            gemm_mfma64<<<dim3(kD / 64, 2048 / 64), blk, 0, stream>>>(
                hchunk, ff2_w2t, ff2_b2, xf + off, xf + off, nullptr,
                2048, kD, kFFN, ACT_NONE, 0.5f, 0);
        }

        ln_kernel<<<kROWS, blk, 0, stream>>>(xf, fn_g, fn_b, d_out, 1);
        return;
    }

    if (ws_size < 22 * MB) {
        stamp_kernel<<<(out_size + 255) / 256, blk, 0, stream>>>(
            (float*)d_out, out_size, 1000.f + (float)(ws_size / MB));
        return;
    }

    // ================= SLOW PATH (scalar, known-good) =================
    float* xf    = (float*)(w);
    bf16*  hbch  = (bf16*)(w + 8 * MB);
    bf16*  Qb    = (bf16*)(w + 8 * MB);
    bf16*  cbuf  = (bf16*)(w + 8 * MB);
    bf16*  convb = (bf16*)(w + 8 * MB);
    bf16*  Kb    = (bf16*)(w + 12 * MB);
    bf16*  Vb    = (bf16*)(w + 16 * MB);
    bf16*  glub  = (bf16*)(w + 16 * MB);
    bf16*  Rb    = (bf16*)(w + 20 * MB);
    bf16*  nb    = (bf16*)d_out;
    bf16*  attnb = (bf16*)d_out;

    cvt_kernel<<<total / 1024, blk, 0, stream>>>(x, xf, total / 4);

    ln_kernel<<<kROWS, blk, 0, stream>>>(xf, ln1_g, ln1_b, nb, 0);
    for (int c = 0; c < 4; ++c) {
        size_t off = (size_t)c * 1024 * kD;
        gemm_scalar<<<dim3(kFFN / 64, 1024 / 64), blk, 0, stream>>>(
            nb + off, ff1_w1, ff1_b1, nullptr, nullptr, hbch, 1024, kFFN, kD, ACT_SILU, 1.f, 0);
        gemm_scalar<<<dim3(kD / 64, 1024 / 64), blk, 0, stream>>>(
            hbch, ff1_w2, ff1_b2, xf + off, xf + off, nullptr, 1024, kD, kFFN, ACT_NONE, 0.5f, 0);
    }

    ln_kernel<<<kROWS, blk, 0, stream>>>(xf, an_g, an_b, nb, 0);
    gemm_scalar<<<dim3(kD / 64, kROWS / 64), blk, 0, stream>>>(
        nb, wq, bq, nullptr, nullptr, Qb, kROWS, kD, kD, ACT_NONE, 1.f, 0);
    gemm_scalar<<<dim3(kD / 64, kROWS / 64), blk, 0, stream>>>(
        nb, wk, bk, nullptr, nullptr, Kb, kROWS, kD, kD, ACT_NONE, 1.f, 0);
    gemm_scalar<<<dim3(kD / 64, kROWS / 64), blk, 0, stream>>>(
        nb, wv, bv, nullptr, nullptr, Vb, kROWS, kD, kD, ACT_NONE, 1.f, 0);
    gemm_scalar<<<dim3(kD / 64, (kP + 63) / 64), blk, 0, stream>>>(
        rel_pe, pos_w, nullptr, nullptr, nullptr, Rb, kP, kD, kD, ACT_NONE, 1.f, 1);
    attn_kernel<<<dim3(kT / 64, kH, kN), blk, 0, stream>>>(Qb, Kb, Vb, Rb, uu, vvp, attnb);
    gemm_scalar<<<dim3(kD / 64, kROWS / 64), blk, 0, stream>>>(
        attnb, wo, bo, xf, xf, nullptr, kROWS, kD, kD, ACT_NONE, 1.f, 0);

    ln_kernel<<<kROWS, blk, 0, stream>>>(xf, cn_g, cn_b, nb, 0);
    gemm_scalar<<<dim3(2 * kD / 64, kROWS / 64), blk, 0, stream>>>(
        nb, pe_w, pe_b, nullptr, nullptr, cbuf, kROWS, 2 * kD, kD, ACT_NONE, 1.f, 0);
    glu_kernel_v<<<total / 2048, blk, 0, stream>>>(cbuf, glub);
    conv_kernel<<<total / 256, blk, 0, stream>>>(glub, dw_w, dw_b, bn_g, bn_b, convb);
    gemm_scalar<<<dim3(kD / 64, kROWS / 64), blk, 0, stream>>>(
        convb, pc_w, pc_b, xf, xf, nullptr, kROWS, kD, kD, ACT_NONE, 1.f, 0);

    ln_kernel<<<kROWS, blk, 0, stream>>>(xf, ln2_g, ln2_b, nb, 0);
    for (int c = 0; c < 4; ++c) {
        size_t off = (size_t)c * 1024 * kD;
        gemm_scalar<<<dim3(kFFN / 64, 1024 / 64), blk, 0, stream>>>(
            nb + off, ff2_w1, ff2_b1, nullptr, nullptr, hbch, 1024, kFFN, kD, ACT_SILU, 1.f, 0);
        gemm_scalar<<<dim3(kD / 64, 1024 / 64), blk, 0, stream>>>(
            hbch, ff2_w2, ff2_b2, xf + off, xf + off, nullptr, 1024, kD, kFFN, ACT_NONE, 0.5f, 0);
    }

    ln_kernel<<<kROWS, blk, 0, stream>>>(xf, fn_g, fn_b, d_out, 1);
}

// Round 13
// 495.705 us; speedup vs baseline: 1.0474x; 1.0474x over previous
//
#include <hip/hip_runtime.h>
#include <hip/hip_bf16.h>

using bf16 = __hip_bfloat16;
typedef __attribute__((ext_vector_type(8))) short short8;
typedef __attribute__((ext_vector_type(4))) short short4v;
typedef __attribute__((ext_vector_type(4))) float f32x4;

static __device__ __forceinline__ float b2f(bf16 v) { return __bfloat162float(v); }
static __device__ __forceinline__ bf16  f2b(float v) { return __float2bfloat16(v); }
static __device__ __forceinline__ short f2bs(float x) {
    union { float f; unsigned u; } c; c.f = x;
    unsigned r = (c.u + 0x7FFFu + ((c.u >> 16) & 1u)) >> 16;
    return (short)r;
}
static __device__ __forceinline__ float bs2f(short s) {
    union { unsigned u; float f; } c; c.u = ((unsigned)(unsigned short)s) << 16;
    return c.f;
}
// async global->LDS, 16B per lane; LDS dst = wave-uniform base + lane*16
static __device__ __forceinline__ void gload16(const short* g, short* l) {
    __builtin_amdgcn_global_load_lds(
        (const __attribute__((address_space(1))) void*)g,
        (__attribute__((address_space(3))) void*)l, 16, 0, 0);
}

constexpr int kD   = 512;
constexpr int kT   = 1024;
constexpr int kN   = 4;
constexpr int kH   = 8;
constexpr int kDH  = 64;
constexpr int kFFN = 2048;
constexpr int kROWS = kN * kT;        // 4096
constexpr int kP    = 2 * kT - 1;     // 2047

#define ACT_NONE 0
#define ACT_SILU 1

// ---------------------------------------------------------------- fallback stamp
__global__ __launch_bounds__(256) void stamp_kernel(float* __restrict__ out, int n, float val) {
    int i = blockIdx.x * 256 + threadIdx.x;
    if (i < n) out[i] = (i == 0 ? val : 0.f);
}

// ---------------------------------------------------------------- copy (slow path only)
__global__ __launch_bounds__(256) void cvt_kernel(const float* __restrict__ in,
                                                  float* __restrict__ out, int n4) {
    int i = blockIdx.x * 256 + threadIdx.x;
    if (i < n4) ((f32x4*)out)[i] = ((const f32x4*)in)[i];
}

// ---------------------------------------------------------------- fused weight transpose
struct WtDesc { const float* src; short* dst; int K; int N; int tstart; };
struct WtArgs { WtDesc d[11]; };

__global__ __launch_bounds__(256) void wt_all_kernel(WtArgs a) {
    __shared__ float t[32][33];
    int bid = blockIdx.x;
    int i = 0;
#pragma unroll
    for (int j = 1; j < 11; ++j) if (bid >= a.d[j].tstart) i = j;
    const float* W = a.d[i].src;
    short* Wt = a.d[i].dst;
    int Kd = a.d[i].K, Nd = a.d[i].N;
    int lt = bid - a.d[i].tstart;
    int nx = Nd >> 5;
    int n0 = (lt % nx) * 32, k0 = (lt / nx) * 32;
    int tx = threadIdx.x & 31, ty = threadIdx.x >> 5;
#pragma unroll
    for (int it = 0; it < 4; ++it)
        t[ty + it * 8][tx] = W[(size_t)(k0 + ty + it * 8) * Nd + n0 + tx];
    __syncthreads();
#pragma unroll
    for (int it = 0; it < 4; ++it)
        Wt[(size_t)(n0 + ty + it * 8) * Kd + k0 + tx] = f2bs(t[tx][ty + it * 8]);
}

// ---------------------------------------------------------------- V transpose per (n,h)
__global__ __launch_bounds__(256) void vtrans_kernel(const bf16* __restrict__ V,
                                                     bf16* __restrict__ Vt) {
    __shared__ short ts[64][72];
    int tt = blockIdx.x, h = blockIdx.y, n = blockIdx.z;
    int tid = threadIdx.x;
    int r = tid >> 3, cg = (tid & 7) * 8;
#pragma unroll
    for (int it = 0; it < 2; ++it) {
        int row = it * 32 + r;
        *(short8*)&ts[row][cg] =
            *(const short8*)((const short*)V + ((size_t)n * kT + tt * 64 + row) * 512 + h * 64 + cg);
    }
    __syncthreads();
#pragma unroll
    for (int it = 0; it < 2; ++it) {
        int d = it * 32 + r;
        short8 o;
#pragma unroll
        for (int i = 0; i < 8; ++i) o[i] = ts[cg + i][d];
        *(short8*)((short*)Vt + ((size_t)(n * 8 + h) * 64 + d) * 1024 + tt * 64 + cg) = o;
    }
}

// ---------------------------------------------------------------- depthwise weight prep (fold BN)
__global__ __launch_bounds__(256) void dwt_kernel(const float* __restrict__ dw_w,
                                                  const float* __restrict__ dw_b,
                                                  const float* __restrict__ bn_g,
                                                  const float* __restrict__ bn_b,
                                                  float* __restrict__ wt,
                                                  float* __restrict__ beff) {
    int idx = blockIdx.x * 256 + threadIdx.x;
    if (idx < 31 * kD) {
        int d = idx & 511, k = idx >> 9;
        wt[k * kD + d] = dw_w[d * 31 + k] * bn_g[d];
    }
    if (idx < kD) beff[idx] = dw_b[idx] * bn_g[idx] + bn_b[idx];
}

// ---------------------------------------------------------------- layernorm, vectorized
// 2 rows per 256-thr block; f32x4 loads (16B/lane); 2 waves per row.
__global__ __launch_bounds__(256) void ln_kernel_v(const float* __restrict__ xin,
                                                   const float* __restrict__ g,
                                                   const float* __restrict__ b,
                                                   void* __restrict__ outp, int out_f32) {
    int tid = threadIdx.x;
    int rh = tid >> 7;                    // 0/1: which row of the pair
    int tl = tid & 127;                   // lane within row (4 floats each)
    int row = blockIdx.x * 2 + rh;
    const float* xr = xin + (size_t)row * kD;
    f32x4 v = *(const f32x4*)(xr + tl * 4);
    float s  = v[0] + v[1] + v[2] + v[3];
    float sq = v[0]*v[0] + v[1]*v[1] + v[2]*v[2] + v[3]*v[3];
    for (int off = 32; off; off >>= 1) {
        s  += __shfl_down(s, off);
        sq += __shfl_down(sq, off);
    }
    __shared__ float ss[4], ssq[4], mean_s[2], rstd_s[2];
    int wid = tid >> 6;
    if ((tid & 63) == 0) { ss[wid] = s; ssq[wid] = sq; }
    __syncthreads();
    if (tid < 2) {
        float S  = ss[tid * 2] + ss[tid * 2 + 1];
        float SQ = ssq[tid * 2] + ssq[tid * 2 + 1];
        float m = S / (float)kD;
        float var = SQ / (float)kD - m * m;
        mean_s[tid] = m;
        rstd_s[tid] = rsqrtf(fmaxf(var, 0.f) + 1e-5f);
    }
    __syncthreads();
    float m = mean_s[rh], rs = rstd_s[rh];
    f32x4 gg = *(const f32x4*)(g + tl * 4);
    f32x4 bb = *(const f32x4*)(b + tl * 4);
    if (out_f32) {
        f32x4 o;
#pragma unroll
        for (int i = 0; i < 4; ++i) o[i] = (v[i] - m) * rs * gg[i] + bb[i];
        *(f32x4*)((float*)outp + (size_t)row * kD + tl * 4) = o;
    } else {
        short4v o;
#pragma unroll
        for (int i = 0; i < 4; ++i) o[i] = f2bs((v[i] - m) * rs * gg[i] + bb[i]);
        *(short4v*)((short*)outp + (size_t)row * kD + tl * 4) = o;
    }
}

// ---------------------------------------------------------------- layernorm (slow path)
__global__ __launch_bounds__(256) void ln_kernel(const float* __restrict__ xin,
                                                 const float* __restrict__ g,
                                                 const float* __restrict__ b,
                                                 void* __restrict__ outp, int out_f32) {
    int row = blockIdx.x;
    const float* xr = xin + (size_t)row * kD;
    int tid = threadIdx.x;
    float v0 = xr[tid], v1 = xr[tid + 256];
    float s = v0 + v1, sq = v0 * v0 + v1 * v1;
    for (int off = 32; off; off >>= 1) {
        s  += __shfl_down(s, off);
        sq += __shfl_down(sq, off);
    }
    __shared__ float ss[4], ssq[4];
    __shared__ float mean_s, rstd_s;
    int wid = tid >> 6, lane = tid & 63;
    if (lane == 0) { ss[wid] = s; ssq[wid] = sq; }
    __syncthreads();
    if (tid == 0) {
        float S  = ss[0] + ss[1] + ss[2] + ss[3];
        float SQ = ssq[0] + ssq[1] + ssq[2] + ssq[3];
        float m = S / (float)kD;
        float var = SQ / (float)kD - m * m;
        mean_s = m;
        rstd_s = rsqrtf(fmaxf(var, 0.f) + 1e-5f);
    }
    __syncthreads();
    float m = mean_s, rs = rstd_s;
    float o0 = (v0 - m) * rs * g[tid]       + b[tid];
    float o1 = (v1 - m) * rs * g[tid + 256] + b[tid + 256];
    size_t i0 = (size_t)row * kD + tid, i1 = i0 + 256;
    if (out_f32) {
        ((float*)outp)[i0] = o0; ((float*)outp)[i1] = o1;
    } else {
        ((bf16*)outp)[i0] = f2b(o0); ((bf16*)outp)[i1] = f2b(o1);
    }
}

// ---------------------------------------------------------------- MFMA GEMM, 64x64 tile (dbuf async)
__global__ __launch_bounds__(256, 4) void gemm_mfma64(
    const void* __restrict__ A, const short* __restrict__ Bt,
    const float* __restrict__ bias, const float* __restrict__ residual,
    float* __restrict__ outf, bf16* __restrict__ outb,
    int M, int N, int K, int act, float scale, int a_f32) {
    __shared__ short As[2][4096];
    __shared__ short Bs[2][4096];
    int tid = threadIdx.x;
    int m0 = blockIdx.y * 64, n0 = blockIdx.x * 64;
    int wid = tid >> 6, lane = tid & 63;
    int wm = (wid >> 1) * 32, wn = (wid & 1) * 32;
    int q = lane >> 4, c16 = lane & 15;

    f32x4 zero4 = {0.f, 0.f, 0.f, 0.f};
    f32x4 acc[2][2] = {{zero4, zero4}, {zero4, zero4}};

    int arow = lane >> 3;
    int aseg = (lane & 7) ^ arow;

    auto issueA = [&](int buf, int k0) {
        if (!a_f32) {
#pragma unroll
            for (int it = 0; it < 2; ++it) {
                int rbase = (wid * 2 + it) * 8;
                gload16((const short*)A + (size_t)(m0 + rbase + arow) * K + k0 + aseg * 8,
                        &As[buf][(wid * 2 + it) * 512]);
            }
        } else {
            int srow = tid >> 3, sseg = tid & 7;
#pragma unroll
            for (int it = 0; it < 2; ++it) {
                int row = it * 32 + srow;
                int rr = m0 + row;
                short8 v = {0, 0, 0, 0, 0, 0, 0, 0};
                if (rr < M) {
                    const float* ap = (const float*)A + (size_t)rr * K + k0 + sseg * 8;
                    f32x4 x0 = *(const f32x4*)ap;
                    f32x4 x1 = *(const f32x4*)(ap + 4);
                    v[0] = f2bs(x0[0]); v[1] = f2bs(x0[1]); v[2] = f2bs(x0[2]); v[3] = f2bs(x0[3]);
                    v[4] = f2bs(x1[0]); v[5] = f2bs(x1[1]); v[6] = f2bs(x1[2]); v[7] = f2bs(x1[3]);
                }
                *(short8*)&As[buf][(row * 8 + (sseg ^ (row & 7))) * 8] = v;
            }
        }
    };
    auto issueB = [&](int buf, int k0) {
#pragma unroll
        for (int it = 0; it < 2; ++it) {
            int rbase = (wid * 2 + it) * 8;
            gload16(Bt + (size_t)(n0 + rbase + arow) * K + k0 + aseg * 8,
                    &Bs[buf][(wid * 2 + it) * 512]);
        }
    };

    issueA(0, 0);
    issueB(0, 0);
    int cur = 0;
    for (int k0 = 0; k0 < K; k0 += 64) {
        __syncthreads();
        if (k0 + 64 < K) {
            issueA(cur ^ 1, k0 + 64);
            issueB(cur ^ 1, k0 + 64);
        }
#pragma unroll
        for (int ks = 0; ks < 2; ++ks) {
            int p = c16 & 7;
            short8 af[2], bfr[2];
#pragma unroll
            for (int mt = 0; mt < 2; ++mt) {
                int row = wm + mt * 16 + c16;
                af[mt] = *(const short8*)&As[cur][(row * 8 + ((ks * 4 + q) ^ p)) * 8];
            }
#pragma unroll
            for (int nt = 0; nt < 2; ++nt) {
                int row = wn + nt * 16 + c16;
                bfr[nt] = *(const short8*)&Bs[cur][(row * 8 + ((ks * 4 + q) ^ p)) * 8];
            }
#pragma unroll
            for (int mt = 0; mt < 2; ++mt)
#pragma unroll
                for (int nt = 0; nt < 2; ++nt)
                    acc[mt][nt] = __builtin_amdgcn_mfma_f32_16x16x32_bf16(
                        af[mt], bfr[nt], acc[mt][nt], 0, 0, 0);
        }
        cur ^= 1;
    }
#pragma unroll
    for (int mt = 0; mt < 2; ++mt) {
#pragma unroll
        for (int reg = 0; reg < 4; ++reg) {
            int r = m0 + wm + mt * 16 + q * 4 + reg;
            if (r >= M) continue;
#pragma unroll
            for (int nt = 0; nt < 2; ++nt) {
                int c = n0 + wn + nt * 16 + c16;
                float h = acc[mt][nt][reg];
                if (bias) h += bias[c];
                if (act == ACT_SILU) h = h / (1.f + __expf(-h));
                h *= scale;
                size_t idx = (size_t)r * N + c;
                if (residual) h += residual[idx];
                if (outf) outf[idx] = h;
                if (outb) outb[idx] = f2b(h);
            }
        }
    }
}

// ---------------------------------------------------------------- fused QKV GEMM (dbuf async)
__global__ __launch_bounds__(256, 4) void gemm_qkv(
    const bf16* __restrict__ A, const short* __restrict__ Bt,
    const float* __restrict__ bq, const float* __restrict__ bk,
    const float* __restrict__ bv,
    bf16* __restrict__ Qb, bf16* __restrict__ Kb, bf16* __restrict__ Vb) {
    const int K = kD;
    __shared__ short As[2][4096];
    __shared__ short Bs[2][4096];
    int tid = threadIdx.x;
    int m0 = blockIdx.y * 64, n0 = blockIdx.x * 64;
    int seg = blockIdx.x >> 3;
    const float* bias = seg == 0 ? bq : (seg == 1 ? bk : bv);
    bf16* outb = seg == 0 ? Qb : (seg == 1 ? Kb : Vb);
    int ns0 = n0 & 511;
    int wid = tid >> 6, lane = tid & 63;
    int wm = (wid >> 1) * 32, wn = (wid & 1) * 32;
    int q = lane >> 4, c16 = lane & 15;

    f32x4 zero4 = {0.f, 0.f, 0.f, 0.f};
    f32x4 acc[2][2] = {{zero4, zero4}, {zero4, zero4}};
    int arow = lane >> 3;
    int aseg = (lane & 7) ^ arow;

    auto issue = [&](int buf, int k0) {
#pragma unroll
        for (int it = 0; it < 2; ++it) {
            int rbase = (wid * 2 + it) * 8;
            gload16((const short*)A + (size_t)(m0 + rbase + arow) * K + k0 + aseg * 8,
                    &As[buf][(wid * 2 + it) * 512]);
            gload16(Bt + (size_t)(n0 + rbase + arow) * K + k0 + aseg * 8,
                    &Bs[buf][(wid * 2 + it) * 512]);
        }
    };

    issue(0, 0);
    int cur = 0;
    for (int k0 = 0; k0 < K; k0 += 64) {
        __syncthreads();
        if (k0 + 64 < K) issue(cur ^ 1, k0 + 64);
#pragma unroll
        for (int ks = 0; ks < 2; ++ks) {
            int p = c16 & 7;
            short8 af[2], bfr[2];
#pragma unroll
            for (int mt = 0; mt < 2; ++mt) {
                int row = wm + mt * 16 + c16;
                af[mt] = *(const short8*)&As[cur][(row * 8 + ((ks * 4 + q) ^ p)) * 8];
            }
#pragma unroll
            for (int nt = 0; nt < 2; ++nt) {
                int row = wn + nt * 16 + c16;
                bfr[nt] = *(const short8*)&Bs[cur][(row * 8 + ((ks * 4 + q) ^ p)) * 8];
            }
#pragma unroll
            for (int mt = 0; mt < 2; ++mt)
#pragma unroll
                for (int nt = 0; nt < 2; ++nt)
                    acc[mt][nt] = __builtin_amdgcn_mfma_f32_16x16x32_bf16(
                        af[mt], bfr[nt], acc[mt][nt], 0, 0, 0);
        }
        cur ^= 1;
    }
#pragma unroll
    for (int mt = 0; mt < 2; ++mt)
#pragma unroll
        for (int reg = 0; reg < 4; ++reg) {
            int r = m0 + wm + mt * 16 + q * 4 + reg;
#pragma unroll
            for (int nt = 0; nt < 2; ++nt) {
                int c = ns0 + wn + nt * 16 + c16;
                outb[(size_t)r * 512 + c] = f2b(acc[mt][nt][reg] + bias[c]);
            }
        }
}

// ---------------------------------------------------------------- scalar GEMM (slow fallback)
__global__ __launch_bounds__(256) void gemm_scalar(
    const void* __restrict__ A, const float* __restrict__ W,
    const float* __restrict__ bias, const float* __restrict__ residual,
    float* __restrict__ outf, bf16* __restrict__ outb,
    int M, int N, int K, int act, float scale, int a_f32) {
    __shared__ float As[16][65];
    __shared__ float Bs[16][65];
    int tid = threadIdx.x;
    int tx = tid & 15, ty = tid >> 4;
    int row0 = blockIdx.y * 64, col0 = blockIdx.x * 64;
    float acc[4][4] = {};
    for (int k0 = 0; k0 < K; k0 += 16) {
        for (int i = tid; i < 64 * 16; i += 256) {
            int r = i >> 4, c = i & 15;
            int rr = row0 + r;
            float v = 0.f;
            if (rr < M) {
                size_t idx = (size_t)rr * K + k0 + c;
                v = a_f32 ? ((const float*)A)[idx] : b2f(((const bf16*)A)[idx]);
            }
            As[c][r] = v;
        }
        for (int i = tid; i < 16 * 64; i += 256) {
            int r = i >> 6, c = i & 63;
            Bs[r][c] = W[(size_t)(k0 + r) * N + col0 + c];
        }
        __syncthreads();
#pragma unroll
        for (int kk = 0; kk < 16; ++kk) {
            float a[4], b[4];
#pragma unroll
            for (int i = 0; i < 4; ++i) a[i] = As[kk][ty * 4 + i];
#pragma unroll
            for (int j = 0; j < 4; ++j) b[j] = Bs[kk][tx * 4 + j];
#pragma unroll
            for (int i = 0; i < 4; ++i)
#pragma unroll
                for (int j = 0; j < 4; ++j) acc[i][j] += a[i] * b[j];
        }
        __syncthreads();
    }
#pragma unroll
    for (int i = 0; i < 4; ++i) {
        int r = row0 + ty * 4 + i;
        if (r >= M) continue;
#pragma unroll
        for (int j = 0; j < 4; ++j) {
            int c = col0 + tx * 4 + j;
            float h = acc[i][j];
            if (bias) h += bias[c];
            if (act == ACT_SILU) h = h / (1.f + __expf(-h));
            h *= scale;
            size_t idx = (size_t)r * N + c;
            if (residual) h += residual[idx];
            if (outf) outf[idx] = h;
            if (outb) outb[idx] = f2b(h);
        }
    }
}

// ---------------------------------------------------------------- MFMA RPE attention
// B-trim: wave w only gathers j in [wm, wm+78] -> compute only 5 jt-groups.
__global__ __launch_bounds__(256, 2) void attn_mfma(
    const bf16* __restrict__ Qg, const bf16* __restrict__ Kg,
    const bf16* __restrict__ Vtg, const bf16* __restrict__ Rg,
    const float* __restrict__ uu, const float* __restrict__ vvp,
    bf16* __restrict__ outb) {
    __shared__ short Qu[64][72];
    __shared__ short Qv[64][72];
    __shared__ short Ks[64][72];
    __shared__ short Vt[64][72];
    __shared__ short Rw[128][72];
    __shared__ short Bp[64][136];

    int tid = threadIdx.x;
    int qb = blockIdx.x, h = blockIdx.y, n = blockIdx.z;
    int t0 = qb * 64;
    size_t baseq = ((size_t)n * kT) * 512 + (size_t)h * kDH;
    size_t basev = ((size_t)(n * 8 + h) * 64) * 1024;
    size_t baseo = ((size_t)n * kT) * kD + (size_t)h * kDH;

    int wid = tid >> 6, lane = tid & 63;
    int q = lane >> 4, c16 = lane & 15;
    int wm = wid * 16;
    int trow = wm + q * 4;

    {
        int t = tid >> 2, dg = (tid & 3) * 16;
        const short* qp = (const short*)Qg + baseq + (size_t)(t0 + t) * 512 + dg;
        short8 q0 = *(const short8*)qp;
        short8 q1 = *(const short8*)(qp + 8);
#pragma unroll
        for (int i = 0; i < 8; ++i) {
            float qv = bs2f(q0[i]);
            Qu[t][dg + i] = f2bs(qv + uu[h * 64 + dg + i]);
            Qv[t][dg + i] = f2bs(qv + vvp[h * 64 + dg + i]);
        }
#pragma unroll
        for (int i = 0; i < 8; ++i) {
            float qv = bs2f(q1[i]);
            Qu[t][dg + 8 + i] = f2bs(qv + uu[h * 64 + dg + 8 + i]);
            Qv[t][dg + 8 + i] = f2bs(qv + vvp[h * 64 + dg + 8 + i]);
        }
    }

    f32x4 zero4 = {0.f, 0.f, 0.f, 0.f};
    f32x4 acc_o[4] = {zero4, zero4, zero4, zero4};
    float m_i[4] = {-1e30f, -1e30f, -1e30f, -1e30f};
    float l_i[4] = {0.f, 0.f, 0.f, 0.f};

    for (int kt = 0; kt < 16; ++kt) {
        int s0 = kt * 64;
        __syncthreads();
        {
            int s = tid >> 2, dg = (tid & 3) * 16;
            const short* kp = (const short*)Kg + baseq + (size_t)(s0 + s) * 512 + dg;
            *(short8*)&Ks[s][dg]     = *(const short8*)kp;
            *(short8*)&Ks[s][dg + 8] = *(const short8*)(kp + 8);
            const short* vp = (const short*)Vtg + basev + (size_t)s * 1024 + s0 + dg;
            *(short8*)&Vt[s][dg]     = *(const short8*)vp;
            *(short8*)&Vt[s][dg + 8] = *(const short8*)(vp + 8);
        }
        int p_base = t0 - s0 + 960;
#pragma unroll
        for (int it = 0; it < 4; ++it) {
            int i = tid + it * 256;
            int j = i >> 3, dg2 = (i & 7) * 8;
            int p = p_base + j;
            p = p < 0 ? 0 : (p > 2046 ? 2046 : p);
            *(short8*)&Rw[j][dg2] =
                *(const short8*)((const short*)Rg + (size_t)p * kD + h * kDH + dg2);
        }
        __syncthreads();

        f32x4 acc_s[4] = {zero4, zero4, zero4, zero4};
        f32x4 acc_b[5] = {zero4, zero4, zero4, zero4, zero4};
#pragma unroll
        for (int ks = 0; ks < 2; ++ks) {
            short8 au = *(const short8*)&Qu[wm + c16][ks * 32 + q * 8];
            short8 av = *(const short8*)&Qv[wm + c16][ks * 32 + q * 8];
#pragma unroll
            for (int nt = 0; nt < 4; ++nt) {
                short8 bk_ = *(const short8*)&Ks[nt * 16 + c16][ks * 32 + q * 8];
                acc_s[nt] = __builtin_amdgcn_mfma_f32_16x16x32_bf16(au, bk_, acc_s[nt], 0, 0, 0);
            }
#pragma unroll
            for (int jt = 0; jt < 5; ++jt) {
                short8 br_ = *(const short8*)&Rw[wm + jt * 16 + c16][ks * 32 + q * 8];
                acc_b[jt] = __builtin_amdgcn_mfma_f32_16x16x32_bf16(av, br_, acc_b[jt], 0, 0, 0);
            }
        }
#pragma unroll
        for (int jt = 0; jt < 5; ++jt)
#pragma unroll
            for (int reg = 0; reg < 4; ++reg)
                Bp[trow + reg][wm + jt * 16 + c16] = f2bs(acc_b[jt][reg]);

        float pmat[4][4];
        float alpha[4];
#pragma unroll
        for (int reg = 0; reg < 4; ++reg) {
            int t = trow + reg;
            float mrow = -1e30f;
#pragma unroll
            for (int nt = 0; nt < 4; ++nt) {
                int s = nt * 16 + c16;
                int j = t - s + 63;
                float sv = (acc_s[nt][reg] + bs2f(Bp[t][j])) * 0.125f;
                pmat[nt][reg] = sv;
                mrow = fmaxf(mrow, sv);
            }
            mrow = fmaxf(mrow, __shfl_xor(mrow, 1));
            mrow = fmaxf(mrow, __shfl_xor(mrow, 2));
            mrow = fmaxf(mrow, __shfl_xor(mrow, 4));
            mrow = fmaxf(mrow, __shfl_xor(mrow, 8));
            float m_new = fmaxf(m_i[reg], mrow);
            alpha[reg] = __expf(m_i[reg] - m_new);
            float ps = 0.f;
#pragma unroll
            for (int nt = 0; nt < 4; ++nt) {
                float pe = __expf(pmat[nt][reg] - m_new);
                pmat[nt][reg] = pe;
                ps += pe;
            }
            ps += __shfl_xor(ps, 1);
            ps += __shfl_xor(ps, 2);
            ps += __shfl_xor(ps, 4);
            ps += __shfl_xor(ps, 8);
            l_i[reg] = l_i[reg] * alpha[reg] + ps;
            m_i[reg] = m_new;
        }
#pragma unroll
        for (int nt = 0; nt < 4; ++nt)
#pragma unroll
            for (int reg = 0; reg < 4; ++reg)
                Bp[trow + reg][nt * 16 + c16] = f2bs(pmat[nt][reg]);
#pragma unroll
        for (int dt = 0; dt < 4; ++dt)
#pragma unroll
            for (int reg = 0; reg < 4; ++reg)
                acc_o[dt][reg] *= alpha[reg];
#pragma unroll
        for (int ks = 0; ks < 2; ++ks) {
            short8 ap = *(const short8*)&Bp[wm + c16][ks * 32 + q * 8];
#pragma unroll
            for (int dt = 0; dt < 4; ++dt) {
                short8 bv_ = *(const short8*)&Vt[dt * 16 + c16][ks * 32 + q * 8];
                acc_o[dt] = __builtin_amdgcn_mfma_f32_16x16x32_bf16(ap, bv_, acc_o[dt], 0, 0, 0);
            }
        }
    }
#pragma unroll
    for (int reg = 0; reg < 4; ++reg) {
        float inv = 1.f / l_i[reg];
        int t = trow + reg;
#pragma unroll
        for (int dt = 0; dt < 4; ++dt)
            outb[baseo + (size_t)(t0 + t) * kD + dt * 16 + c16] = f2b(acc_o[dt][reg] * inv);
    }
}

// ---------------------------------------------------------------- scalar attention (slow path)
__global__ __launch_bounds__(256) void attn_kernel(
    const bf16* __restrict__ Qg, const bf16* __restrict__ Kg,
    const bf16* __restrict__ Vg, const bf16* __restrict__ Rg,
    const float* __restrict__ uu, const float* __restrict__ vvp,
    bf16* __restrict__ outb) {
    __shared__ float Qs[64][65];
    __shared__ bf16 Ps[64][66];
    __shared__ bf16 Ks[64][66];
    __shared__ bf16 Vs[64][66];
    __shared__ bf16 Rs[127][66];
    __shared__ float uf[64], vf[64];
    __shared__ float uK[64], vR[127];

    int tid = threadIdx.x;
    int qb = blockIdx.x, h = blockIdx.y, n = blockIdx.z;
    int t0 = qb * 64;
    size_t base = ((size_t)n * kT) * kD + (size_t)h * kDH;

    if (tid < 64) {
        uf[tid] = uu[h * 64 + tid];
        vf[tid] = vvp[h * 64 + tid];
    }
    for (int i = tid; i < 64 * 64; i += 256) {
        int r = i >> 6, d = i & 63;
        Qs[r][d] = b2f(Qg[base + (size_t)(t0 + r) * kD + d]);
    }
    int r = tid >> 2, seg = tid & 3;
    float m_i = -1e30f, l_i = 0.f;
    float Oa[16];
#pragma unroll
    for (int i = 0; i < 16; ++i) Oa[i] = 0.f;

    for (int kt = 0; kt < 16; ++kt) {
        int s0 = kt * 64;
        __syncthreads();
        for (int i = tid; i < 64 * 64; i += 256) {
            int s = i >> 6, d = i & 63;
            Ks[s][d] = Kg[base + (size_t)(s0 + s) * kD + d];
            Vs[s][d] = Vg[base + (size_t)(s0 + s) * kD + d];
        }
        int p_base = t0 - s0 + 960;
        for (int i = tid; i < 127 * 64; i += 256) {
            int j = i >> 6, d = i & 63;
            int p = p_base + j;
            p = p < 0 ? 0 : (p > 2046 ? 2046 : p);
            Rs[j][d] = Rg[(size_t)p * kD + h * kDH + d];
        }
        __syncthreads();
        if (tid < 64) {
            float s_ = 0.f;
            for (int d = 0; d < 64; ++d) s_ += uf[d] * b2f(Ks[tid][d]);
            uK[tid] = s_;
        } else if (tid < 64 + 127) {
            int j = tid - 64;
            float s_ = 0.f;
            for (int d = 0; d < 64; ++d) s_ += vf[d] * b2f(Rs[j][d]);
            vR[j] = s_;
        }
        __syncthreads();
        float sv[16];
        float smax = -1e30f;
#pragma unroll
        for (int jj = 0; jj < 16; ++jj) {
            int s = seg * 16 + jj;
            int j = r - s + 63;
            float acc = 0.f;
            for (int d = 0; d < 64; ++d)
                acc += Qs[r][d] * (b2f(Ks[s][d]) + b2f(Rs[j][d]));
            acc = (acc + uK[s] + vR[j]) * 0.125f;
            sv[jj] = acc;
            smax = fmaxf(smax, acc);
        }
        smax = fmaxf(smax, __shfl_xor(smax, 1));
        smax = fmaxf(smax, __shfl_xor(smax, 2));
        float m_new = fmaxf(m_i, smax);
        float alpha = __expf(m_i - m_new);
        float psum = 0.f;
#pragma unroll
        for (int jj = 0; jj < 16; ++jj) {
            float p = __expf(sv[jj] - m_new);
            Ps[r][seg * 16 + jj] = f2b(p);
            psum += p;
        }
        psum += __shfl_xor(psum, 1);
        psum += __shfl_xor(psum, 2);
        l_i = l_i * alpha + psum;
        m_i = m_new;
#pragma unroll
        for (int i = 0; i < 16; ++i) Oa[i] *= alpha;
        __syncthreads();
        for (int s = 0; s < 64; ++s) {
            float p = b2f(Ps[r][s]);
#pragma unroll
            for (int dd = 0; dd < 16; ++dd)
                Oa[dd] += p * b2f(Vs[s][seg * 16 + dd]);
        }
    }
    float inv = 1.f / l_i;
#pragma unroll
    for (int dd = 0; dd < 16; ++dd)
        outb[base + (size_t)(t0 + r) * kD + seg * 16 + dd] = f2b(Oa[dd] * inv);
}

// ---------------------------------------------------------------- GLU (slow path)
__global__ __launch_bounds__(256) void glu_kernel_v(const bf16* __restrict__ c,
                                                    bf16* __restrict__ out) {
    int i8 = (blockIdx.x * 256 + threadIdx.x) * 8;
    int row = i8 >> 9, d = i8 & 511;
    const short* cp = (const short*)c + (size_t)row * 1024;
    short8 a8 = *(const short8*)(cp + d);
    short8 g8 = *(const short8*)(cp + 512 + d);
    short8 o;
#pragma unroll
    for (int i = 0; i < 8; ++i) {
        float a = bs2f(a8[i]), g = bs2f(g8[i]);
        o[i] = f2bs(a / (1.f + __expf(-g)));
    }
    *(short8*)((short*)out + i8) = o;
}

// ---------------------------------------------------------------- fused GLU + depthwise conv + BN + SiLU
__global__ __launch_bounds__(256) void gluconv_kernel(
    const bf16* __restrict__ cbuf, const float* __restrict__ wt,
    const float* __restrict__ beff, bf16* __restrict__ outb) {
    __shared__ short gsm[94][72];
    __shared__ float wsm[31][64];
    __shared__ float bsm[64];
    int tid = threadIdx.x;
    int dg0 = blockIdx.x * 64;
    int t0  = blockIdx.y * 64;
    int n   = blockIdx.z;

#pragma unroll
    for (int it = 0; it < 3; ++it) {
        int idx = tid + it * 256;
        if (idx < 94 * 8) {
            int row = idx >> 3, cg = (idx & 7) * 8;
            int t = t0 - 15 + row;
            short8 o = {0, 0, 0, 0, 0, 0, 0, 0};
            if ((unsigned)t < (unsigned)kT) {
                const short* cp = (const short*)cbuf + ((size_t)n * kT + t) * 1024 + dg0 + cg;
                short8 a8 = *(const short8*)cp;
                short8 g8 = *(const short8*)(cp + 512);
#pragma unroll
                for (int i = 0; i < 8; ++i)
                    o[i] = f2bs(bs2f(a8[i]) / (1.f + __expf(-bs2f(g8[i]))));
            }
            *(short8*)&gsm[row][cg] = o;
        }
    }
#pragma unroll
    for (int it = 0; it < 8; ++it) {
        int i = tid + it * 256;
        if (i < 31 * 64) wsm[i >> 6][i & 63] = wt[(i >> 6) * kD + dg0 + (i & 63)];
    }
    if (tid < 64) bsm[tid] = beff[dg0 + tid];
    __syncthreads();

    int tl = tid >> 2, dgl = (tid & 3) * 16;
    float acc[16] = {};
#pragma unroll
    for (int k = 0; k < 31; ++k) {
        short8 g0 = *(const short8*)&gsm[tl + k][dgl];
        short8 g1 = *(const short8*)&gsm[tl + k][dgl + 8];
#pragma unroll
        for (int i = 0; i < 8; ++i) {
            acc[i]     += bs2f(g0[i]) * wsm[k][dgl + i];
            acc[8 + i] += bs2f(g1[i]) * wsm[k][dgl + 8 + i];
        }
    }
    short8 o0, o1;
#pragma unroll
    for (int i = 0; i < 8; ++i) {
        float h = acc[i] + bsm[dgl + i];
        o0[i] = f2bs(h / (1.f + __expf(-h)));
        h = acc[8 + i] + bsm[dgl + 8 + i];
        o1[i] = f2bs(h / (1.f + __expf(-h)));
    }
    short* op = (short*)outb + ((size_t)n * kT + t0 + tl) * kD + dg0 + dgl;
    *(short8*)op = o0;
    *(short8*)(op + 8) = o1;
}

// ---------------------------------------------------------------- scalar conv (slow path)
__global__ __launch_bounds__(256) void conv_kernel(
    const bf16* __restrict__ glu, const float* __restrict__ dw_w,
    const float* __restrict__ dw_b, const float* __restrict__ bn_g,
    const float* __restrict__ bn_b, bf16* __restrict__ outb) {
    int idx = blockIdx.x * 256 + threadIdx.x;
    int d = idx & 511;
    int t = (idx >> 9) & 1023;
    int n = idx >> 19;
    const bf16* gp = glu + ((size_t)n * kT) * kD + d;
    float acc = 0.f;
#pragma unroll
    for (int k = 0; k < 31; ++k) {
        int tt = t + k - 15;
        if ((unsigned)tt < (unsigned)kT)
            acc += b2f(gp[(size_t)tt * kD]) * dw_w[d * 31 + k];
    }
    acc += dw_b[d];
    acc = acc * bn_g[d] + bn_b[d];
    acc = acc / (1.f + __expf(-acc));
    outb[idx] = f2b(acc);
}

// ================================================================ launch
extern "C" void kernel_launch(void* const* d_in, const int* in_sizes, int n_in,
                              void* d_out, int out_size, void* d_ws, size_t ws_size,
                              hipStream_t stream) {
    const float* x      = (const float*)d_in[0];
    const float* rel_pe = (const float*)d_in[1];
    const float* ln1_g  = (const float*)d_in[2];
    const float* ln1_b  = (const float*)d_in[3];
    const float* ff1_w1 = (const float*)d_in[4];
    const float* ff1_b1 = (const float*)d_in[5];
    const float* ff1_w2 = (const float*)d_in[6];
    const float* ff1_b2 = (const float*)d_in[7];
    const float* an_g   = (const float*)d_in[8];
    const float* an_b   = (const float*)d_in[9];
    const float* wq = (const float*)d_in[10]; const float* bq = (const float*)d_in[11];
    const float* wk = (const float*)d_in[12]; const float* bk = (const float*)d_in[13];
    const float* wv = (const float*)d_in[14]; const float* bv = (const float*)d_in[15];
    const float* wo = (const float*)d_in[16]; const float* bo = (const float*)d_in[17];
    const float* pos_w = (const float*)d_in[18];
    const float* uu = (const float*)d_in[19]; const float* vvp = (const float*)d_in[20];
    const float* cn_g = (const float*)d_in[21]; const float* cn_b = (const float*)d_in[22];
    const float* pe_w = (const float*)d_in[23]; const float* pe_b = (const float*)d_in[24];
    const float* dw_w = (const float*)d_in[25]; const float* dw_b = (const float*)d_in[26];
    const float* bn_g = (const float*)d_in[27]; const float* bn_b = (const float*)d_in[28];
    const float* pc_w = (const float*)d_in[29]; const float* pc_b = (const float*)d_in[30];
    const float* ln2_g = (const float*)d_in[31]; const float* ln2_b = (const float*)d_in[32];
    const float* ff2_w1 = (const float*)d_in[33]; const float* ff2_b1 = (const float*)d_in[34];
    const float* ff2_w2 = (const float*)d_in[35]; const float* ff2_b2 = (const float*)d_in[36];
    const float* fn_g = (const float*)d_in[37]; const float* fn_b = (const float*)d_in[38];
    (void)n_in; (void)in_sizes;

    const int total = kROWS * kD;
    dim3 blk(256);
    const size_t MB = 1ull << 20;
    char* w = (char*)d_ws;

    if (ws_size >= 30 * MB) {
        // ================= FAST PATH (MFMA) =================
        float* xf      = (float*)(w);
        short* ff1_w1t = (short*)(w + 8 * MB);
        short* ff1_w2t = (short*)(w + 10 * MB);
        short* wqt     = (short*)(w + 12 * MB);
        short* wkt     = (short*)(w + 12 * MB + 512 * 1024);
        short* wvt     = (short*)(w + 13 * MB);
        short* wot     = (short*)(w + 13 * MB + 512 * 1024);
        short* poswt   = (short*)(w + 14 * MB);
        short* pewt    = (short*)(w + 14 * MB + 512 * 1024);
        short* pcwt    = (short*)(w + 15 * MB + 512 * 1024);
        short* ff2_w1t = (short*)(w + 16 * MB);
        short* ff2_w2t = (short*)(w + 18 * MB);
        char*  dyn     = w + 20 * MB;
        bf16* hchunk = (bf16*)dyn;
        bf16* Qb     = (bf16*)dyn;
        bf16* Kb     = (bf16*)(dyn + 4 * MB);
        bf16* Rb     = (bf16*)(dyn + 8 * MB);   // attention phase only
        bf16* cbuf   = (bf16*)dyn;
        float* dwt   = (float*)(dyn + 8 * MB);  // conv phase ONLY (aliases Rb!)
        float* beff  = (float*)(dyn + 8 * MB + 256 * 1024);
        bf16* nb     = (bf16*)d_out;                               // lo 4 MB
        bf16* Vtg    = (bf16*)d_out;                               // lo 4 MB (after qkv; nb dead)
        bf16* convb  = (bf16*)d_out;
        bf16* Vb     = (bf16*)d_out + (size_t)kROWS * kD;          // hi 4 MB
        bf16* attnb  = Vb;                                         // hi 4 MB (after vtrans)

        // ---- all weight transposes in ONE launch
        WtArgs wa;
        const float* srcs[11] = {ff1_w1, ff1_w2, wq, wk, wv, wo, pos_w, pe_w, pc_w, ff2_w1, ff2_w2};
        short* dsts[11] = {ff1_w1t, ff1_w2t, wqt, wkt, wvt, wot, poswt, pewt, pcwt, ff2_w1t, ff2_w2t};
        int Ks_[11] = {512, 2048, 512, 512, 512, 512, 512, 512, 512, 512, 2048};
        int Ns_[11] = {2048, 512, 512, 512, 512, 512, 512, 1024, 512, 2048, 512};
        int cum = 0;
        for (int i = 0; i < 11; ++i) {
            wa.d[i].src = srcs[i]; wa.d[i].dst = dsts[i];
            wa.d[i].K = Ks_[i]; wa.d[i].N = Ns_[i]; wa.d[i].tstart = cum;
            cum += (Ns_[i] / 32) * (Ks_[i] / 32);
        }
        wt_all_kernel<<<cum, blk, 0, stream>>>(wa);

        // ---- macaron FF1 (ln reads x; down-proj residual = x, writes xf)
        ln_kernel_v<<<kROWS / 2, blk, 0, stream>>>(x, ln1_g, ln1_b, nb, 0);
        for (int c = 0; c < 2; ++c) {
            size_t off = (size_t)c * 2048 * kD;
            gemm_mfma64<<<dim3(kFFN / 64, 2048 / 64), blk, 0, stream>>>(
                nb + off, ff1_w1t, ff1_b1, nullptr, nullptr, hchunk,
                2048, kFFN, kD, ACT_SILU, 1.f, 0);
            gemm_mfma64<<<dim3(kD / 64, 2048 / 64), blk, 0, stream>>>(
                hchunk, ff1_w2t, ff1_b2, x + off, xf + off, nullptr,
                2048, kD, kFFN, ACT_NONE, 0.5f, 0);
        }

        // ---- RPE attention
        ln_kernel_v<<<kROWS / 2, blk, 0, stream>>>(xf, an_g, an_b, nb, 0);
        gemm_qkv<<<dim3(24, kROWS / 64), blk, 0, stream>>>(
            nb, wqt, bq, bk, bv, Qb, Kb, Vb);
        vtrans_kernel<<<dim3(16, 8, 4), blk, 0, stream>>>(Vb, Vtg);
        gemm_mfma64<<<dim3(kD / 64, (kP + 63) / 64), blk, 0, stream>>>(
            rel_pe, poswt, nullptr, nullptr, nullptr, Rb, kP, kD, kD, ACT_NONE, 1.f, 1);
        attn_mfma<<<dim3(kT / 64, kH, kN), blk, 0, stream>>>(Qb, Kb, Vtg, Rb, uu, vvp, attnb);
        gemm_mfma64<<<dim3(kD / 64, kROWS / 64), blk, 0, stream>>>(
            attnb, wot, bo, xf, xf, nullptr, kROWS, kD, kD, ACT_NONE, 1.f, 0);

        // ---- conv module (dwt MUST run after attention: dwt/beff alias Rb)
        dwt_kernel<<<62, blk, 0, stream>>>(dw_w, dw_b, bn_g, bn_b, dwt, beff);
        ln_kernel_v<<<kROWS / 2, blk, 0, stream>>>(xf, cn_g, cn_b, nb, 0);
        gemm_mfma64<<<dim3(2 * kD / 64, kROWS / 64), blk, 0, stream>>>(
            nb, pewt, pe_b, nullptr, nullptr, cbuf, kROWS, 2 * kD, kD, ACT_NONE, 1.f, 0);
        gluconv_kernel<<<dim3(8, 16, 4), blk, 0, stream>>>(cbuf, dwt, beff, convb);
        gemm_mfma64<<<dim3(kD / 64, kROWS / 64), blk, 0, stream>>>(
            convb, pcwt, pc_b, xf, xf, nullptr, kROWS, kD, kD, ACT_NONE, 1.f, 0);

        // ---- macaron FF2
        ln_kernel_v<<<kROWS / 2, blk, 0, stream>>>(xf, ln2_g, ln2_b, nb, 0);
        for (int c = 0; c < 2; ++c) {
            size_t off = (size_t)c * 2048 * kD;
            gemm_mfma64<<<dim3(kFFN / 64, 2048 / 64), blk, 0, stream>>>(
                nb + off, ff2_w1t, ff2_b1, nullptr, nullptr, hchunk,
                2048, kFFN, kD, ACT_SILU, 1.f, 0);
            gemm_mfma64<<<dim3(kD / 64, 2048 / 64), blk, 0, stream>>>(
                hchunk, ff2_w2t, ff2_b2, xf + off, xf + off, nullptr,
                2048, kD, kFFN, ACT_NONE, 0.5f, 0);
        }

        ln_kernel_v<<<kROWS / 2, blk, 0, stream>>>(xf, fn_g, fn_b, d_out, 1);
        return;
    }

    if (ws_size < 22 * MB) {
        stamp_kernel<<<(out_size + 255) / 256, blk, 0, stream>>>(
            (float*)d_out, out_size, 1000.f + (float)(ws_size / MB));
        return;
    }

    // ================= SLOW PATH (scalar, known-good) =================
    float* xf    = (float*)(w);
    bf16*  hbch  = (bf16*)(w + 8 * MB);
    bf16*  Qb    = (bf16*)(w + 8 * MB);
    bf16*  cbuf  = (bf16*)(w + 8 * MB);
    bf16*  convb = (bf16*)(w + 8 * MB);
    bf16*  Kb    = (bf16*)(w + 12 * MB);
    bf16*  Vb    = (bf16*)(w + 16 * MB);
    bf16*  glub  = (bf16*)(w + 16 * MB);
    bf16*  Rb    = (bf16*)(w + 20 * MB);
    bf16*  nb    = (bf16*)d_out;
    bf16*  attnb = (bf16*)d_out;

    cvt_kernel<<<total / 1024, blk, 0, stream>>>(x, xf, total / 4);

    ln_kernel<<<kROWS, blk, 0, stream>>>(xf, ln1_g, ln1_b, nb, 0);
    for (int c = 0; c < 4; ++c) {
        size_t off = (size_t)c * 1024 * kD;
        gemm_scalar<<<dim3(kFFN / 64, 1024 / 64), blk, 0, stream>>>(
            nb + off, ff1_w1, ff1_b1, nullptr, nullptr, hbch, 1024, kFFN, kD, ACT_SILU, 1.f, 0);
        gemm_scalar<<<dim3(kD / 64, 1024 / 64), blk, 0, stream>>>(
            hbch, ff1_w2, ff1_b2, xf + off, xf + off, nullptr, 1024, kD, kFFN, ACT_NONE, 0.5f, 0);
    }

    ln_kernel<<<kROWS, blk, 0, stream>>>(xf, an_g, an_b, nb, 0);
    gemm_scalar<<<dim3(kD / 64, kROWS / 64), blk, 0, stream>>>(
        nb, wq, bq, nullptr, nullptr, Qb, kROWS, kD, kD, ACT_NONE, 1.f, 0);
    gemm_scalar<<<dim3(kD / 64, kROWS / 64), blk, 0, stream>>>(
        nb, wk, bk, nullptr, nullptr, Kb, kROWS, kD, kD, ACT_NONE, 1.f, 0);
    gemm_scalar<<<dim3(kD / 64, kROWS / 64), blk, 0, stream>>>(
        nb, wv, bv, nullptr, nullptr, Vb, kROWS, kD, kD, ACT_NONE, 1.f, 0);
    gemm_scalar<<<dim3(kD / 64, (kP + 63) / 64), blk, 0, stream>>>(
        rel_pe, pos_w, nullptr, nullptr, nullptr, Rb, kP, kD, kD, ACT_NONE, 1.f, 1);
    attn_kernel<<<dim3(kT / 64, kH, kN), blk, 0, stream>>>(Qb, Kb, Vb, Rb, uu, vvp, attnb);
    gemm_scalar<<<dim3(kD / 64, kROWS / 64), blk, 0, stream>>>(
        attnb, wo, bo, xf, xf, nullptr, kROWS, kD, kD, ACT_NONE, 1.f, 0);

    ln_kernel<<<kROWS, blk, 0, stream>>>(xf, cn_g, cn_b, nb, 0);
    gemm_scalar<<<dim3(2 * kD / 64, kROWS / 64), blk, 0, stream>>>(
        nb, pe_w, pe_b, nullptr, nullptr, cbuf, kROWS, 2 * kD, kD, ACT_NONE, 1.f, 0);
    glu_kernel_v<<<total / 2048, blk, 0, stream>>>(cbuf, glub);
    conv_kernel<<<total / 256, blk, 0, stream>>>(glub, dw_w, dw_b, bn_g, bn_b, convb);
    gemm_scalar<<<dim3(kD / 64, kROWS / 64), blk, 0, stream>>>(
        convb, pc_w, pc_b, xf, xf, nullptr, kROWS, kD, kD, ACT_NONE, 1.f, 0);

    ln_kernel<<<kROWS, blk, 0, stream>>>(xf, ln2_g, ln2_b, nb, 0);
    for (int c = 0; c < 4; ++c) {
        size_t off = (size_t)c * 1024 * kD;
        gemm_scalar<<<dim3(kFFN / 64, 1024 / 64), blk, 0, stream>>>(
            nb + off, ff2_w1, ff2_b1, nullptr, nullptr, hbch, 1024, kFFN, kD, ACT_SILU, 1.f, 0);
        gemm_scalar<<<dim3(kD / 64, 1024 / 64), blk, 0, stream>>>(
            hbch, ff2_w2, ff2_b2, xf + off, xf + off, nullptr, 1024, kD, kFFN, ACT_NONE, 0.5f, 0);
    }

    ln_kernel<<<kROWS, blk, 0, stream>>>(xf, fn_g, fn_b, d_out, 1);
}

// Round 14
// 484.497 us; speedup vs baseline: 1.0716x; 1.0231x over previous
//
#include <hip/hip_runtime.h>
#include <hip/hip_bf16.h>

using bf16 = __hip_bfloat16;
typedef __attribute__((ext_vector_type(8))) short short8;
typedef __attribute__((ext_vector_type(4))) short short4v;
typedef __attribute__((ext_vector_type(4))) float f32x4;

static __device__ __forceinline__ float b2f(bf16 v) { return __bfloat162float(v); }
static __device__ __forceinline__ bf16  f2b(float v) { return __float2bfloat16(v); }
static __device__ __forceinline__ short f2bs(float x) {
    union { float f; unsigned u; } c; c.f = x;
    unsigned r = (c.u + 0x7FFFu + ((c.u >> 16) & 1u)) >> 16;
    return (short)r;
}
static __device__ __forceinline__ float bs2f(short s) {
    union { unsigned u; float f; } c; c.u = ((unsigned)(unsigned short)s) << 16;
    return c.f;
}
// async global->LDS, 16B per lane; LDS dst = wave-uniform base + lane*16
static __device__ __forceinline__ void gload16(const short* g, short* l) {
    __builtin_amdgcn_global_load_lds(
        (const __attribute__((address_space(1))) void*)g,
        (__attribute__((address_space(3))) void*)l, 16, 0, 0);
}

constexpr int kD   = 512;
constexpr int kT   = 1024;
constexpr int kN   = 4;
constexpr int kH   = 8;
constexpr int kDH  = 64;
constexpr int kFFN = 2048;
constexpr int kROWS = kN * kT;        // 4096
constexpr int kP    = 2 * kT - 1;     // 2047

#define ACT_NONE 0
#define ACT_SILU 1

// ---------------------------------------------------------------- fallback stamp
__global__ __launch_bounds__(256) void stamp_kernel(float* __restrict__ out, int n, float val) {
    int i = blockIdx.x * 256 + threadIdx.x;
    if (i < n) out[i] = (i == 0 ? val : 0.f);
}

// ---------------------------------------------------------------- copy (slow path only)
__global__ __launch_bounds__(256) void cvt_kernel(const float* __restrict__ in,
                                                  float* __restrict__ out, int n4) {
    int i = blockIdx.x * 256 + threadIdx.x;
    if (i < n4) ((f32x4*)out)[i] = ((const f32x4*)in)[i];
}

// ---------------------------------------------------------------- fused weight transpose
struct WtDesc { const float* src; short* dst; int K; int N; int tstart; };
struct WtArgs { WtDesc d[11]; };

__global__ __launch_bounds__(256) void wt_all_kernel(WtArgs a) {
    __shared__ float t[32][33];
    int bid = blockIdx.x;
    int i = 0;
#pragma unroll
    for (int j = 1; j < 11; ++j) if (bid >= a.d[j].tstart) i = j;
    const float* W = a.d[i].src;
    short* Wt = a.d[i].dst;
    int Kd = a.d[i].K, Nd = a.d[i].N;
    int lt = bid - a.d[i].tstart;
    int nx = Nd >> 5;
    int n0 = (lt % nx) * 32, k0 = (lt / nx) * 32;
    int tx = threadIdx.x & 31, ty = threadIdx.x >> 5;
#pragma unroll
    for (int it = 0; it < 4; ++it)
        t[ty + it * 8][tx] = W[(size_t)(k0 + ty + it * 8) * Nd + n0 + tx];
    __syncthreads();
#pragma unroll
    for (int it = 0; it < 4; ++it)
        Wt[(size_t)(n0 + ty + it * 8) * Kd + k0 + tx] = f2bs(t[tx][ty + it * 8]);
}

// ---------------------------------------------------------------- V transpose per (n,h)
__global__ __launch_bounds__(256) void vtrans_kernel(const bf16* __restrict__ V,
                                                     bf16* __restrict__ Vt) {
    __shared__ short ts[64][72];
    int tt = blockIdx.x, h = blockIdx.y, n = blockIdx.z;
    int tid = threadIdx.x;
    int r = tid >> 3, cg = (tid & 7) * 8;
#pragma unroll
    for (int it = 0; it < 2; ++it) {
        int row = it * 32 + r;
        *(short8*)&ts[row][cg] =
            *(const short8*)((const short*)V + ((size_t)n * kT + tt * 64 + row) * 512 + h * 64 + cg);
    }
    __syncthreads();
#pragma unroll
    for (int it = 0; it < 2; ++it) {
        int d = it * 32 + r;
        short8 o;
#pragma unroll
        for (int i = 0; i < 8; ++i) o[i] = ts[cg + i][d];
        *(short8*)((short*)Vt + ((size_t)(n * 8 + h) * 64 + d) * 1024 + tt * 64 + cg) = o;
    }
}

// ---------------------------------------------------------------- depthwise weight prep (fold BN)
__global__ __launch_bounds__(256) void dwt_kernel(const float* __restrict__ dw_w,
                                                  const float* __restrict__ dw_b,
                                                  const float* __restrict__ bn_g,
                                                  const float* __restrict__ bn_b,
                                                  float* __restrict__ wt,
                                                  float* __restrict__ beff) {
    int idx = blockIdx.x * 256 + threadIdx.x;
    if (idx < 31 * kD) {
        int d = idx & 511, k = idx >> 9;
        wt[k * kD + d] = dw_w[d * 31 + k] * bn_g[d];
    }
    if (idx < kD) beff[idx] = dw_b[idx] * bn_g[idx] + bn_b[idx];
}

// ---------------------------------------------------------------- layernorm, vectorized
__global__ __launch_bounds__(256) void ln_kernel_v(const float* __restrict__ xin,
                                                   const float* __restrict__ g,
                                                   const float* __restrict__ b,
                                                   void* __restrict__ outp, int out_f32) {
    int tid = threadIdx.x;
    int rh = tid >> 7;
    int tl = tid & 127;
    int row = blockIdx.x * 2 + rh;
    const float* xr = xin + (size_t)row * kD;
    f32x4 v = *(const f32x4*)(xr + tl * 4);
    float s  = v[0] + v[1] + v[2] + v[3];
    float sq = v[0]*v[0] + v[1]*v[1] + v[2]*v[2] + v[3]*v[3];
    for (int off = 32; off; off >>= 1) {
        s  += __shfl_down(s, off);
        sq += __shfl_down(sq, off);
    }
    __shared__ float ss[4], ssq[4], mean_s[2], rstd_s[2];
    int wid = tid >> 6;
    if ((tid & 63) == 0) { ss[wid] = s; ssq[wid] = sq; }
    __syncthreads();
    if (tid < 2) {
        float S  = ss[tid * 2] + ss[tid * 2 + 1];
        float SQ = ssq[tid * 2] + ssq[tid * 2 + 1];
        float m = S / (float)kD;
        float var = SQ / (float)kD - m * m;
        mean_s[tid] = m;
        rstd_s[tid] = rsqrtf(fmaxf(var, 0.f) + 1e-5f);
    }
    __syncthreads();
    float m = mean_s[rh], rs = rstd_s[rh];
    f32x4 gg = *(const f32x4*)(g + tl * 4);
    f32x4 bb = *(const f32x4*)(b + tl * 4);
    if (out_f32) {
        f32x4 o;
#pragma unroll
        for (int i = 0; i < 4; ++i) o[i] = (v[i] - m) * rs * gg[i] + bb[i];
        *(f32x4*)((float*)outp + (size_t)row * kD + tl * 4) = o;
    } else {
        short4v o;
#pragma unroll
        for (int i = 0; i < 4; ++i) o[i] = f2bs((v[i] - m) * rs * gg[i] + bb[i]);
        *(short4v*)((short*)outp + (size_t)row * kD + tl * 4) = o;
    }
}

// ---------------------------------------------------------------- layernorm (slow path)
__global__ __launch_bounds__(256) void ln_kernel(const float* __restrict__ xin,
                                                 const float* __restrict__ g,
                                                 const float* __restrict__ b,
                                                 void* __restrict__ outp, int out_f32) {
    int row = blockIdx.x;
    const float* xr = xin + (size_t)row * kD;
    int tid = threadIdx.x;
    float v0 = xr[tid], v1 = xr[tid + 256];
    float s = v0 + v1, sq = v0 * v0 + v1 * v1;
    for (int off = 32; off; off >>= 1) {
        s  += __shfl_down(s, off);
        sq += __shfl_down(sq, off);
    }
    __shared__ float ss[4], ssq[4];
    __shared__ float mean_s, rstd_s;
    int wid = tid >> 6, lane = tid & 63;
    if (lane == 0) { ss[wid] = s; ssq[wid] = sq; }
    __syncthreads();
    if (tid == 0) {
        float S  = ss[0] + ss[1] + ss[2] + ss[3];
        float SQ = ssq[0] + ssq[1] + ssq[2] + ssq[3];
        float m = S / (float)kD;
        float var = SQ / (float)kD - m * m;
        mean_s = m;
        rstd_s = rsqrtf(fmaxf(var, 0.f) + 1e-5f);
    }
    __syncthreads();
    float m = mean_s, rs = rstd_s;
    float o0 = (v0 - m) * rs * g[tid]       + b[tid];
    float o1 = (v1 - m) * rs * g[tid + 256] + b[tid + 256];
    size_t i0 = (size_t)row * kD + tid, i1 = i0 + 256;
    if (out_f32) {
        ((float*)outp)[i0] = o0; ((float*)outp)[i1] = o1;
    } else {
        ((bf16*)outp)[i0] = f2b(o0); ((bf16*)outp)[i1] = f2b(o1);
    }
}

// ---------------------------------------------------------------- MFMA GEMM, 64x64 tile (dbuf async)
__global__ __launch_bounds__(256, 4) void gemm_mfma64(
    const void* __restrict__ A, const short* __restrict__ Bt,
    const float* __restrict__ bias, const float* __restrict__ residual,
    float* __restrict__ outf, bf16* __restrict__ outb,
    int M, int N, int K, int act, float scale, int a_f32) {
    __shared__ short As[2][4096];
    __shared__ short Bs[2][4096];
    int tid = threadIdx.x;
    int m0 = blockIdx.y * 64, n0 = blockIdx.x * 64;
    int wid = tid >> 6, lane = tid & 63;
    int wm = (wid >> 1) * 32, wn = (wid & 1) * 32;
    int q = lane >> 4, c16 = lane & 15;

    f32x4 zero4 = {0.f, 0.f, 0.f, 0.f};
    f32x4 acc[2][2] = {{zero4, zero4}, {zero4, zero4}};

    int arow = lane >> 3;
    int aseg = (lane & 7) ^ arow;

    auto issueA = [&](int buf, int k0) {
        if (!a_f32) {
#pragma unroll
            for (int it = 0; it < 2; ++it) {
                int rbase = (wid * 2 + it) * 8;
                gload16((const short*)A + (size_t)(m0 + rbase + arow) * K + k0 + aseg * 8,
                        &As[buf][(wid * 2 + it) * 512]);
            }
        } else {
            int srow = tid >> 3, sseg = tid & 7;
#pragma unroll
            for (int it = 0; it < 2; ++it) {
                int row = it * 32 + srow;
                int rr = m0 + row;
                short8 v = {0, 0, 0, 0, 0, 0, 0, 0};
                if (rr < M) {
                    const float* ap = (const float*)A + (size_t)rr * K + k0 + sseg * 8;
                    f32x4 x0 = *(const f32x4*)ap;
                    f32x4 x1 = *(const f32x4*)(ap + 4);
                    v[0] = f2bs(x0[0]); v[1] = f2bs(x0[1]); v[2] = f2bs(x0[2]); v[3] = f2bs(x0[3]);
                    v[4] = f2bs(x1[0]); v[5] = f2bs(x1[1]); v[6] = f2bs(x1[2]); v[7] = f2bs(x1[3]);
                }
                *(short8*)&As[buf][(row * 8 + (sseg ^ (row & 7))) * 8] = v;
            }
        }
    };
    auto issueB = [&](int buf, int k0) {
#pragma unroll
        for (int it = 0; it < 2; ++it) {
            int rbase = (wid * 2 + it) * 8;
            gload16(Bt + (size_t)(n0 + rbase + arow) * K + k0 + aseg * 8,
                    &Bs[buf][(wid * 2 + it) * 512]);
        }
    };

    issueA(0, 0);
    issueB(0, 0);
    int cur = 0;
    for (int k0 = 0; k0 < K; k0 += 64) {
        __syncthreads();
        if (k0 + 64 < K) {
            issueA(cur ^ 1, k0 + 64);
            issueB(cur ^ 1, k0 + 64);
        }
#pragma unroll
        for (int ks = 0; ks < 2; ++ks) {
            int p = c16 & 7;
            short8 af[2], bfr[2];
#pragma unroll
            for (int mt = 0; mt < 2; ++mt) {
                int row = wm + mt * 16 + c16;
                af[mt] = *(const short8*)&As[cur][(row * 8 + ((ks * 4 + q) ^ p)) * 8];
            }
#pragma unroll
            for (int nt = 0; nt < 2; ++nt) {
                int row = wn + nt * 16 + c16;
                bfr[nt] = *(const short8*)&Bs[cur][(row * 8 + ((ks * 4 + q) ^ p)) * 8];
            }
#pragma unroll
            for (int mt = 0; mt < 2; ++mt)
#pragma unroll
                for (int nt = 0; nt < 2; ++nt)
                    acc[mt][nt] = __builtin_amdgcn_mfma_f32_16x16x32_bf16(
                        af[mt], bfr[nt], acc[mt][nt], 0, 0, 0);
        }
        cur ^= 1;
    }
#pragma unroll
    for (int mt = 0; mt < 2; ++mt) {
#pragma unroll
        for (int reg = 0; reg < 4; ++reg) {
            int r = m0 + wm + mt * 16 + q * 4 + reg;
            if (r >= M) continue;
#pragma unroll
            for (int nt = 0; nt < 2; ++nt) {
                int c = n0 + wn + nt * 16 + c16;
                float h = acc[mt][nt][reg];
                if (bias) h += bias[c];
                if (act == ACT_SILU) h = h / (1.f + __expf(-h));
                h *= scale;
                size_t idx = (size_t)r * N + c;
                if (residual) h += residual[idx];
                if (outf) outf[idx] = h;
                if (outb) outb[idx] = f2b(h);
            }
        }
    }
}

// ---------------------------------------------------------------- fused QKV GEMM (dbuf async)
__global__ __launch_bounds__(256, 4) void gemm_qkv(
    const bf16* __restrict__ A, const short* __restrict__ Bt,
    const float* __restrict__ bq, const float* __restrict__ bk,
    const float* __restrict__ bv,
    bf16* __restrict__ Qb, bf16* __restrict__ Kb, bf16* __restrict__ Vb) {
    const int K = kD;
    __shared__ short As[2][4096];
    __shared__ short Bs[2][4096];
    int tid = threadIdx.x;
    int m0 = blockIdx.y * 64, n0 = blockIdx.x * 64;
    int seg = blockIdx.x >> 3;
    const float* bias = seg == 0 ? bq : (seg == 1 ? bk : bv);
    bf16* outb = seg == 0 ? Qb : (seg == 1 ? Kb : Vb);
    int ns0 = n0 & 511;
    int wid = tid >> 6, lane = tid & 63;
    int wm = (wid >> 1) * 32, wn = (wid & 1) * 32;
    int q = lane >> 4, c16 = lane & 15;

    f32x4 zero4 = {0.f, 0.f, 0.f, 0.f};
    f32x4 acc[2][2] = {{zero4, zero4}, {zero4, zero4}};
    int arow = lane >> 3;
    int aseg = (lane & 7) ^ arow;

    auto issue = [&](int buf, int k0) {
#pragma unroll
        for (int it = 0; it < 2; ++it) {
            int rbase = (wid * 2 + it) * 8;
            gload16((const short*)A + (size_t)(m0 + rbase + arow) * K + k0 + aseg * 8,
                    &As[buf][(wid * 2 + it) * 512]);
            gload16(Bt + (size_t)(n0 + rbase + arow) * K + k0 + aseg * 8,
                    &Bs[buf][(wid * 2 + it) * 512]);
        }
    };

    issue(0, 0);
    int cur = 0;
    for (int k0 = 0; k0 < K; k0 += 64) {
        __syncthreads();
        if (k0 + 64 < K) issue(cur ^ 1, k0 + 64);
#pragma unroll
        for (int ks = 0; ks < 2; ++ks) {
            int p = c16 & 7;
            short8 af[2], bfr[2];
#pragma unroll
            for (int mt = 0; mt < 2; ++mt) {
                int row = wm + mt * 16 + c16;
                af[mt] = *(const short8*)&As[cur][(row * 8 + ((ks * 4 + q) ^ p)) * 8];
            }
#pragma unroll
            for (int nt = 0; nt < 2; ++nt) {
                int row = wn + nt * 16 + c16;
                bfr[nt] = *(const short8*)&Bs[cur][(row * 8 + ((ks * 4 + q) ^ p)) * 8];
            }
#pragma unroll
            for (int mt = 0; mt < 2; ++mt)
#pragma unroll
                for (int nt = 0; nt < 2; ++nt)
                    acc[mt][nt] = __builtin_amdgcn_mfma_f32_16x16x32_bf16(
                        af[mt], bfr[nt], acc[mt][nt], 0, 0, 0);
        }
        cur ^= 1;
    }
#pragma unroll
    for (int mt = 0; mt < 2; ++mt)
#pragma unroll
        for (int reg = 0; reg < 4; ++reg) {
            int r = m0 + wm + mt * 16 + q * 4 + reg;
#pragma unroll
            for (int nt = 0; nt < 2; ++nt) {
                int c = ns0 + wn + nt * 16 + c16;
                outb[(size_t)r * 512 + c] = f2b(acc[mt][nt][reg] + bias[c]);
            }
        }
}

// ---------------------------------------------------------------- scalar GEMM (slow fallback)
__global__ __launch_bounds__(256) void gemm_scalar(
    const void* __restrict__ A, const float* __restrict__ W,
    const float* __restrict__ bias, const float* __restrict__ residual,
    float* __restrict__ outf, bf16* __restrict__ outb,
    int M, int N, int K, int act, float scale, int a_f32) {
    __shared__ float As[16][65];
    __shared__ float Bs[16][65];
    int tid = threadIdx.x;
    int tx = tid & 15, ty = tid >> 4;
    int row0 = blockIdx.y * 64, col0 = blockIdx.x * 64;
    float acc[4][4] = {};
    for (int k0 = 0; k0 < K; k0 += 16) {
        for (int i = tid; i < 64 * 16; i += 256) {
            int r = i >> 4, c = i & 15;
            int rr = row0 + r;
            float v = 0.f;
            if (rr < M) {
                size_t idx = (size_t)rr * K + k0 + c;
                v = a_f32 ? ((const float*)A)[idx] : b2f(((const bf16*)A)[idx]);
            }
            As[c][r] = v;
        }
        for (int i = tid; i < 16 * 64; i += 256) {
            int r = i >> 6, c = i & 63;
            Bs[r][c] = W[(size_t)(k0 + r) * N + col0 + c];
        }
        __syncthreads();
#pragma unroll
        for (int kk = 0; kk < 16; ++kk) {
            float a[4], b[4];
#pragma unroll
            for (int i = 0; i < 4; ++i) a[i] = As[kk][ty * 4 + i];
#pragma unroll
            for (int j = 0; j < 4; ++j) b[j] = Bs[kk][tx * 4 + j];
#pragma unroll
            for (int i = 0; i < 4; ++i)
#pragma unroll
                for (int j = 0; j < 4; ++j) acc[i][j] += a[i] * b[j];
        }
        __syncthreads();
    }
#pragma unroll
    for (int i = 0; i < 4; ++i) {
        int r = row0 + ty * 4 + i;
        if (r >= M) continue;
#pragma unroll
        for (int j = 0; j < 4; ++j) {
            int c = col0 + tx * 4 + j;
            float h = acc[i][j];
            if (bias) h += bias[c];
            if (act == ACT_SILU) h = h / (1.f + __expf(-h));
            h *= scale;
            size_t idx = (size_t)r * N + c;
            if (residual) h += residual[idx];
            if (outf) outf[idx] = h;
            if (outb) outb[idx] = f2b(h);
        }
    }
}

// ---------------------------------------------------------------- MFMA RPE attention (LDS diet)
// Q(+u)/Q(+v) fragments live in registers (fixed across kt). K/Vt/R staged via
// async gload16 into XOR-swizzled unpadded tiles. Bp trimmed to wave-local j
// window (width 88, 16B-aligned rows). LDS 43 KB -> 3 blocks/CU.
__global__ __launch_bounds__(256, 3) void attn_mfma(
    const bf16* __restrict__ Qg, const bf16* __restrict__ Kg,
    const bf16* __restrict__ Vtg, const bf16* __restrict__ Rg,
    const float* __restrict__ uu, const float* __restrict__ vvp,
    bf16* __restrict__ outb) {
    __shared__ short KsL[4096];    // 64x64 swizzled
    __shared__ short VtL[4096];    // 64x64 swizzled
    __shared__ short RwL[8192];    // 128x64 swizzled
    __shared__ short Bp[64][88];   // Braw (cols 0..79 = j-wm), then P (cols 0..63)

    int tid = threadIdx.x;
    int qb = blockIdx.x, h = blockIdx.y, n = blockIdx.z;
    int t0 = qb * 64;
    size_t baseq = ((size_t)n * kT) * 512 + (size_t)h * kDH;
    size_t basev = ((size_t)(n * 8 + h) * 64) * 1024;
    size_t baseo = ((size_t)n * kT) * kD + (size_t)h * kDH;

    int wid = tid >> 6, lane = tid & 63;
    int q = lane >> 4, c16 = lane & 15;
    int wm = wid * 16;
    int trow = wm + q * 4;

    // ---- Q fragments with u,v folded, in registers (constant across kt)
    short8 qu[2], qvv[2];
    {
        const short* qp = (const short*)Qg + baseq + (size_t)(t0 + wm + c16) * 512;
#pragma unroll
        for (int ks = 0; ks < 2; ++ks) {
            short8 q8 = *(const short8*)(qp + ks * 32 + q * 8);
            const float* up = uu + h * 64 + ks * 32 + q * 8;
            const float* vp = vvp + h * 64 + ks * 32 + q * 8;
#pragma unroll
            for (int i = 0; i < 8; ++i) {
                float xq = bs2f(q8[i]);
                qu[ks][i]  = f2bs(xq + up[i]);
                qvv[ks][i] = f2bs(xq + vp[i]);
            }
        }
    }

    int arow = lane >> 3;
    int aseg = (lane & 7) ^ arow;

    f32x4 zero4 = {0.f, 0.f, 0.f, 0.f};
    f32x4 acc_o[4] = {zero4, zero4, zero4, zero4};
    float m_i[4] = {-1e30f, -1e30f, -1e30f, -1e30f};
    float l_i[4] = {0.f, 0.f, 0.f, 0.f};

    for (int kt = 0; kt < 16; ++kt) {
        int s0 = kt * 64;
        __syncthreads();   // prev iter's LDS reads done
        // ---- async staging: K (2/wave), Vt (2/wave), R (4/wave)
#pragma unroll
        for (int it = 0; it < 2; ++it) {
            int g = wid * 2 + it;    // group 0..7, rows g*8+arow
            gload16((const short*)Kg + baseq + (size_t)(s0 + g * 8 + arow) * 512 + aseg * 8,
                    KsL + g * 512);
            gload16((const short*)Vtg + basev + (size_t)(g * 8 + arow) * 1024 + s0 + aseg * 8,
                    VtL + g * 512);
        }
        int p_base = t0 - s0 + 960;
#pragma unroll
        for (int it = 0; it < 4; ++it) {
            int g = wid * 4 + it;    // group 0..15
            int j = g * 8 + arow;
            int p = p_base + j;
            p = p < 0 ? 0 : (p > 2046 ? 2046 : p);
            gload16((const short*)Rg + (size_t)p * kD + h * kDH + aseg * 8,
                    RwL + g * 512);
        }
        __syncthreads();   // drain

        // ---- MFMA: S_qk = Qu K^T (4), Braw = Qv Rw^T (5, B-trim), per ks
        f32x4 acc_s[4] = {zero4, zero4, zero4, zero4};
        f32x4 acc_b[5] = {zero4, zero4, zero4, zero4, zero4};
#pragma unroll
        for (int ks = 0; ks < 2; ++ks) {
            int pq = c16 & 7;
#pragma unroll
            for (int nt = 0; nt < 4; ++nt) {
                int row = nt * 16 + c16;
                short8 bk_ = *(const short8*)&KsL[(row * 8 + ((ks * 4 + q) ^ pq)) * 8];
                acc_s[nt] = __builtin_amdgcn_mfma_f32_16x16x32_bf16(qu[ks], bk_, acc_s[nt], 0, 0, 0);
            }
#pragma unroll
            for (int jt = 0; jt < 5; ++jt) {
                int row = wm + jt * 16 + c16;
                short8 br_ = *(const short8*)&RwL[(row * 8 + ((ks * 4 + q) ^ pq)) * 8];
                acc_b[jt] = __builtin_amdgcn_mfma_f32_16x16x32_bf16(qvv[ks], br_, acc_b[jt], 0, 0, 0);
            }
        }
        // ---- store Braw at col j-wm (wave-private rows; no barrier)
#pragma unroll
        for (int jt = 0; jt < 5; ++jt)
#pragma unroll
            for (int reg = 0; reg < 4; ++reg)
                Bp[trow + reg][jt * 16 + c16] = f2bs(acc_b[jt][reg]);

        // ---- rel-shift gather + online softmax
        float pmat[4][4];
        float alpha[4];
#pragma unroll
        for (int reg = 0; reg < 4; ++reg) {
            int t = trow + reg;
            float mrow = -1e30f;
#pragma unroll
            for (int nt = 0; nt < 4; ++nt) {
                int s = nt * 16 + c16;
                int jc = t - s + 63 - wm;   // [0,78]
                float sv = (acc_s[nt][reg] + bs2f(Bp[t][jc])) * 0.125f;
                pmat[nt][reg] = sv;
                mrow = fmaxf(mrow, sv);
            }
            mrow = fmaxf(mrow, __shfl_xor(mrow, 1));
            mrow = fmaxf(mrow, __shfl_xor(mrow, 2));
            mrow = fmaxf(mrow, __shfl_xor(mrow, 4));
            mrow = fmaxf(mrow, __shfl_xor(mrow, 8));
            float m_new = fmaxf(m_i[reg], mrow);
            alpha[reg] = __expf(m_i[reg] - m_new);
            float ps = 0.f;
#pragma unroll
            for (int nt = 0; nt < 4; ++nt) {
                float pe = __expf(pmat[nt][reg] - m_new);
                pmat[nt][reg] = pe;
                ps += pe;
            }
            ps += __shfl_xor(ps, 1);
            ps += __shfl_xor(ps, 2);
            ps += __shfl_xor(ps, 4);
            ps += __shfl_xor(ps, 8);
            l_i[reg] = l_i[reg] * alpha[reg] + ps;
            m_i[reg] = m_new;
        }
        // ---- write P over Bp cols 0..63 (gathers complete: wave-lockstep)
#pragma unroll
        for (int nt = 0; nt < 4; ++nt)
#pragma unroll
            for (int reg = 0; reg < 4; ++reg)
                Bp[trow + reg][nt * 16 + c16] = f2bs(pmat[nt][reg]);
#pragma unroll
        for (int dt = 0; dt < 4; ++dt)
#pragma unroll
            for (int reg = 0; reg < 4; ++reg)
                acc_o[dt][reg] *= alpha[reg];
        // ---- PV (P rows wave-private; Vt block-shared)
#pragma unroll
        for (int ks = 0; ks < 2; ++ks) {
            int pq = c16 & 7;
            short8 ap = *(const short8*)&Bp[wm + c16][ks * 32 + q * 8];
#pragma unroll
            for (int dt = 0; dt < 4; ++dt) {
                int row = dt * 16 + c16;
                short8 bv_ = *(const short8*)&VtL[(row * 8 + ((ks * 4 + q) ^ pq)) * 8];
                acc_o[dt] = __builtin_amdgcn_mfma_f32_16x16x32_bf16(ap, bv_, acc_o[dt], 0, 0, 0);
            }
        }
    }
#pragma unroll
    for (int reg = 0; reg < 4; ++reg) {
        float inv = 1.f / l_i[reg];
        int t = trow + reg;
#pragma unroll
        for (int dt = 0; dt < 4; ++dt)
            outb[baseo + (size_t)(t0 + t) * kD + dt * 16 + c16] = f2b(acc_o[dt][reg] * inv);
    }
}

// ---------------------------------------------------------------- scalar attention (slow path)
__global__ __launch_bounds__(256) void attn_kernel(
    const bf16* __restrict__ Qg, const bf16* __restrict__ Kg,
    const bf16* __restrict__ Vg, const bf16* __restrict__ Rg,
    const float* __restrict__ uu, const float* __restrict__ vvp,
    bf16* __restrict__ outb) {
    __shared__ float Qs[64][65];
    __shared__ bf16 Ps[64][66];
    __shared__ bf16 Ks[64][66];
    __shared__ bf16 Vs[64][66];
    __shared__ bf16 Rs[127][66];
    __shared__ float uf[64], vf[64];
    __shared__ float uK[64], vR[127];

    int tid = threadIdx.x;
    int qb = blockIdx.x, h = blockIdx.y, n = blockIdx.z;
    int t0 = qb * 64;
    size_t base = ((size_t)n * kT) * kD + (size_t)h * kDH;

    if (tid < 64) {
        uf[tid] = uu[h * 64 + tid];
        vf[tid] = vvp[h * 64 + tid];
    }
    for (int i = tid; i < 64 * 64; i += 256) {
        int r = i >> 6, d = i & 63;
        Qs[r][d] = b2f(Qg[base + (size_t)(t0 + r) * kD + d]);
    }
    int r = tid >> 2, seg = tid & 3;
    float m_i = -1e30f, l_i = 0.f;
    float Oa[16];
#pragma unroll
    for (int i = 0; i < 16; ++i) Oa[i] = 0.f;

    for (int kt = 0; kt < 16; ++kt) {
        int s0 = kt * 64;
        __syncthreads();
        for (int i = tid; i < 64 * 64; i += 256) {
            int s = i >> 6, d = i & 63;
            Ks[s][d] = Kg[base + (size_t)(s0 + s) * kD + d];
            Vs[s][d] = Vg[base + (size_t)(s0 + s) * kD + d];
        }
        int p_base = t0 - s0 + 960;
        for (int i = tid; i < 127 * 64; i += 256) {
            int j = i >> 6, d = i & 63;
            int p = p_base + j;
            p = p < 0 ? 0 : (p > 2046 ? 2046 : p);
            Rs[j][d] = Rg[(size_t)p * kD + h * kDH + d];
        }
        __syncthreads();
        if (tid < 64) {
            float s_ = 0.f;
            for (int d = 0; d < 64; ++d) s_ += uf[d] * b2f(Ks[tid][d]);
            uK[tid] = s_;
        } else if (tid < 64 + 127) {
            int j = tid - 64;
            float s_ = 0.f;
            for (int d = 0; d < 64; ++d) s_ += vf[d] * b2f(Rs[j][d]);
            vR[j] = s_;
        }
        __syncthreads();
        float sv[16];
        float smax = -1e30f;
#pragma unroll
        for (int jj = 0; jj < 16; ++jj) {
            int s = seg * 16 + jj;
            int j = r - s + 63;
            float acc = 0.f;
            for (int d = 0; d < 64; ++d)
                acc += Qs[r][d] * (b2f(Ks[s][d]) + b2f(Rs[j][d]));
            acc = (acc + uK[s] + vR[j]) * 0.125f;
            sv[jj] = acc;
            smax = fmaxf(smax, acc);
        }
        smax = fmaxf(smax, __shfl_xor(smax, 1));
        smax = fmaxf(smax, __shfl_xor(smax, 2));
        float m_new = fmaxf(m_i, smax);
        float alpha = __expf(m_i - m_new);
        float psum = 0.f;
#pragma unroll
        for (int jj = 0; jj < 16; ++jj) {
            float p = __expf(sv[jj] - m_new);
            Ps[r][seg * 16 + jj] = f2b(p);
            psum += p;
        }
        psum += __shfl_xor(psum, 1);
        psum += __shfl_xor(psum, 2);
        l_i = l_i * alpha + psum;
        m_i = m_new;
#pragma unroll
        for (int i = 0; i < 16; ++i) Oa[i] *= alpha;
        __syncthreads();
        for (int s = 0; s < 64; ++s) {
            float p = b2f(Ps[r][s]);
#pragma unroll
            for (int dd = 0; dd < 16; ++dd)
                Oa[dd] += p * b2f(Vs[s][seg * 16 + dd]);
        }
    }
    float inv = 1.f / l_i;
#pragma unroll
    for (int dd = 0; dd < 16; ++dd)
        outb[base + (size_t)(t0 + r) * kD + seg * 16 + dd] = f2b(Oa[dd] * inv);
}

// ---------------------------------------------------------------- GLU (slow path)
__global__ __launch_bounds__(256) void glu_kernel_v(const bf16* __restrict__ c,
                                                    bf16* __restrict__ out) {
    int i8 = (blockIdx.x * 256 + threadIdx.x) * 8;
    int row = i8 >> 9, d = i8 & 511;
    const short* cp = (const short*)c + (size_t)row * 1024;
    short8 a8 = *(const short8*)(cp + d);
    short8 g8 = *(const short8*)(cp + 512 + d);
    short8 o;
#pragma unroll
    for (int i = 0; i < 8; ++i) {
        float a = bs2f(a8[i]), g = bs2f(g8[i]);
        o[i] = f2bs(a / (1.f + __expf(-g)));
    }
    *(short8*)((short*)out + i8) = o;
}

// ---------------------------------------------------------------- fused GLU + depthwise conv + BN + SiLU
__global__ __launch_bounds__(256) void gluconv_kernel(
    const bf16* __restrict__ cbuf, const float* __restrict__ wt,
    const float* __restrict__ beff, bf16* __restrict__ outb) {
    __shared__ short gsm[94][72];
    __shared__ float wsm[31][64];
    __shared__ float bsm[64];
    int tid = threadIdx.x;
    int dg0 = blockIdx.x * 64;
    int t0  = blockIdx.y * 64;
    int n   = blockIdx.z;

#pragma unroll
    for (int it = 0; it < 3; ++it) {
        int idx = tid + it * 256;
        if (idx < 94 * 8) {
            int row = idx >> 3, cg = (idx & 7) * 8;
            int t = t0 - 15 + row;
            short8 o = {0, 0, 0, 0, 0, 0, 0, 0};
            if ((unsigned)t < (unsigned)kT) {
                const short* cp = (const short*)cbuf + ((size_t)n * kT + t) * 1024 + dg0 + cg;
                short8 a8 = *(const short8*)cp;
                short8 g8 = *(const short8*)(cp + 512);
#pragma unroll
                for (int i = 0; i < 8; ++i)
                    o[i] = f2bs(bs2f(a8[i]) / (1.f + __expf(-bs2f(g8[i]))));
            }
            *(short8*)&gsm[row][cg] = o;
        }
    }
#pragma unroll
    for (int it = 0; it < 8; ++it) {
        int i = tid + it * 256;
        if (i < 31 * 64) wsm[i >> 6][i & 63] = wt[(i >> 6) * kD + dg0 + (i & 63)];
    }
    if (tid < 64) bsm[tid] = beff[dg0 + tid];
    __syncthreads();

    int tl = tid >> 2, dgl = (tid & 3) * 16;
    float acc[16] = {};
#pragma unroll
    for (int k = 0; k < 31; ++k) {
        short8 g0 = *(const short8*)&gsm[tl + k][dgl];
        short8 g1 = *(const short8*)&gsm[tl + k][dgl + 8];
#pragma unroll
        for (int i = 0; i < 8; ++i) {
            acc[i]     += bs2f(g0[i]) * wsm[k][dgl + i];
            acc[8 + i] += bs2f(g1[i]) * wsm[k][dgl + 8 + i];
        }
    }
    short8 o0, o1;
#pragma unroll
    for (int i = 0; i < 8; ++i) {
        float h = acc[i] + bsm[dgl + i];
        o0[i] = f2bs(h / (1.f + __expf(-h)));
        h = acc[8 + i] + bsm[dgl + 8 + i];
        o1[i] = f2bs(h / (1.f + __expf(-h)));
    }
    short* op = (short*)outb + ((size_t)n * kT + t0 + tl) * kD + dg0 + dgl;
    *(short8*)op = o0;
    *(short8*)(op + 8) = o1;
}

// ---------------------------------------------------------------- scalar conv (slow path)
__global__ __launch_bounds__(256) void conv_kernel(
    const bf16* __restrict__ glu, const float* __restrict__ dw_w,
    const float* __restrict__ dw_b, const float* __restrict__ bn_g,
    const float* __restrict__ bn_b, bf16* __restrict__ outb) {
    int idx = blockIdx.x * 256 + threadIdx.x;
    int d = idx & 511;
    int t = (idx >> 9) & 1023;
    int n = idx >> 19;
    const bf16* gp = glu + ((size_t)n * kT) * kD + d;
    float acc = 0.f;
#pragma unroll
    for (int k = 0; k < 31; ++k) {
        int tt = t + k - 15;
        if ((unsigned)tt < (unsigned)kT)
            acc += b2f(gp[(size_t)tt * kD]) * dw_w[d * 31 + k];
    }
    acc += dw_b[d];
    acc = acc * bn_g[d] + bn_b[d];
    acc = acc / (1.f + __expf(-acc));
    outb[idx] = f2b(acc);
}

// ================================================================ launch
extern "C" void kernel_launch(void* const* d_in, const int* in_sizes, int n_in,
                              void* d_out, int out_size, void* d_ws, size_t ws_size,
                              hipStream_t stream) {
    const float* x      = (const float*)d_in[0];
    const float* rel_pe = (const float*)d_in[1];
    const float* ln1_g  = (const float*)d_in[2];
    const float* ln1_b  = (const float*)d_in[3];
    const float* ff1_w1 = (const float*)d_in[4];
    const float* ff1_b1 = (const float*)d_in[5];
    const float* ff1_w2 = (const float*)d_in[6];
    const float* ff1_b2 = (const float*)d_in[7];
    const float* an_g   = (const float*)d_in[8];
    const float* an_b   = (const float*)d_in[9];
    const float* wq = (const float*)d_in[10]; const float* bq = (const float*)d_in[11];
    const float* wk = (const float*)d_in[12]; const float* bk = (const float*)d_in[13];
    const float* wv = (const float*)d_in[14]; const float* bv = (const float*)d_in[15];
    const float* wo = (const float*)d_in[16]; const float* bo = (const float*)d_in[17];
    const float* pos_w = (const float*)d_in[18];
    const float* uu = (const float*)d_in[19]; const float* vvp = (const float*)d_in[20];
    const float* cn_g = (const float*)d_in[21]; const float* cn_b = (const float*)d_in[22];
    const float* pe_w = (const float*)d_in[23]; const float* pe_b = (const float*)d_in[24];
    const float* dw_w = (const float*)d_in[25]; const float* dw_b = (const float*)d_in[26];
    const float* bn_g = (const float*)d_in[27]; const float* bn_b = (const float*)d_in[28];
    const float* pc_w = (const float*)d_in[29]; const float* pc_b = (const float*)d_in[30];
    const float* ln2_g = (const float*)d_in[31]; const float* ln2_b = (const float*)d_in[32];
    const float* ff2_w1 = (const float*)d_in[33]; const float* ff2_b1 = (const float*)d_in[34];
    const float* ff2_w2 = (const float*)d_in[35]; const float* ff2_b2 = (const float*)d_in[36];
    const float* fn_g = (const float*)d_in[37]; const float* fn_b = (const float*)d_in[38];
    (void)n_in; (void)in_sizes;

    const int total = kROWS * kD;
    dim3 blk(256);
    const size_t MB = 1ull << 20;
    char* w = (char*)d_ws;

    if (ws_size >= 30 * MB) {
        // ================= FAST PATH (MFMA) =================
        float* xf      = (float*)(w);
        short* ff1_w1t = (short*)(w + 8 * MB);
        short* ff1_w2t = (short*)(w + 10 * MB);
        short* wqt     = (short*)(w + 12 * MB);
        short* wkt     = (short*)(w + 12 * MB + 512 * 1024);
        short* wvt     = (short*)(w + 13 * MB);
        short* wot     = (short*)(w + 13 * MB + 512 * 1024);
        short* poswt   = (short*)(w + 14 * MB);
        short* pewt    = (short*)(w + 14 * MB + 512 * 1024);
        short* pcwt    = (short*)(w + 15 * MB + 512 * 1024);
        short* ff2_w1t = (short*)(w + 16 * MB);
        short* ff2_w2t = (short*)(w + 18 * MB);
        char*  dyn     = w + 20 * MB;
        bf16* hchunk = (bf16*)dyn;
        bf16* Qb     = (bf16*)dyn;
        bf16* Kb     = (bf16*)(dyn + 4 * MB);
        bf16* Rb     = (bf16*)(dyn + 8 * MB);   // attention phase only
        bf16* cbuf   = (bf16*)dyn;
        float* dwt   = (float*)(dyn + 8 * MB);  // conv phase ONLY (aliases Rb!)
        float* beff  = (float*)(dyn + 8 * MB + 256 * 1024);
        bf16* nb     = (bf16*)d_out;
        bf16* Vtg    = (bf16*)d_out;                               // lo 4 MB (after qkv)
        bf16* convb  = (bf16*)d_out;
        bf16* Vb     = (bf16*)d_out + (size_t)kROWS * kD;          // hi 4 MB
        bf16* attnb  = Vb;                                         // hi 4 MB (after vtrans)

        // ---- all weight transposes in ONE launch
        WtArgs wa;
        const float* srcs[11] = {ff1_w1, ff1_w2, wq, wk, wv, wo, pos_w, pe_w, pc_w, ff2_w1, ff2_w2};
        short* dsts[11] = {ff1_w1t, ff1_w2t, wqt, wkt, wvt, wot, poswt, pewt, pcwt, ff2_w1t, ff2_w2t};
        int Ks_[11] = {512, 2048, 512, 512, 512, 512, 512, 512, 512, 512, 2048};
        int Ns_[11] = {2048, 512, 512, 512, 512, 512, 512, 1024, 512, 2048, 512};
        int cum = 0;
        for (int i = 0; i < 11; ++i) {
            wa.d[i].src = srcs[i]; wa.d[i].dst = dsts[i];
            wa.d[i].K = Ks_[i]; wa.d[i].N = Ns_[i]; wa.d[i].tstart = cum;
            cum += (Ns_[i] / 32) * (Ks_[i] / 32);
        }
        wt_all_kernel<<<cum, blk, 0, stream>>>(wa);

        // ---- macaron FF1
        ln_kernel_v<<<kROWS / 2, blk, 0, stream>>>(x, ln1_g, ln1_b, nb, 0);
        for (int c = 0; c < 2; ++c) {
            size_t off = (size_t)c * 2048 * kD;
            gemm_mfma64<<<dim3(kFFN / 64, 2048 / 64), blk, 0, stream>>>(
                nb + off, ff1_w1t, ff1_b1, nullptr, nullptr, hchunk,
                2048, kFFN, kD, ACT_SILU, 1.f, 0);
            gemm_mfma64<<<dim3(kD / 64, 2048 / 64), blk, 0, stream>>>(
                hchunk, ff1_w2t, ff1_b2, x + off, xf + off, nullptr,
                2048, kD, kFFN, ACT_NONE, 0.5f, 0);
        }

        // ---- RPE attention
        ln_kernel_v<<<kROWS / 2, blk, 0, stream>>>(xf, an_g, an_b, nb, 0);
        gemm_qkv<<<dim3(24, kROWS / 64), blk, 0, stream>>>(
            nb, wqt, bq, bk, bv, Qb, Kb, Vb);
        vtrans_kernel<<<dim3(16, 8, 4), blk, 0, stream>>>(Vb, Vtg);
        gemm_mfma64<<<dim3(kD / 64, (kP + 63) / 64), blk, 0, stream>>>(
            rel_pe, poswt, nullptr, nullptr, nullptr, Rb, kP, kD, kD, ACT_NONE, 1.f, 1);
        attn_mfma<<<dim3(kT / 64, kH, kN), blk, 0, stream>>>(Qb, Kb, Vtg, Rb, uu, vvp, attnb);
        gemm_mfma64<<<dim3(kD / 64, kROWS / 64), blk, 0, stream>>>(
            attnb, wot, bo, xf, xf, nullptr, kROWS, kD, kD, ACT_NONE, 1.f, 0);

        // ---- conv module (dwt MUST run after attention: dwt/beff alias Rb)
        dwt_kernel<<<62, blk, 0, stream>>>(dw_w, dw_b, bn_g, bn_b, dwt, beff);
        ln_kernel_v<<<kROWS / 2, blk, 0, stream>>>(xf, cn_g, cn_b, nb, 0);
        gemm_mfma64<<<dim3(2 * kD / 64, kROWS / 64), blk, 0, stream>>>(
            nb, pewt, pe_b, nullptr, nullptr, cbuf, kROWS, 2 * kD, kD, ACT_NONE, 1.f, 0);
        gluconv_kernel<<<dim3(8, 16, 4), blk, 0, stream>>>(cbuf, dwt, beff, convb);
        gemm_mfma64<<<dim3(kD / 64, kROWS / 64), blk, 0, stream>>>(
            convb, pcwt, pc_b, xf, xf, nullptr, kROWS, kD, kD, ACT_NONE, 1.f, 0);

        // ---- macaron FF2
        ln_kernel_v<<<kROWS / 2, blk, 0, stream>>>(xf, ln2_g, ln2_b, nb, 0);
        for (int c = 0; c < 2; ++c) {
            size_t off = (size_t)c * 2048 * kD;
            gemm_mfma64<<<dim3(kFFN / 64, 2048 / 64), blk, 0, stream>>>(
                nb + off, ff2_w1t, ff2_b1, nullptr, nullptr, hchunk,
                2048, kFFN, kD, ACT_SILU, 1.f, 0);
            gemm_mfma64<<<dim3(kD / 64, 2048 / 64), blk, 0, stream>>>(
                hchunk, ff2_w2t, ff2_b2, xf + off, xf + off, nullptr,
                2048, kD, kFFN, ACT_NONE, 0.5f, 0);
        }

        ln_kernel_v<<<kROWS / 2, blk, 0, stream>>>(xf, fn_g, fn_b, d_out, 1);
        return;
    }

    if (ws_size < 22 * MB) {
        stamp_kernel<<<(out_size + 255) / 256, blk, 0, stream>>>(
            (float*)d_out, out_size, 1000.f + (float)(ws_size / MB));
        return;
    }

    // ================= SLOW PATH (scalar, known-good) =================
    float* xf    = (float*)(w);
    bf16*  hbch  = (bf16*)(w + 8 * MB);
    bf16*  Qb    = (bf16*)(w + 8 * MB);
    bf16*  cbuf  = (bf16*)(w + 8 * MB);
    bf16*  convb = (bf16*)(w + 8 * MB);
    bf16*  Kb    = (bf16*)(w + 12 * MB);
    bf16*  Vb    = (bf16*)(w + 16 * MB);
    bf16*  glub  = (bf16*)(w + 16 * MB);
    bf16*  Rb    = (bf16*)(w + 20 * MB);
    bf16*  nb    = (bf16*)d_out;
    bf16*  attnb = (bf16*)d_out;

    cvt_kernel<<<total / 1024, blk, 0, stream>>>(x, xf, total / 4);

    ln_kernel<<<kROWS, blk, 0, stream>>>(xf, ln1_g, ln1_b, nb, 0);
    for (int c = 0; c < 4; ++c) {
        size_t off = (size_t)c * 1024 * kD;
        gemm_scalar<<<dim3(kFFN / 64, 1024 / 64), blk, 0, stream>>>(
            nb + off, ff1_w1, ff1_b1, nullptr, nullptr, hbch, 1024, kFFN, kD, ACT_SILU, 1.f, 0);
        gemm_scalar<<<dim3(kD / 64, 1024 / 64), blk, 0, stream>>>(
            hbch, ff1_w2, ff1_b2, xf + off, xf + off, nullptr, 1024, kD, kFFN, ACT_NONE, 0.5f, 0);
    }

    ln_kernel<<<kROWS, blk, 0, stream>>>(xf, an_g, an_b, nb, 0);
    gemm_scalar<<<dim3(kD / 64, kROWS / 64), blk, 0, stream>>>(
        nb, wq, bq, nullptr, nullptr, Qb, kROWS, kD, kD, ACT_NONE, 1.f, 0);
    gemm_scalar<<<dim3(kD / 64, kROWS / 64), blk, 0, stream>>>(
        nb, wk, bk, nullptr, nullptr, Kb, kROWS, kD, kD, ACT_NONE, 1.f, 0);
    gemm_scalar<<<dim3(kD / 64, kROWS / 64), blk, 0, stream>>>(
        nb, wv, bv, nullptr, nullptr, Vb, kROWS, kD, kD, ACT_NONE, 1.f, 0);
    gemm_scalar<<<dim3(kD / 64, (kP + 63) / 64), blk, 0, stream>>>(
        rel_pe, pos_w, nullptr, nullptr, nullptr, Rb, kP, kD, kD, ACT_NONE, 1.f, 1);
    attn_kernel<<<dim3(kT / 64, kH, kN), blk, 0, stream>>>(Qb, Kb, Vb, Rb, uu, vvp, attnb);
    gemm_scalar<<<dim3(kD / 64, kROWS / 64), blk, 0, stream>>>(
        attnb, wo, bo, xf, xf, nullptr, kROWS, kD, kD, ACT_NONE, 1.f, 0);

    ln_kernel<<<kROWS, blk, 0, stream>>>(xf, cn_g, cn_b, nb, 0);
    gemm_scalar<<<dim3(2 * kD / 64, kROWS / 64), blk, 0, stream>>>(
        nb, pe_w, pe_b, nullptr, nullptr, cbuf, kROWS, 2 * kD, kD, ACT_NONE, 1.f, 0);
    glu_kernel_v<<<total / 2048, blk, 0, stream>>>(cbuf, glub);
    conv_kernel<<<total / 256, blk, 0, stream>>>(glub, dw_w, dw_b, bn_g, bn_b, convb);
    gemm_scalar<<<dim3(kD / 64, kROWS / 64), blk, 0, stream>>>(
        convb, pc_w, pc_b, xf, xf, nullptr, kROWS, kD, kD, ACT_NONE, 1.f, 0);

    ln_kernel<<<kROWS, blk, 0, stream>>>(xf, ln2_g, ln2_b, nb, 0);
    for (int c = 0; c < 4; ++c) {
        size_t off = (size_t)c * 1024 * kD;
        gemm_scalar<<<dim3(kFFN / 64, 1024 / 64), blk, 0, stream>>>(
            nb + off, ff2_w1, ff2_b1, nullptr, nullptr, hbch, 1024, kFFN, kD, ACT_SILU, 1.f, 0);
        gemm_scalar<<<dim3(kD / 64, 1024 / 64), blk, 0, stream>>>(
            hbch, ff2_w2, ff2_b2, xf + off, xf + off, nullptr, 1024, kD, kFFN, ACT_NONE, 0.5f, 0);
    }

    ln_kernel<<<kROWS, blk, 0, stream>>>(xf, fn_g, fn_b, d_out, 1);
}

// Round 15
// 483.685 us; speedup vs baseline: 1.0734x; 1.0017x over previous
//
#include <hip/hip_runtime.h>
#include <hip/hip_bf16.h>

using bf16 = __hip_bfloat16;
typedef __attribute__((ext_vector_type(8))) short short8;
typedef __attribute__((ext_vector_type(4))) short short4v;
typedef __attribute__((ext_vector_type(4))) float f32x4;

static __device__ __forceinline__ float b2f(bf16 v) { return __bfloat162float(v); }
static __device__ __forceinline__ bf16  f2b(float v) { return __float2bfloat16(v); }
static __device__ __forceinline__ short f2bs(float x) {
    union { float f; unsigned u; } c; c.f = x;
    unsigned r = (c.u + 0x7FFFu + ((c.u >> 16) & 1u)) >> 16;
    return (short)r;
}
static __device__ __forceinline__ float bs2f(short s) {
    union { unsigned u; float f; } c; c.u = ((unsigned)(unsigned short)s) << 16;
    return c.f;
}
// async global->LDS, 16B per lane; LDS dst = wave-uniform base + lane*16
static __device__ __forceinline__ void gload16(const short* g, short* l) {
    __builtin_amdgcn_global_load_lds(
        (const __attribute__((address_space(1))) void*)g,
        (__attribute__((address_space(3))) void*)l, 16, 0, 0);
}

constexpr int kD   = 512;
constexpr int kT   = 1024;
constexpr int kN   = 4;
constexpr int kH   = 8;
constexpr int kDH  = 64;
constexpr int kFFN = 2048;
constexpr int kROWS = kN * kT;        // 4096
constexpr int kP    = 2 * kT - 1;     // 2047

#define ACT_NONE 0
#define ACT_SILU 1

// ---------------------------------------------------------------- fallback stamp
__global__ __launch_bounds__(256) void stamp_kernel(float* __restrict__ out, int n, float val) {
    int i = blockIdx.x * 256 + threadIdx.x;
    if (i < n) out[i] = (i == 0 ? val : 0.f);
}

// ---------------------------------------------------------------- copy (slow path only)
__global__ __launch_bounds__(256) void cvt_kernel(const float* __restrict__ in,
                                                  float* __restrict__ out, int n4) {
    int i = blockIdx.x * 256 + threadIdx.x;
    if (i < n4) ((f32x4*)out)[i] = ((const f32x4*)in)[i];
}

// ---------------------------------------------------------------- fused weight transpose
struct WtDesc { const float* src; short* dst; int K; int N; int tstart; };
struct WtArgs { WtDesc d[11]; };

__global__ __launch_bounds__(256) void wt_all_kernel(WtArgs a) {
    __shared__ float t[32][33];
    int bid = blockIdx.x;
    int i = 0;
#pragma unroll
    for (int j = 1; j < 11; ++j) if (bid >= a.d[j].tstart) i = j;
    const float* W = a.d[i].src;
    short* Wt = a.d[i].dst;
    int Kd = a.d[i].K, Nd = a.d[i].N;
    int lt = bid - a.d[i].tstart;
    int nx = Nd >> 5;
    int n0 = (lt % nx) * 32, k0 = (lt / nx) * 32;
    int tx = threadIdx.x & 31, ty = threadIdx.x >> 5;
#pragma unroll
    for (int it = 0; it < 4; ++it)
        t[ty + it * 8][tx] = W[(size_t)(k0 + ty + it * 8) * Nd + n0 + tx];
    __syncthreads();
#pragma unroll
    for (int it = 0; it < 4; ++it)
        Wt[(size_t)(n0 + ty + it * 8) * Kd + k0 + tx] = f2bs(t[tx][ty + it * 8]);
}

// ---------------------------------------------------------------- V transpose per (n,h)
__global__ __launch_bounds__(256) void vtrans_kernel(const bf16* __restrict__ V,
                                                     bf16* __restrict__ Vt) {
    __shared__ short ts[64][72];
    int tt = blockIdx.x, h = blockIdx.y, n = blockIdx.z;
    int tid = threadIdx.x;
    int r = tid >> 3, cg = (tid & 7) * 8;
#pragma unroll
    for (int it = 0; it < 2; ++it) {
        int row = it * 32 + r;
        *(short8*)&ts[row][cg] =
            *(const short8*)((const short*)V + ((size_t)n * kT + tt * 64 + row) * 512 + h * 64 + cg);
    }
    __syncthreads();
#pragma unroll
    for (int it = 0; it < 2; ++it) {
        int d = it * 32 + r;
        short8 o;
#pragma unroll
        for (int i = 0; i < 8; ++i) o[i] = ts[cg + i][d];
        *(short8*)((short*)Vt + ((size_t)(n * 8 + h) * 64 + d) * 1024 + tt * 64 + cg) = o;
    }
}

// ---------------------------------------------------------------- depthwise weight prep (fold BN)
__global__ __launch_bounds__(256) void dwt_kernel(const float* __restrict__ dw_w,
                                                  const float* __restrict__ dw_b,
                                                  const float* __restrict__ bn_g,
                                                  const float* __restrict__ bn_b,
                                                  float* __restrict__ wt,
                                                  float* __restrict__ beff) {
    int idx = blockIdx.x * 256 + threadIdx.x;
    if (idx < 31 * kD) {
        int d = idx & 511, k = idx >> 9;
        wt[k * kD + d] = dw_w[d * 31 + k] * bn_g[d];
    }
    if (idx < kD) beff[idx] = dw_b[idx] * bn_g[idx] + bn_b[idx];
}

// ---------------------------------------------------------------- layernorm, vectorized
__global__ __launch_bounds__(256) void ln_kernel_v(const float* __restrict__ xin,
                                                   const float* __restrict__ g,
                                                   const float* __restrict__ b,
                                                   void* __restrict__ outp, int out_f32) {
    int tid = threadIdx.x;
    int rh = tid >> 7;
    int tl = tid & 127;
    int row = blockIdx.x * 2 + rh;
    const float* xr = xin + (size_t)row * kD;
    f32x4 v = *(const f32x4*)(xr + tl * 4);
    float s  = v[0] + v[1] + v[2] + v[3];
    float sq = v[0]*v[0] + v[1]*v[1] + v[2]*v[2] + v[3]*v[3];
    for (int off = 32; off; off >>= 1) {
        s  += __shfl_down(s, off);
        sq += __shfl_down(sq, off);
    }
    __shared__ float ss[4], ssq[4], mean_s[2], rstd_s[2];
    int wid = tid >> 6;
    if ((tid & 63) == 0) { ss[wid] = s; ssq[wid] = sq; }
    __syncthreads();
    if (tid < 2) {
        float S  = ss[tid * 2] + ss[tid * 2 + 1];
        float SQ = ssq[tid * 2] + ssq[tid * 2 + 1];
        float m = S / (float)kD;
        float var = SQ / (float)kD - m * m;
        mean_s[tid] = m;
        rstd_s[tid] = rsqrtf(fmaxf(var, 0.f) + 1e-5f);
    }
    __syncthreads();
    float m = mean_s[rh], rs = rstd_s[rh];
    f32x4 gg = *(const f32x4*)(g + tl * 4);
    f32x4 bb = *(const f32x4*)(b + tl * 4);
    if (out_f32) {
        f32x4 o;
#pragma unroll
        for (int i = 0; i < 4; ++i) o[i] = (v[i] - m) * rs * gg[i] + bb[i];
        *(f32x4*)((float*)outp + (size_t)row * kD + tl * 4) = o;
    } else {
        short4v o;
#pragma unroll
        for (int i = 0; i < 4; ++i) o[i] = f2bs((v[i] - m) * rs * gg[i] + bb[i]);
        *(short4v*)((short*)outp + (size_t)row * kD + tl * 4) = o;
    }
}

// ---------------------------------------------------------------- layernorm (slow path)
__global__ __launch_bounds__(256) void ln_kernel(const float* __restrict__ xin,
                                                 const float* __restrict__ g,
                                                 const float* __restrict__ b,
                                                 void* __restrict__ outp, int out_f32) {
    int row = blockIdx.x;
    const float* xr = xin + (size_t)row * kD;
    int tid = threadIdx.x;
    float v0 = xr[tid], v1 = xr[tid + 256];
    float s = v0 + v1, sq = v0 * v0 + v1 * v1;
    for (int off = 32; off; off >>= 1) {
        s  += __shfl_down(s, off);
        sq += __shfl_down(sq, off);
    }
    __shared__ float ss[4], ssq[4];
    __shared__ float mean_s, rstd_s;
    int wid = tid >> 6, lane = tid & 63;
    if (lane == 0) { ss[wid] = s; ssq[wid] = sq; }
    __syncthreads();
    if (tid == 0) {
        float S  = ss[0] + ss[1] + ss[2] + ss[3];
        float SQ = ssq[0] + ssq[1] + ssq[2] + ssq[3];
        float m = S / (float)kD;
        float var = SQ / (float)kD - m * m;
        mean_s = m;
        rstd_s = rsqrtf(fmaxf(var, 0.f) + 1e-5f);
    }
    __syncthreads();
    float m = mean_s, rs = rstd_s;
    float o0 = (v0 - m) * rs * g[tid]       + b[tid];
    float o1 = (v1 - m) * rs * g[tid + 256] + b[tid + 256];
    size_t i0 = (size_t)row * kD + tid, i1 = i0 + 256;
    if (out_f32) {
        ((float*)outp)[i0] = o0; ((float*)outp)[i1] = o1;
    } else {
        ((bf16*)outp)[i0] = f2b(o0); ((bf16*)outp)[i1] = f2b(o1);
    }
}

// ---------------------------------------------------------------- MFMA GEMM, 64x64 tile (dbuf async)
__global__ __launch_bounds__(256, 4) void gemm_mfma64(
    const void* __restrict__ A, const short* __restrict__ Bt,
    const float* __restrict__ bias, const float* __restrict__ residual,
    float* __restrict__ outf, bf16* __restrict__ outb,
    int M, int N, int K, int act, float scale, int a_f32) {
    __shared__ short As[2][4096];
    __shared__ short Bs[2][4096];
    int tid = threadIdx.x;
    int m0 = blockIdx.y * 64, n0 = blockIdx.x * 64;
    int wid = tid >> 6, lane = tid & 63;
    int wm = (wid >> 1) * 32, wn = (wid & 1) * 32;
    int q = lane >> 4, c16 = lane & 15;

    f32x4 zero4 = {0.f, 0.f, 0.f, 0.f};
    f32x4 acc[2][2] = {{zero4, zero4}, {zero4, zero4}};

    int arow = lane >> 3;
    int aseg = (lane & 7) ^ arow;

    auto issueA = [&](int buf, int k0) {
        if (!a_f32) {
#pragma unroll
            for (int it = 0; it < 2; ++it) {
                int rbase = (wid * 2 + it) * 8;
                gload16((const short*)A + (size_t)(m0 + rbase + arow) * K + k0 + aseg * 8,
                        &As[buf][(wid * 2 + it) * 512]);
            }
        } else {
            int srow = tid >> 3, sseg = tid & 7;
#pragma unroll
            for (int it = 0; it < 2; ++it) {
                int row = it * 32 + srow;
                int rr = m0 + row;
                short8 v = {0, 0, 0, 0, 0, 0, 0, 0};
                if (rr < M) {
                    const float* ap = (const float*)A + (size_t)rr * K + k0 + sseg * 8;
                    f32x4 x0 = *(const f32x4*)ap;
                    f32x4 x1 = *(const f32x4*)(ap + 4);
                    v[0] = f2bs(x0[0]); v[1] = f2bs(x0[1]); v[2] = f2bs(x0[2]); v[3] = f2bs(x0[3]);
                    v[4] = f2bs(x1[0]); v[5] = f2bs(x1[1]); v[6] = f2bs(x1[2]); v[7] = f2bs(x1[3]);
                }
                *(short8*)&As[buf][(row * 8 + (sseg ^ (row & 7))) * 8] = v;
            }
        }
    };
    auto issueB = [&](int buf, int k0) {
#pragma unroll
        for (int it = 0; it < 2; ++it) {
            int rbase = (wid * 2 + it) * 8;
            gload16(Bt + (size_t)(n0 + rbase + arow) * K + k0 + aseg * 8,
                    &Bs[buf][(wid * 2 + it) * 512]);
        }
    };

    issueA(0, 0);
    issueB(0, 0);
    int cur = 0;
    for (int k0 = 0; k0 < K; k0 += 64) {
        __syncthreads();
        if (k0 + 64 < K) {
            issueA(cur ^ 1, k0 + 64);
            issueB(cur ^ 1, k0 + 64);
        }
#pragma unroll
        for (int ks = 0; ks < 2; ++ks) {
            int p = c16 & 7;
            short8 af[2], bfr[2];
#pragma unroll
            for (int mt = 0; mt < 2; ++mt) {
                int row = wm + mt * 16 + c16;
                af[mt] = *(const short8*)&As[cur][(row * 8 + ((ks * 4 + q) ^ p)) * 8];
            }
#pragma unroll
            for (int nt = 0; nt < 2; ++nt) {
                int row = wn + nt * 16 + c16;
                bfr[nt] = *(const short8*)&Bs[cur][(row * 8 + ((ks * 4 + q) ^ p)) * 8];
            }
#pragma unroll
            for (int mt = 0; mt < 2; ++mt)
#pragma unroll
                for (int nt = 0; nt < 2; ++nt)
                    acc[mt][nt] = __builtin_amdgcn_mfma_f32_16x16x32_bf16(
                        af[mt], bfr[nt], acc[mt][nt], 0, 0, 0);
        }
        cur ^= 1;
    }
#pragma unroll
    for (int mt = 0; mt < 2; ++mt) {
#pragma unroll
        for (int reg = 0; reg < 4; ++reg) {
            int r = m0 + wm + mt * 16 + q * 4 + reg;
            if (r >= M) continue;
#pragma unroll
            for (int nt = 0; nt < 2; ++nt) {
                int c = n0 + wn + nt * 16 + c16;
                float h = acc[mt][nt][reg];
                if (bias) h += bias[c];
                if (act == ACT_SILU) h = h / (1.f + __expf(-h));
                h *= scale;
                size_t idx = (size_t)r * N + c;
                if (residual) h += residual[idx];
                if (outf) outf[idx] = h;
                if (outb) outb[idx] = f2b(h);
            }
        }
    }
}

// ---------------------------------------------------------------- fused QKV GEMM (dbuf async)
__global__ __launch_bounds__(256, 4) void gemm_qkv(
    const bf16* __restrict__ A, const short* __restrict__ Bt,
    const float* __restrict__ bq, const float* __restrict__ bk,
    const float* __restrict__ bv,
    bf16* __restrict__ Qb, bf16* __restrict__ Kb, bf16* __restrict__ Vb) {
    const int K = kD;
    __shared__ short As[2][4096];
    __shared__ short Bs[2][4096];
    int tid = threadIdx.x;
    int m0 = blockIdx.y * 64, n0 = blockIdx.x * 64;
    int seg = blockIdx.x >> 3;
    const float* bias = seg == 0 ? bq : (seg == 1 ? bk : bv);
    bf16* outb = seg == 0 ? Qb : (seg == 1 ? Kb : Vb);
    int ns0 = n0 & 511;
    int wid = tid >> 6, lane = tid & 63;
    int wm = (wid >> 1) * 32, wn = (wid & 1) * 32;
    int q = lane >> 4, c16 = lane & 15;

    f32x4 zero4 = {0.f, 0.f, 0.f, 0.f};
    f32x4 acc[2][2] = {{zero4, zero4}, {zero4, zero4}};
    int arow = lane >> 3;
    int aseg = (lane & 7) ^ arow;

    auto issue = [&](int buf, int k0) {
#pragma unroll
        for (int it = 0; it < 2; ++it) {
            int rbase = (wid * 2 + it) * 8;
            gload16((const short*)A + (size_t)(m0 + rbase + arow) * K + k0 + aseg * 8,
                    &As[buf][(wid * 2 + it) * 512]);
            gload16(Bt + (size_t)(n0 + rbase + arow) * K + k0 + aseg * 8,
                    &Bs[buf][(wid * 2 + it) * 512]);
        }
    };

    issue(0, 0);
    int cur = 0;
    for (int k0 = 0; k0 < K; k0 += 64) {
        __syncthreads();
        if (k0 + 64 < K) issue(cur ^ 1, k0 + 64);
#pragma unroll
        for (int ks = 0; ks < 2; ++ks) {
            int p = c16 & 7;
            short8 af[2], bfr[2];
#pragma unroll
            for (int mt = 0; mt < 2; ++mt) {
                int row = wm + mt * 16 + c16;
                af[mt] = *(const short8*)&As[cur][(row * 8 + ((ks * 4 + q) ^ p)) * 8];
            }
#pragma unroll
            for (int nt = 0; nt < 2; ++nt) {
                int row = wn + nt * 16 + c16;
                bfr[nt] = *(const short8*)&Bs[cur][(row * 8 + ((ks * 4 + q) ^ p)) * 8];
            }
#pragma unroll
            for (int mt = 0; mt < 2; ++mt)
#pragma unroll
                for (int nt = 0; nt < 2; ++nt)
                    acc[mt][nt] = __builtin_amdgcn_mfma_f32_16x16x32_bf16(
                        af[mt], bfr[nt], acc[mt][nt], 0, 0, 0);
        }
        cur ^= 1;
    }
#pragma unroll
    for (int mt = 0; mt < 2; ++mt)
#pragma unroll
        for (int reg = 0; reg < 4; ++reg) {
            int r = m0 + wm + mt * 16 + q * 4 + reg;
#pragma unroll
            for (int nt = 0; nt < 2; ++nt) {
                int c = ns0 + wn + nt * 16 + c16;
                outb[(size_t)r * 512 + c] = f2b(acc[mt][nt][reg] + bias[c]);
            }
        }
}

// ---------------------------------------------------------------- scalar GEMM (slow fallback)
__global__ __launch_bounds__(256) void gemm_scalar(
    const void* __restrict__ A, const float* __restrict__ W,
    const float* __restrict__ bias, const float* __restrict__ residual,
    float* __restrict__ outf, bf16* __restrict__ outb,
    int M, int N, int K, int act, float scale, int a_f32) {
    __shared__ float As[16][65];
    __shared__ float Bs[16][65];
    int tid = threadIdx.x;
    int tx = tid & 15, ty = tid >> 4;
    int row0 = blockIdx.y * 64, col0 = blockIdx.x * 64;
    float acc[4][4] = {};
    for (int k0 = 0; k0 < K; k0 += 16) {
        for (int i = tid; i < 64 * 16; i += 256) {
            int r = i >> 4, c = i & 15;
            int rr = row0 + r;
            float v = 0.f;
            if (rr < M) {
                size_t idx = (size_t)rr * K + k0 + c;
                v = a_f32 ? ((const float*)A)[idx] : b2f(((const bf16*)A)[idx]);
            }
            As[c][r] = v;
        }
        for (int i = tid; i < 16 * 64; i += 256) {
            int r = i >> 6, c = i & 63;
            Bs[r][c] = W[(size_t)(k0 + r) * N + col0 + c];
        }
        __syncthreads();
#pragma unroll
        for (int kk = 0; kk < 16; ++kk) {
            float a[4], b[4];
#pragma unroll
            for (int i = 0; i < 4; ++i) a[i] = As[kk][ty * 4 + i];
#pragma unroll
            for (int j = 0; j < 4; ++j) b[j] = Bs[kk][tx * 4 + j];
#pragma unroll
            for (int i = 0; i < 4; ++i)
#pragma unroll
                for (int j = 0; j < 4; ++j) acc[i][j] += a[i] * b[j];
        }
        __syncthreads();
    }
#pragma unroll
    for (int i = 0; i < 4; ++i) {
        int r = row0 + ty * 4 + i;
        if (r >= M) continue;
#pragma unroll
        for (int j = 0; j < 4; ++j) {
            int c = col0 + tx * 4 + j;
            float h = acc[i][j];
            if (bias) h += bias[c];
            if (act == ACT_SILU) h = h / (1.f + __expf(-h));
            h *= scale;
            size_t idx = (size_t)r * N + c;
            if (residual) h += residual[idx];
            if (outf) outf[idx] = h;
            if (outb) outb[idx] = f2b(h);
        }
    }
}

// ---------------------------------------------------------------- MFMA RPE attention
// Grid-limited to 2 blocks/CU (512 blocks), so LDS up to 80 KB is free:
// double-buffer K/Vt/R async staging (prefetch kt+1 during kt's compute).
// Q(+u)/Q(+v) fragments in registers; Bp trimmed to wave-local j window.
__global__ __launch_bounds__(256, 2) void attn_mfma(
    const bf16* __restrict__ Qg, const bf16* __restrict__ Kg,
    const bf16* __restrict__ Vtg, const bf16* __restrict__ Rg,
    const float* __restrict__ uu, const float* __restrict__ vvp,
    bf16* __restrict__ outb) {
    __shared__ short KsL[2][4096];    // 64x64 swizzled
    __shared__ short VtL[2][4096];    // 64x64 swizzled
    __shared__ short RwL[2][8192];    // 128x64 swizzled
    __shared__ short Bp[64][88];      // Braw (cols 0..79 = j-wm), then P (cols 0..63)

    int tid = threadIdx.x;
    int qb = blockIdx.x, h = blockIdx.y, n = blockIdx.z;
    int t0 = qb * 64;
    size_t baseq = ((size_t)n * kT) * 512 + (size_t)h * kDH;
    size_t basev = ((size_t)(n * 8 + h) * 64) * 1024;
    size_t baseo = ((size_t)n * kT) * kD + (size_t)h * kDH;

    int wid = tid >> 6, lane = tid & 63;
    int q = lane >> 4, c16 = lane & 15;
    int wm = wid * 16;
    int trow = wm + q * 4;

    // ---- Q fragments with u,v folded, in registers (constant across kt)
    short8 qu[2], qvv[2];
    {
        const short* qp = (const short*)Qg + baseq + (size_t)(t0 + wm + c16) * 512;
#pragma unroll
        for (int ks = 0; ks < 2; ++ks) {
            short8 q8 = *(const short8*)(qp + ks * 32 + q * 8);
            const float* up = uu + h * 64 + ks * 32 + q * 8;
            const float* vp = vvp + h * 64 + ks * 32 + q * 8;
#pragma unroll
            for (int i = 0; i < 8; ++i) {
                float xq = bs2f(q8[i]);
                qu[ks][i]  = f2bs(xq + up[i]);
                qvv[ks][i] = f2bs(xq + vp[i]);
            }
        }
    }

    int arow = lane >> 3;
    int aseg = (lane & 7) ^ arow;

    auto issue = [&](int buf, int kt) {
        int s0 = kt * 64;
#pragma unroll
        for (int it = 0; it < 2; ++it) {
            int g = wid * 2 + it;
            gload16((const short*)Kg + baseq + (size_t)(s0 + g * 8 + arow) * 512 + aseg * 8,
                    &KsL[buf][g * 512]);
            gload16((const short*)Vtg + basev + (size_t)(g * 8 + arow) * 1024 + s0 + aseg * 8,
                    &VtL[buf][g * 512]);
        }
        int p_base = t0 - s0 + 960;
#pragma unroll
        for (int it = 0; it < 4; ++it) {
            int g = wid * 4 + it;
            int j = g * 8 + arow;
            int p = p_base + j;
            p = p < 0 ? 0 : (p > 2046 ? 2046 : p);
            gload16((const short*)Rg + (size_t)p * kD + h * kDH + aseg * 8,
                    &RwL[buf][g * 512]);
        }
    };

    f32x4 zero4 = {0.f, 0.f, 0.f, 0.f};
    f32x4 acc_o[4] = {zero4, zero4, zero4, zero4};
    float m_i[4] = {-1e30f, -1e30f, -1e30f, -1e30f};
    float l_i[4] = {0.f, 0.f, 0.f, 0.f};

    issue(0, 0);
    int cur = 0;
    for (int kt = 0; kt < 16; ++kt) {
        __syncthreads();   // buf[cur] drained; prev iter's reads of buf[cur^1] done
        if (kt + 1 < 16) issue(cur ^ 1, kt + 1);

        // ---- MFMA: S_qk = Qu K^T (4), Braw = Qv Rw^T (5, B-trim), per ks
        f32x4 acc_s[4] = {zero4, zero4, zero4, zero4};
        f32x4 acc_b[5] = {zero4, zero4, zero4, zero4, zero4};
#pragma unroll
        for (int ks = 0; ks < 2; ++ks) {
            int pq = c16 & 7;
#pragma unroll
            for (int nt = 0; nt < 4; ++nt) {
                int row = nt * 16 + c16;
                short8 bk_ = *(const short8*)&KsL[cur][(row * 8 + ((ks * 4 + q) ^ pq)) * 8];
                acc_s[nt] = __builtin_amdgcn_mfma_f32_16x16x32_bf16(qu[ks], bk_, acc_s[nt], 0, 0, 0);
            }
#pragma unroll
            for (int jt = 0; jt < 5; ++jt) {
                int row = wm + jt * 16 + c16;
                short8 br_ = *(const short8*)&RwL[cur][(row * 8 + ((ks * 4 + q) ^ pq)) * 8];
                acc_b[jt] = __builtin_amdgcn_mfma_f32_16x16x32_bf16(qvv[ks], br_, acc_b[jt], 0, 0, 0);
            }
        }
        // ---- store Braw at col j-wm (wave-private rows; no barrier)
#pragma unroll
        for (int jt = 0; jt < 5; ++jt)
#pragma unroll
            for (int reg = 0; reg < 4; ++reg)
                Bp[trow + reg][jt * 16 + c16] = f2bs(acc_b[jt][reg]);

        // ---- rel-shift gather + online softmax
        float pmat[4][4];
        float alpha[4];
#pragma unroll
        for (int reg = 0; reg < 4; ++reg) {
            int t = trow + reg;
            float mrow = -1e30f;
#pragma unroll
            for (int nt = 0; nt < 4; ++nt) {
                int s = nt * 16 + c16;
                int jc = t - s + 63 - wm;   // [0,78]
                float sv = (acc_s[nt][reg] + bs2f(Bp[t][jc])) * 0.125f;
                pmat[nt][reg] = sv;
                mrow = fmaxf(mrow, sv);
            }
            mrow = fmaxf(mrow, __shfl_xor(mrow, 1));
            mrow = fmaxf(mrow, __shfl_xor(mrow, 2));
            mrow = fmaxf(mrow, __shfl_xor(mrow, 4));
            mrow = fmaxf(mrow, __shfl_xor(mrow, 8));
            float m_new = fmaxf(m_i[reg], mrow);
            alpha[reg] = __expf(m_i[reg] - m_new);
            float ps = 0.f;
#pragma unroll
            for (int nt = 0; nt < 4; ++nt) {
                float pe = __expf(pmat[nt][reg] - m_new);
                pmat[nt][reg] = pe;
                ps += pe;
            }
            ps += __shfl_xor(ps, 1);
            ps += __shfl_xor(ps, 2);
            ps += __shfl_xor(ps, 4);
            ps += __shfl_xor(ps, 8);
            l_i[reg] = l_i[reg] * alpha[reg] + ps;
            m_i[reg] = m_new;
        }
        // ---- write P over Bp cols 0..63 (wave-lockstep)
#pragma unroll
        for (int nt = 0; nt < 4; ++nt)
#pragma unroll
            for (int reg = 0; reg < 4; ++reg)
                Bp[trow + reg][nt * 16 + c16] = f2bs(pmat[nt][reg]);
#pragma unroll
        for (int dt = 0; dt < 4; ++dt)
#pragma unroll
            for (int reg = 0; reg < 4; ++reg)
                acc_o[dt][reg] *= alpha[reg];
        // ---- PV
#pragma unroll
        for (int ks = 0; ks < 2; ++ks) {
            int pq = c16 & 7;
            short8 ap = *(const short8*)&Bp[wm + c16][ks * 32 + q * 8];
#pragma unroll
            for (int dt = 0; dt < 4; ++dt) {
                int row = dt * 16 + c16;
                short8 bv_ = *(const short8*)&VtL[cur][(row * 8 + ((ks * 4 + q) ^ pq)) * 8];
                acc_o[dt] = __builtin_amdgcn_mfma_f32_16x16x32_bf16(ap, bv_, acc_o[dt], 0, 0, 0);
            }
        }
        cur ^= 1;
    }
#pragma unroll
    for (int reg = 0; reg < 4; ++reg) {
        float inv = 1.f / l_i[reg];
        int t = trow + reg;
#pragma unroll
        for (int dt = 0; dt < 4; ++dt)
            outb[baseo + (size_t)(t0 + t) * kD + dt * 16 + c16] = f2b(acc_o[dt][reg] * inv);
    }
}

// ---------------------------------------------------------------- scalar attention (slow path)
__global__ __launch_bounds__(256) void attn_kernel(
    const bf16* __restrict__ Qg, const bf16* __restrict__ Kg,
    const bf16* __restrict__ Vg, const bf16* __restrict__ Rg,
    const float* __restrict__ uu, const float* __restrict__ vvp,
    bf16* __restrict__ outb) {
    __shared__ float Qs[64][65];
    __shared__ bf16 Ps[64][66];
    __shared__ bf16 Ks[64][66];
    __shared__ bf16 Vs[64][66];
    __shared__ bf16 Rs[127][66];
    __shared__ float uf[64], vf[64];
    __shared__ float uK[64], vR[127];

    int tid = threadIdx.x;
    int qb = blockIdx.x, h = blockIdx.y, n = blockIdx.z;
    int t0 = qb * 64;
    size_t base = ((size_t)n * kT) * kD + (size_t)h * kDH;

    if (tid < 64) {
        uf[tid] = uu[h * 64 + tid];
        vf[tid] = vvp[h * 64 + tid];
    }
    for (int i = tid; i < 64 * 64; i += 256) {
        int r = i >> 6, d = i & 63;
        Qs[r][d] = b2f(Qg[base + (size_t)(t0 + r) * kD + d]);
    }
    int r = tid >> 2, seg = tid & 3;
    float m_i = -1e30f, l_i = 0.f;
    float Oa[16];
#pragma unroll
    for (int i = 0; i < 16; ++i) Oa[i] = 0.f;

    for (int kt = 0; kt < 16; ++kt) {
        int s0 = kt * 64;
        __syncthreads();
        for (int i = tid; i < 64 * 64; i += 256) {
            int s = i >> 6, d = i & 63;
            Ks[s][d] = Kg[base + (size_t)(s0 + s) * kD + d];
            Vs[s][d] = Vg[base + (size_t)(s0 + s) * kD + d];
        }
        int p_base = t0 - s0 + 960;
        for (int i = tid; i < 127 * 64; i += 256) {
            int j = i >> 6, d = i & 63;
            int p = p_base + j;
            p = p < 0 ? 0 : (p > 2046 ? 2046 : p);
            Rs[j][d] = Rg[(size_t)p * kD + h * kDH + d];
        }
        __syncthreads();
        if (tid < 64) {
            float s_ = 0.f;
            for (int d = 0; d < 64; ++d) s_ += uf[d] * b2f(Ks[tid][d]);
            uK[tid] = s_;
        } else if (tid < 64 + 127) {
            int j = tid - 64;
            float s_ = 0.f;
            for (int d = 0; d < 64; ++d) s_ += vf[d] * b2f(Rs[j][d]);
            vR[j] = s_;
        }
        __syncthreads();
        float sv[16];
        float smax = -1e30f;
#pragma unroll
        for (int jj = 0; jj < 16; ++jj) {
            int s = seg * 16 + jj;
            int j = r - s + 63;
            float acc = 0.f;
            for (int d = 0; d < 64; ++d)
                acc += Qs[r][d] * (b2f(Ks[s][d]) + b2f(Rs[j][d]));
            acc = (acc + uK[s] + vR[j]) * 0.125f;
            sv[jj] = acc;
            smax = fmaxf(smax, acc);
        }
        smax = fmaxf(smax, __shfl_xor(smax, 1));
        smax = fmaxf(smax, __shfl_xor(smax, 2));
        float m_new = fmaxf(m_i, smax);
        float alpha = __expf(m_i - m_new);
        float psum = 0.f;
#pragma unroll
        for (int jj = 0; jj < 16; ++jj) {
            float p = __expf(sv[jj] - m_new);
            Ps[r][seg * 16 + jj] = f2b(p);
            psum += p;
        }
        psum += __shfl_xor(psum, 1);
        psum += __shfl_xor(psum, 2);
        l_i = l_i * alpha + psum;
        m_i = m_new;
#pragma unroll
        for (int i = 0; i < 16; ++i) Oa[i] *= alpha;
        __syncthreads();
        for (int s = 0; s < 64; ++s) {
            float p = b2f(Ps[r][s]);
#pragma unroll
            for (int dd = 0; dd < 16; ++dd)
                Oa[dd] += p * b2f(Vs[s][seg * 16 + dd]);
        }
    }
    float inv = 1.f / l_i;
#pragma unroll
    for (int dd = 0; dd < 16; ++dd)
        outb[base + (size_t)(t0 + r) * kD + seg * 16 + dd] = f2b(Oa[dd] * inv);
}

// ---------------------------------------------------------------- GLU (slow path)
__global__ __launch_bounds__(256) void glu_kernel_v(const bf16* __restrict__ c,
                                                    bf16* __restrict__ out) {
    int i8 = (blockIdx.x * 256 + threadIdx.x) * 8;
    int row = i8 >> 9, d = i8 & 511;
    const short* cp = (const short*)c + (size_t)row * 1024;
    short8 a8 = *(const short8*)(cp + d);
    short8 g8 = *(const short8*)(cp + 512 + d);
    short8 o;
#pragma unroll
    for (int i = 0; i < 8; ++i) {
        float a = bs2f(a8[i]), g = bs2f(g8[i]);
        o[i] = f2bs(a / (1.f + __expf(-g)));
    }
    *(short8*)((short*)out + i8) = o;
}

// ---------------------------------------------------------------- fused GLU + depthwise conv + BN + SiLU
__global__ __launch_bounds__(256) void gluconv_kernel(
    const bf16* __restrict__ cbuf, const float* __restrict__ wt,
    const float* __restrict__ beff, bf16* __restrict__ outb) {
    __shared__ short gsm[94][72];
    __shared__ float wsm[31][64];
    __shared__ float bsm[64];
    int tid = threadIdx.x;
    int dg0 = blockIdx.x * 64;
    int t0  = blockIdx.y * 64;
    int n   = blockIdx.z;

#pragma unroll
    for (int it = 0; it < 3; ++it) {
        int idx = tid + it * 256;
        if (idx < 94 * 8) {
            int row = idx >> 3, cg = (idx & 7) * 8;
            int t = t0 - 15 + row;
            short8 o = {0, 0, 0, 0, 0, 0, 0, 0};
            if ((unsigned)t < (unsigned)kT) {
                const short* cp = (const short*)cbuf + ((size_t)n * kT + t) * 1024 + dg0 + cg;
                short8 a8 = *(const short8*)cp;
                short8 g8 = *(const short8*)(cp + 512);
#pragma unroll
                for (int i = 0; i < 8; ++i)
                    o[i] = f2bs(bs2f(a8[i]) / (1.f + __expf(-bs2f(g8[i]))));
            }
            *(short8*)&gsm[row][cg] = o;
        }
    }
#pragma unroll
    for (int it = 0; it < 8; ++it) {
        int i = tid + it * 256;
        if (i < 31 * 64) wsm[i >> 6][i & 63] = wt[(i >> 6) * kD + dg0 + (i & 63)];
    }
    if (tid < 64) bsm[tid] = beff[dg0 + tid];
    __syncthreads();

    int tl = tid >> 2, dgl = (tid & 3) * 16;
    float acc[16] = {};
#pragma unroll
    for (int k = 0; k < 31; ++k) {
        short8 g0 = *(const short8*)&gsm[tl + k][dgl];
        short8 g1 = *(const short8*)&gsm[tl + k][dgl + 8];
#pragma unroll
        for (int i = 0; i < 8; ++i) {
            acc[i]     += bs2f(g0[i]) * wsm[k][dgl + i];
            acc[8 + i] += bs2f(g1[i]) * wsm[k][dgl + 8 + i];
        }
    }
    short8 o0, o1;
#pragma unroll
    for (int i = 0; i < 8; ++i) {
        float h = acc[i] + bsm[dgl + i];
        o0[i] = f2bs(h / (1.f + __expf(-h)));
        h = acc[8 + i] + bsm[dgl + 8 + i];
        o1[i] = f2bs(h / (1.f + __expf(-h)));
    }
    short* op = (short*)outb + ((size_t)n * kT + t0 + tl) * kD + dg0 + dgl;
    *(short8*)op = o0;
    *(short8*)(op + 8) = o1;
}

// ---------------------------------------------------------------- scalar conv (slow path)
__global__ __launch_bounds__(256) void conv_kernel(
    const bf16* __restrict__ glu, const float* __restrict__ dw_w,
    const float* __restrict__ dw_b, const float* __restrict__ bn_g,
    const float* __restrict__ bn_b, bf16* __restrict__ outb) {
    int idx = blockIdx.x * 256 + threadIdx.x;
    int d = idx & 511;
    int t = (idx >> 9) & 1023;
    int n = idx >> 19;
    const bf16* gp = glu + ((size_t)n * kT) * kD + d;
    float acc = 0.f;
#pragma unroll
    for (int k = 0; k < 31; ++k) {
        int tt = t + k - 15;
        if ((unsigned)tt < (unsigned)kT)
            acc += b2f(gp[(size_t)tt * kD]) * dw_w[d * 31 + k];
    }
    acc += dw_b[d];
    acc = acc * bn_g[d] + bn_b[d];
    acc = acc / (1.f + __expf(-acc));
    outb[idx] = f2b(acc);
}

// ================================================================ launch
extern "C" void kernel_launch(void* const* d_in, const int* in_sizes, int n_in,
                              void* d_out, int out_size, void* d_ws, size_t ws_size,
                              hipStream_t stream) {
    const float* x      = (const float*)d_in[0];
    const float* rel_pe = (const float*)d_in[1];
    const float* ln1_g  = (const float*)d_in[2];
    const float* ln1_b  = (const float*)d_in[3];
    const float* ff1_w1 = (const float*)d_in[4];
    const float* ff1_b1 = (const float*)d_in[5];
    const float* ff1_w2 = (const float*)d_in[6];
    const float* ff1_b2 = (const float*)d_in[7];
    const float* an_g   = (const float*)d_in[8];
    const float* an_b   = (const float*)d_in[9];
    const float* wq = (const float*)d_in[10]; const float* bq = (const float*)d_in[11];
    const float* wk = (const float*)d_in[12]; const float* bk = (const float*)d_in[13];
    const float* wv = (const float*)d_in[14]; const float* bv = (const float*)d_in[15];
    const float* wo = (const float*)d_in[16]; const float* bo = (const float*)d_in[17];
    const float* pos_w = (const float*)d_in[18];
    const float* uu = (const float*)d_in[19]; const float* vvp = (const float*)d_in[20];
    const float* cn_g = (const float*)d_in[21]; const float* cn_b = (const float*)d_in[22];
    const float* pe_w = (const float*)d_in[23]; const float* pe_b = (const float*)d_in[24];
    const float* dw_w = (const float*)d_in[25]; const float* dw_b = (const float*)d_in[26];
    const float* bn_g = (const float*)d_in[27]; const float* bn_b = (const float*)d_in[28];
    const float* pc_w = (const float*)d_in[29]; const float* pc_b = (const float*)d_in[30];
    const float* ln2_g = (const float*)d_in[31]; const float* ln2_b = (const float*)d_in[32];
    const float* ff2_w1 = (const float*)d_in[33]; const float* ff2_b1 = (const float*)d_in[34];
    const float* ff2_w2 = (const float*)d_in[35]; const float* ff2_b2 = (const float*)d_in[36];
    const float* fn_g = (const float*)d_in[37]; const float* fn_b = (const float*)d_in[38];
    (void)n_in; (void)in_sizes;

    const int total = kROWS * kD;
    dim3 blk(256);
    const size_t MB = 1ull << 20;
    char* w = (char*)d_ws;

    if (ws_size >= 30 * MB) {
        // ================= FAST PATH (MFMA) =================
        float* xf      = (float*)(w);
        short* ff1_w1t = (short*)(w + 8 * MB);
        short* ff1_w2t = (short*)(w + 10 * MB);
        short* wqt     = (short*)(w + 12 * MB);
        short* wkt     = (short*)(w + 12 * MB + 512 * 1024);
        short* wvt     = (short*)(w + 13 * MB);
        short* wot     = (short*)(w + 13 * MB + 512 * 1024);
        short* poswt   = (short*)(w + 14 * MB);
        short* pewt    = (short*)(w + 14 * MB + 512 * 1024);
        short* pcwt    = (short*)(w + 15 * MB + 512 * 1024);
        short* ff2_w1t = (short*)(w + 16 * MB);
        short* ff2_w2t = (short*)(w + 18 * MB);
        char*  dyn     = w + 20 * MB;
        bf16* hchunk = (bf16*)dyn;
        bf16* Qb     = (bf16*)dyn;
        bf16* Kb     = (bf16*)(dyn + 4 * MB);
        bf16* Rb     = (bf16*)(dyn + 8 * MB);   // attention phase only
        bf16* cbuf   = (bf16*)dyn;
        float* dwt   = (float*)(dyn + 8 * MB);  // conv phase ONLY (aliases Rb!)
        float* beff  = (float*)(dyn + 8 * MB + 256 * 1024);
        bf16* nb     = (bf16*)d_out;
        bf16* Vtg    = (bf16*)d_out;                               // lo 4 MB (after qkv)
        bf16* convb  = (bf16*)d_out;
        bf16* Vb     = (bf16*)d_out + (size_t)kROWS * kD;          // hi 4 MB
        bf16* attnb  = Vb;                                         // hi 4 MB (after vtrans)

        // ---- all weight transposes in ONE launch
        WtArgs wa;
        const float* srcs[11] = {ff1_w1, ff1_w2, wq, wk, wv, wo, pos_w, pe_w, pc_w, ff2_w1, ff2_w2};
        short* dsts[11] = {ff1_w1t, ff1_w2t, wqt, wkt, wvt, wot, poswt, pewt, pcwt, ff2_w1t, ff2_w2t};
        int Ks_[11] = {512, 2048, 512, 512, 512, 512, 512, 512, 512, 512, 2048};
        int Ns_[11] = {2048, 512, 512, 512, 512, 512, 512, 1024, 512, 2048, 512};
        int cum = 0;
        for (int i = 0; i < 11; ++i) {
            wa.d[i].src = srcs[i]; wa.d[i].dst = dsts[i];
            wa.d[i].K = Ks_[i]; wa.d[i].N = Ns_[i]; wa.d[i].tstart = cum;
            cum += (Ns_[i] / 32) * (Ks_[i] / 32);
        }
        wt_all_kernel<<<cum, blk, 0, stream>>>(wa);

        // ---- macaron FF1
        ln_kernel_v<<<kROWS / 2, blk, 0, stream>>>(x, ln1_g, ln1_b, nb, 0);
        for (int c = 0; c < 2; ++c) {
            size_t off = (size_t)c * 2048 * kD;
            gemm_mfma64<<<dim3(kFFN / 64, 2048 / 64), blk, 0, stream>>>(
                nb + off, ff1_w1t, ff1_b1, nullptr, nullptr, hchunk,
                2048, kFFN, kD, ACT_SILU, 1.f, 0);
            gemm_mfma64<<<dim3(kD / 64, 2048 / 64), blk, 0, stream>>>(
                hchunk, ff1_w2t, ff1_b2, x + off, xf + off, nullptr,
                2048, kD, kFFN, ACT_NONE, 0.5f, 0);
        }

        // ---- RPE attention
        ln_kernel_v<<<kROWS / 2, blk, 0, stream>>>(xf, an_g, an_b, nb, 0);
        gemm_qkv<<<dim3(24, kROWS / 64), blk, 0, stream>>>(
            nb, wqt, bq, bk, bv, Qb, Kb, Vb);
        vtrans_kernel<<<dim3(16, 8, 4), blk, 0, stream>>>(Vb, Vtg);
        gemm_mfma64<<<dim3(kD / 64, (kP + 63) / 64), blk, 0, stream>>>(
            rel_pe, poswt, nullptr, nullptr, nullptr, Rb, kP, kD, kD, ACT_NONE, 1.f, 1);
        attn_mfma<<<dim3(kT / 64, kH, kN), blk, 0, stream>>>(Qb, Kb, Vtg, Rb, uu, vvp, attnb);
        gemm_mfma64<<<dim3(kD / 64, kROWS / 64), blk, 0, stream>>>(
            attnb, wot, bo, xf, xf, nullptr, kROWS, kD, kD, ACT_NONE, 1.f, 0);

        // ---- conv module (dwt MUST run after attention: dwt/beff alias Rb)
        dwt_kernel<<<62, blk, 0, stream>>>(dw_w, dw_b, bn_g, bn_b, dwt, beff);
        ln_kernel_v<<<kROWS / 2, blk, 0, stream>>>(xf, cn_g, cn_b, nb, 0);
        gemm_mfma64<<<dim3(2 * kD / 64, kROWS / 64), blk, 0, stream>>>(
            nb, pewt, pe_b, nullptr, nullptr, cbuf, kROWS, 2 * kD, kD, ACT_NONE, 1.f, 0);
        gluconv_kernel<<<dim3(8, 16, 4), blk, 0, stream>>>(cbuf, dwt, beff, convb);
        gemm_mfma64<<<dim3(kD / 64, kROWS / 64), blk, 0, stream>>>(
            convb, pcwt, pc_b, xf, xf, nullptr, kROWS, kD, kD, ACT_NONE, 1.f, 0);

        // ---- macaron FF2
        ln_kernel_v<<<kROWS / 2, blk, 0, stream>>>(xf, ln2_g, ln2_b, nb, 0);
        for (int c = 0; c < 2; ++c) {
            size_t off = (size_t)c * 2048 * kD;
            gemm_mfma64<<<dim3(kFFN / 64, 2048 / 64), blk, 0, stream>>>(
                nb + off, ff2_w1t, ff2_b1, nullptr, nullptr, hchunk,
                2048, kFFN, kD, ACT_SILU, 1.f, 0);
            gemm_mfma64<<<dim3(kD / 64, 2048 / 64), blk, 0, stream>>>(
                hchunk, ff2_w2t, ff2_b2, xf + off, xf + off, nullptr,
                2048, kD, kFFN, ACT_NONE, 0.5f, 0);
        }

        ln_kernel_v<<<kROWS / 2, blk, 0, stream>>>(xf, fn_g, fn_b, d_out, 1);
        return;
    }

    if (ws_size < 22 * MB) {
        stamp_kernel<<<(out_size + 255) / 256, blk, 0, stream>>>(
            (float*)d_out, out_size, 1000.f + (float)(ws_size / MB));
        return;
    }

    // ================= SLOW PATH (scalar, known-good) =================
    float* xf    = (float*)(w);
    bf16*  hbch  = (bf16*)(w + 8 * MB);
    bf16*  Qb    = (bf16*)(w + 8 * MB);
    bf16*  cbuf  = (bf16*)(w + 8 * MB);
    bf16*  convb = (bf16*)(w + 8 * MB);
    bf16*  Kb    = (bf16*)(w + 12 * MB);
    bf16*  Vb    = (bf16*)(w + 16 * MB);
    bf16*  glub  = (bf16*)(w + 16 * MB);
    bf16*  Rb    = (bf16*)(w + 20 * MB);
    bf16*  nb    = (bf16*)d_out;
    bf16*  attnb = (bf16*)d_out;

    cvt_kernel<<<total / 1024, blk, 0, stream>>>(x, xf, total / 4);

    ln_kernel<<<kROWS, blk, 0, stream>>>(xf, ln1_g, ln1_b, nb, 0);
    for (int c = 0; c < 4; ++c) {
        size_t off = (size_t)c * 1024 * kD;
        gemm_scalar<<<dim3(kFFN / 64, 1024 / 64), blk, 0, stream>>>(
            nb + off, ff1_w1, ff1_b1, nullptr, nullptr, hbch, 1024, kFFN, kD, ACT_SILU, 1.f, 0);
        gemm_scalar<<<dim3(kD / 64, 1024 / 64), blk, 0, stream>>>(
            hbch, ff1_w2, ff1_b2, xf + off, xf + off, nullptr, 1024, kD, kFFN, ACT_NONE, 0.5f, 0);
    }

    ln_kernel<<<kROWS, blk, 0, stream>>>(xf, an_g, an_b, nb, 0);
    gemm_scalar<<<dim3(kD / 64, kROWS / 64), blk, 0, stream>>>(
        nb, wq, bq, nullptr, nullptr, Qb, kROWS, kD, kD, ACT_NONE, 1.f, 0);
    gemm_scalar<<<dim3(kD / 64, kROWS / 64), blk, 0, stream>>>(
        nb, wk, bk, nullptr, nullptr, Kb, kROWS, kD, kD, ACT_NONE, 1.f, 0);
    gemm_scalar<<<dim3(kD / 64, kROWS / 64), blk, 0, stream>>>(
        nb, wv, bv, nullptr, nullptr, Vb, kROWS, kD, kD, ACT_NONE, 1.f, 0);
    gemm_scalar<<<dim3(kD / 64, (kP + 63) / 64), blk, 0, stream>>>(
        rel_pe, pos_w, nullptr, nullptr, nullptr, Rb, kP, kD, kD, ACT_NONE, 1.f, 1);
    attn_kernel<<<dim3(kT / 64, kH, kN), blk, 0, stream>>>(Qb, Kb, Vb, Rb, uu, vvp, attnb);
    gemm_scalar<<<dim3(kD / 64, kROWS / 64), blk, 0, stream>>>(
        attnb, wo, bo, xf, xf, nullptr, kROWS, kD, kD, ACT_NONE, 1.f, 0);

    ln_kernel<<<kROWS, blk, 0, stream>>>(xf, cn_g, cn_b, nb, 0);
    gemm_scalar<<<dim3(2 * kD / 64, kROWS / 64), blk, 0, stream>>>(
        nb, pe_w, pe_b, nullptr, nullptr, cbuf, kROWS, 2 * kD, kD, ACT_NONE, 1.f, 0);
    glu_kernel_v<<<total / 2048, blk, 0, stream>>>(cbuf, glub);
    conv_kernel<<<total / 256, blk, 0, stream>>>(glub, dw_w, dw_b, bn_g, bn_b, convb);
    gemm_scalar<<<dim3(kD / 64, kROWS / 64), blk, 0, stream>>>(
        convb, pc_w, pc_b, xf, xf, nullptr, kROWS, kD, kD, ACT_NONE, 1.f, 0);

    ln_kernel<<<kROWS, blk, 0, stream>>>(xf, ln2_g, ln2_b, nb, 0);
    for (int c = 0; c < 4; ++c) {
        size_t off = (size_t)c * 1024 * kD;
        gemm_scalar<<<dim3(kFFN / 64, 1024 / 64), blk, 0, stream>>>(
            nb + off, ff2_w1, ff2_b1, nullptr, nullptr, hbch, 1024, kFFN, kD, ACT_SILU, 1.f, 0);
        gemm_scalar<<<dim3(kD / 64, 1024 / 64), blk, 0, stream>>>(
            hbch, ff2_w2, ff2_b2, xf + off, xf + off, nullptr, 1024, kD, kFFN, ACT_NONE, 0.5f, 0);
    }

    ln_kernel<<<kROWS, blk, 0, stream>>>(xf, fn_g, fn_b, d_out, 1);
}

// Round 16
// 462.145 us; speedup vs baseline: 1.1234x; 1.0466x over previous
//
#include <hip/hip_runtime.h>
#include <hip/hip_bf16.h>

using bf16 = __hip_bfloat16;
typedef __attribute__((ext_vector_type(8))) short short8;
typedef __attribute__((ext_vector_type(4))) short short4v;
typedef __attribute__((ext_vector_type(4))) float f32x4;

static __device__ __forceinline__ float b2f(bf16 v) { return __bfloat162float(v); }
static __device__ __forceinline__ bf16  f2b(float v) { return __float2bfloat16(v); }
static __device__ __forceinline__ short f2bs(float x) {
    union { float f; unsigned u; } c; c.f = x;
    unsigned r = (c.u + 0x7FFFu + ((c.u >> 16) & 1u)) >> 16;
    return (short)r;
}
static __device__ __forceinline__ float bs2f(short s) {
    union { unsigned u; float f; } c; c.u = ((unsigned)(unsigned short)s) << 16;
    return c.f;
}
// async global->LDS, 16B per lane; LDS dst = wave-uniform base + lane*16
static __device__ __forceinline__ void gload16(const short* g, short* l) {
    __builtin_amdgcn_global_load_lds(
        (const __attribute__((address_space(1))) void*)g,
        (__attribute__((address_space(3))) void*)l, 16, 0, 0);
}

constexpr int kD   = 512;
constexpr int kT   = 1024;
constexpr int kN   = 4;
constexpr int kH   = 8;
constexpr int kDH  = 64;
constexpr int kFFN = 2048;
constexpr int kROWS = kN * kT;        // 4096
constexpr int kP    = 2 * kT - 1;     // 2047

#define ACT_NONE 0
#define ACT_SILU 1

// ---------------------------------------------------------------- fallback stamp
__global__ __launch_bounds__(256) void stamp_kernel(float* __restrict__ out, int n, float val) {
    int i = blockIdx.x * 256 + threadIdx.x;
    if (i < n) out[i] = (i == 0 ? val : 0.f);
}

// ---------------------------------------------------------------- copy (slow path only)
__global__ __launch_bounds__(256) void cvt_kernel(const float* __restrict__ in,
                                                  float* __restrict__ out, int n4) {
    int i = blockIdx.x * 256 + threadIdx.x;
    if (i < n4) ((f32x4*)out)[i] = ((const f32x4*)in)[i];
}

// ---------------------------------------------------------------- fused weight transpose
struct WtDesc { const float* src; short* dst; int K; int N; int tstart; };
struct WtArgs { WtDesc d[11]; };

__global__ __launch_bounds__(256) void wt_all_kernel(WtArgs a) {
    __shared__ float t[32][33];
    int bid = blockIdx.x;
    int i = 0;
#pragma unroll
    for (int j = 1; j < 11; ++j) if (bid >= a.d[j].tstart) i = j;
    const float* W = a.d[i].src;
    short* Wt = a.d[i].dst;
    int Kd = a.d[i].K, Nd = a.d[i].N;
    int lt = bid - a.d[i].tstart;
    int nx = Nd >> 5;
    int n0 = (lt % nx) * 32, k0 = (lt / nx) * 32;
    int tx = threadIdx.x & 31, ty = threadIdx.x >> 5;
#pragma unroll
    for (int it = 0; it < 4; ++it)
        t[ty + it * 8][tx] = W[(size_t)(k0 + ty + it * 8) * Nd + n0 + tx];
    __syncthreads();
#pragma unroll
    for (int it = 0; it < 4; ++it)
        Wt[(size_t)(n0 + ty + it * 8) * Kd + k0 + tx] = f2bs(t[tx][ty + it * 8]);
}

// ---------------------------------------------------------------- V transpose per (n,h)
__global__ __launch_bounds__(256) void vtrans_kernel(const bf16* __restrict__ V,
                                                     bf16* __restrict__ Vt) {
    __shared__ short ts[64][72];
    int tt = blockIdx.x, h = blockIdx.y, n = blockIdx.z;
    int tid = threadIdx.x;
    int r = tid >> 3, cg = (tid & 7) * 8;
#pragma unroll
    for (int it = 0; it < 2; ++it) {
        int row = it * 32 + r;
        *(short8*)&ts[row][cg] =
            *(const short8*)((const short*)V + ((size_t)n * kT + tt * 64 + row) * 512 + h * 64 + cg);
    }
    __syncthreads();
#pragma unroll
    for (int it = 0; it < 2; ++it) {
        int d = it * 32 + r;
        short8 o;
#pragma unroll
        for (int i = 0; i < 8; ++i) o[i] = ts[cg + i][d];
        *(short8*)((short*)Vt + ((size_t)(n * 8 + h) * 64 + d) * 1024 + tt * 64 + cg) = o;
    }
}

// ---------------------------------------------------------------- depthwise weight prep (fold BN)
__global__ __launch_bounds__(256) void dwt_kernel(const float* __restrict__ dw_w,
                                                  const float* __restrict__ dw_b,
                                                  const float* __restrict__ bn_g,
                                                  const float* __restrict__ bn_b,
                                                  float* __restrict__ wt,
                                                  float* __restrict__ beff) {
    int idx = blockIdx.x * 256 + threadIdx.x;
    if (idx < 31 * kD) {
        int d = idx & 511, k = idx >> 9;
        wt[k * kD + d] = dw_w[d * 31 + k] * bn_g[d];
    }
    if (idx < kD) beff[idx] = dw_b[idx] * bn_g[idx] + bn_b[idx];
}

// ---------------------------------------------------------------- layernorm, vectorized
__global__ __launch_bounds__(256) void ln_kernel_v(const float* __restrict__ xin,
                                                   const float* __restrict__ g,
                                                   const float* __restrict__ b,
                                                   void* __restrict__ outp, int out_f32) {
    int tid = threadIdx.x;
    int rh = tid >> 7;
    int tl = tid & 127;
    int row = blockIdx.x * 2 + rh;
    const float* xr = xin + (size_t)row * kD;
    f32x4 v = *(const f32x4*)(xr + tl * 4);
    float s  = v[0] + v[1] + v[2] + v[3];
    float sq = v[0]*v[0] + v[1]*v[1] + v[2]*v[2] + v[3]*v[3];
    for (int off = 32; off; off >>= 1) {
        s  += __shfl_down(s, off);
        sq += __shfl_down(sq, off);
    }
    __shared__ float ss[4], ssq[4], mean_s[2], rstd_s[2];
    int wid = tid >> 6;
    if ((tid & 63) == 0) { ss[wid] = s; ssq[wid] = sq; }
    __syncthreads();
    if (tid < 2) {
        float S  = ss[tid * 2] + ss[tid * 2 + 1];
        float SQ = ssq[tid * 2] + ssq[tid * 2 + 1];
        float m = S / (float)kD;
        float var = SQ / (float)kD - m * m;
        mean_s[tid] = m;
        rstd_s[tid] = rsqrtf(fmaxf(var, 0.f) + 1e-5f);
    }
    __syncthreads();
    float m = mean_s[rh], rs = rstd_s[rh];
    f32x4 gg = *(const f32x4*)(g + tl * 4);
    f32x4 bb = *(const f32x4*)(b + tl * 4);
    if (out_f32) {
        f32x4 o;
#pragma unroll
        for (int i = 0; i < 4; ++i) o[i] = (v[i] - m) * rs * gg[i] + bb[i];
        *(f32x4*)((float*)outp + (size_t)row * kD + tl * 4) = o;
    } else {
        short4v o;
#pragma unroll
        for (int i = 0; i < 4; ++i) o[i] = f2bs((v[i] - m) * rs * gg[i] + bb[i]);
        *(short4v*)((short*)outp + (size_t)row * kD + tl * 4) = o;
    }
}

// ---------------------------------------------------------------- layernorm (slow path)
__global__ __launch_bounds__(256) void ln_kernel(const float* __restrict__ xin,
                                                 const float* __restrict__ g,
                                                 const float* __restrict__ b,
                                                 void* __restrict__ outp, int out_f32) {
    int row = blockIdx.x;
    const float* xr = xin + (size_t)row * kD;
    int tid = threadIdx.x;
    float v0 = xr[tid], v1 = xr[tid + 256];
    float s = v0 + v1, sq = v0 * v0 + v1 * v1;
    for (int off = 32; off; off >>= 1) {
        s  += __shfl_down(s, off);
        sq += __shfl_down(sq, off);
    }
    __shared__ float ss[4], ssq[4];
    __shared__ float mean_s, rstd_s;
    int wid = tid >> 6, lane = tid & 63;
    if (lane == 0) { ss[wid] = s; ssq[wid] = sq; }
    __syncthreads();
    if (tid == 0) {
        float S  = ss[0] + ss[1] + ss[2] + ss[3];
        float SQ = ssq[0] + ssq[1] + ssq[2] + ssq[3];
        float m = S / (float)kD;
        float var = SQ / (float)kD - m * m;
        mean_s = m;
        rstd_s = rsqrtf(fmaxf(var, 0.f) + 1e-5f);
    }
    __syncthreads();
    float m = mean_s, rs = rstd_s;
    float o0 = (v0 - m) * rs * g[tid]       + b[tid];
    float o1 = (v1 - m) * rs * g[tid + 256] + b[tid + 256];
    size_t i0 = (size_t)row * kD + tid, i1 = i0 + 256;
    if (out_f32) {
        ((float*)outp)[i0] = o0; ((float*)outp)[i1] = o1;
    } else {
        ((bf16*)outp)[i0] = f2b(o0); ((bf16*)outp)[i1] = f2b(o1);
    }
}

// ---------------------------------------------------------------- MFMA GEMM, 64x64 tile (dbuf async)
__global__ __launch_bounds__(256, 4) void gemm_mfma64(
    const void* __restrict__ A, const short* __restrict__ Bt,
    const float* __restrict__ bias, const float* __restrict__ residual,
    float* __restrict__ outf, bf16* __restrict__ outb,
    int M, int N, int K, int act, float scale, int a_f32) {
    __shared__ short As[2][4096];
    __shared__ short Bs[2][4096];
    int tid = threadIdx.x;
    int m0 = blockIdx.y * 64, n0 = blockIdx.x * 64;
    int wid = tid >> 6, lane = tid & 63;
    int wm = (wid >> 1) * 32, wn = (wid & 1) * 32;
    int q = lane >> 4, c16 = lane & 15;

    f32x4 zero4 = {0.f, 0.f, 0.f, 0.f};
    f32x4 acc[2][2] = {{zero4, zero4}, {zero4, zero4}};

    int arow = lane >> 3;
    int aseg = (lane & 7) ^ arow;

    auto issueA = [&](int buf, int k0) {
        if (!a_f32) {
#pragma unroll
            for (int it = 0; it < 2; ++it) {
                int rbase = (wid * 2 + it) * 8;
                gload16((const short*)A + (size_t)(m0 + rbase + arow) * K + k0 + aseg * 8,
                        &As[buf][(wid * 2 + it) * 512]);
            }
        } else {
            int srow = tid >> 3, sseg = tid & 7;
#pragma unroll
            for (int it = 0; it < 2; ++it) {
                int row = it * 32 + srow;
                int rr = m0 + row;
                short8 v = {0, 0, 0, 0, 0, 0, 0, 0};
                if (rr < M) {
                    const float* ap = (const float*)A + (size_t)rr * K + k0 + sseg * 8;
                    f32x4 x0 = *(const f32x4*)ap;
                    f32x4 x1 = *(const f32x4*)(ap + 4);
                    v[0] = f2bs(x0[0]); v[1] = f2bs(x0[1]); v[2] = f2bs(x0[2]); v[3] = f2bs(x0[3]);
                    v[4] = f2bs(x1[0]); v[5] = f2bs(x1[1]); v[6] = f2bs(x1[2]); v[7] = f2bs(x1[3]);
                }
                *(short8*)&As[buf][(row * 8 + (sseg ^ (row & 7))) * 8] = v;
            }
        }
    };
    auto issueB = [&](int buf, int k0) {
#pragma unroll
        for (int it = 0; it < 2; ++it) {
            int rbase = (wid * 2 + it) * 8;
            gload16(Bt + (size_t)(n0 + rbase + arow) * K + k0 + aseg * 8,
                    &Bs[buf][(wid * 2 + it) * 512]);
        }
    };

    issueA(0, 0);
    issueB(0, 0);
    int cur = 0;
    for (int k0 = 0; k0 < K; k0 += 64) {
        __syncthreads();
        if (k0 + 64 < K) {
            issueA(cur ^ 1, k0 + 64);
            issueB(cur ^ 1, k0 + 64);
        }
#pragma unroll
        for (int ks = 0; ks < 2; ++ks) {
            int p = c16 & 7;
            short8 af[2], bfr[2];
#pragma unroll
            for (int mt = 0; mt < 2; ++mt) {
                int row = wm + mt * 16 + c16;
                af[mt] = *(const short8*)&As[cur][(row * 8 + ((ks * 4 + q) ^ p)) * 8];
            }
#pragma unroll
            for (int nt = 0; nt < 2; ++nt) {
                int row = wn + nt * 16 + c16;
                bfr[nt] = *(const short8*)&Bs[cur][(row * 8 + ((ks * 4 + q) ^ p)) * 8];
            }
#pragma unroll
            for (int mt = 0; mt < 2; ++mt)
#pragma unroll
                for (int nt = 0; nt < 2; ++nt)
                    acc[mt][nt] = __builtin_amdgcn_mfma_f32_16x16x32_bf16(
                        af[mt], bfr[nt], acc[mt][nt], 0, 0, 0);
        }
        cur ^= 1;
    }
#pragma unroll
    for (int mt = 0; mt < 2; ++mt) {
#pragma unroll
        for (int reg = 0; reg < 4; ++reg) {
            int r = m0 + wm + mt * 16 + q * 4 + reg;
            if (r >= M) continue;
#pragma unroll
            for (int nt = 0; nt < 2; ++nt) {
                int c = n0 + wn + nt * 16 + c16;
                float h = acc[mt][nt][reg];
                if (bias) h += bias[c];
                if (act == ACT_SILU) h = h / (1.f + __expf(-h));
                h *= scale;
                size_t idx = (size_t)r * N + c;
                if (residual) h += residual[idx];
                if (outf) outf[idx] = h;
                if (outb) outb[idx] = f2b(h);
            }
        }
    }
}

// ---------------------------------------------------------------- MFMA GEMM, 32x64 tile (dbuf async)
// For the FF down-projections (M=2048, N=512, K=2048): 64-row tiles give only
// 256 blocks = 1 block/CU (grid-starved, latency-bound). 32-row tiles double
// the grid to 512 = 2 blocks/CU. 24 KB LDS.
__global__ __launch_bounds__(256, 4) void gemm_mfma32(
    const bf16* __restrict__ A, const short* __restrict__ Bt,
    const float* __restrict__ bias, const float* __restrict__ residual,
    float* __restrict__ outf, bf16* __restrict__ outb,
    int M, int N, int K, int act, float scale) {
    __shared__ short As[2][2048];   // 32x64 swizzled
    __shared__ short Bs[2][4096];   // 64x64 swizzled
    int tid = threadIdx.x;
    int m0 = blockIdx.y * 32, n0 = blockIdx.x * 64;
    int wid = tid >> 6, lane = tid & 63;
    int wm = (wid >> 1) * 16, wn = (wid & 1) * 32;
    int q = lane >> 4, c16 = lane & 15;

    f32x4 zero4 = {0.f, 0.f, 0.f, 0.f};
    f32x4 acc[2] = {zero4, zero4};

    int arow = lane >> 3;
    int aseg = (lane & 7) ^ arow;

    auto issue = [&](int buf, int k0) {
        // A: 4 groups of 8 rows; wave wid loads group wid
        gload16((const short*)A + (size_t)(m0 + wid * 8 + arow) * K + k0 + aseg * 8,
                &As[buf][wid * 512]);
        // B: 8 groups; wave wid loads groups wid*2, wid*2+1
#pragma unroll
        for (int it = 0; it < 2; ++it) {
            int g = wid * 2 + it;
            gload16(Bt + (size_t)(n0 + g * 8 + arow) * K + k0 + aseg * 8,
                    &Bs[buf][g * 512]);
        }
    };

    issue(0, 0);
    int cur = 0;
    for (int k0 = 0; k0 < K; k0 += 64) {
        __syncthreads();
        if (k0 + 64 < K) issue(cur ^ 1, k0 + 64);
#pragma unroll
        for (int ks = 0; ks < 2; ++ks) {
            int p = c16 & 7;
            int rowA = wm + c16;
            short8 af = *(const short8*)&As[cur][(rowA * 8 + ((ks * 4 + q) ^ p)) * 8];
#pragma unroll
            for (int nt = 0; nt < 2; ++nt) {
                int row = wn + nt * 16 + c16;
                short8 bfr = *(const short8*)&Bs[cur][(row * 8 + ((ks * 4 + q) ^ p)) * 8];
                acc[nt] = __builtin_amdgcn_mfma_f32_16x16x32_bf16(af, bfr, acc[nt], 0, 0, 0);
            }
        }
        cur ^= 1;
    }
#pragma unroll
    for (int reg = 0; reg < 4; ++reg) {
        int r = m0 + wm + q * 4 + reg;
#pragma unroll
        for (int nt = 0; nt < 2; ++nt) {
            int c = n0 + wn + nt * 16 + c16;
            float h = acc[nt][reg];
            if (bias) h += bias[c];
            if (act == ACT_SILU) h = h / (1.f + __expf(-h));
            h *= scale;
            size_t idx = (size_t)r * N + c;
            if (residual) h += residual[idx];
            if (outf) outf[idx] = h;
            if (outb) outb[idx] = f2b(h);
        }
    }
}

// ---------------------------------------------------------------- fused QKV GEMM (dbuf async)
__global__ __launch_bounds__(256, 4) void gemm_qkv(
    const bf16* __restrict__ A, const short* __restrict__ Bt,
    const float* __restrict__ bq, const float* __restrict__ bk,
    const float* __restrict__ bv,
    bf16* __restrict__ Qb, bf16* __restrict__ Kb, bf16* __restrict__ Vb) {
    const int K = kD;
    __shared__ short As[2][4096];
    __shared__ short Bs[2][4096];
    int tid = threadIdx.x;
    int m0 = blockIdx.y * 64, n0 = blockIdx.x * 64;
    int seg = blockIdx.x >> 3;
    const float* bias = seg == 0 ? bq : (seg == 1 ? bk : bv);
    bf16* outb = seg == 0 ? Qb : (seg == 1 ? Kb : Vb);
    int ns0 = n0 & 511;
    int wid = tid >> 6, lane = tid & 63;
    int wm = (wid >> 1) * 32, wn = (wid & 1) * 32;
    int q = lane >> 4, c16 = lane & 15;

    f32x4 zero4 = {0.f, 0.f, 0.f, 0.f};
    f32x4 acc[2][2] = {{zero4, zero4}, {zero4, zero4}};
    int arow = lane >> 3;
    int aseg = (lane & 7) ^ arow;

    auto issue = [&](int buf, int k0) {
#pragma unroll
        for (int it = 0; it < 2; ++it) {
            int rbase = (wid * 2 + it) * 8;
            gload16((const short*)A + (size_t)(m0 + rbase + arow) * K + k0 + aseg * 8,
                    &As[buf][(wid * 2 + it) * 512]);
            gload16(Bt + (size_t)(n0 + rbase + arow) * K + k0 + aseg * 8,
                    &Bs[buf][(wid * 2 + it) * 512]);
        }
    };

    issue(0, 0);
    int cur = 0;
    for (int k0 = 0; k0 < K; k0 += 64) {
        __syncthreads();
        if (k0 + 64 < K) issue(cur ^ 1, k0 + 64);
#pragma unroll
        for (int ks = 0; ks < 2; ++ks) {
            int p = c16 & 7;
            short8 af[2], bfr[2];
#pragma unroll
            for (int mt = 0; mt < 2; ++mt) {
                int row = wm + mt * 16 + c16;
                af[mt] = *(const short8*)&As[cur][(row * 8 + ((ks * 4 + q) ^ p)) * 8];
            }
#pragma unroll
            for (int nt = 0; nt < 2; ++nt) {
                int row = wn + nt * 16 + c16;
                bfr[nt] = *(const short8*)&Bs[cur][(row * 8 + ((ks * 4 + q) ^ p)) * 8];
            }
#pragma unroll
            for (int mt = 0; mt < 2; ++mt)
#pragma unroll
                for (int nt = 0; nt < 2; ++nt)
                    acc[mt][nt] = __builtin_amdgcn_mfma_f32_16x16x32_bf16(
                        af[mt], bfr[nt], acc[mt][nt], 0, 0, 0);
        }
        cur ^= 1;
    }
#pragma unroll
    for (int mt = 0; mt < 2; ++mt)
#pragma unroll
        for (int reg = 0; reg < 4; ++reg) {
            int r = m0 + wm + mt * 16 + q * 4 + reg;
#pragma unroll
            for (int nt = 0; nt < 2; ++nt) {
                int c = ns0 + wn + nt * 16 + c16;
                outb[(size_t)r * 512 + c] = f2b(acc[mt][nt][reg] + bias[c]);
            }
        }
}

// ---------------------------------------------------------------- scalar GEMM (slow fallback)
__global__ __launch_bounds__(256) void gemm_scalar(
    const void* __restrict__ A, const float* __restrict__ W,
    const float* __restrict__ bias, const float* __restrict__ residual,
    float* __restrict__ outf, bf16* __restrict__ outb,
    int M, int N, int K, int act, float scale, int a_f32) {
    __shared__ float As[16][65];
    __shared__ float Bs[16][65];
    int tid = threadIdx.x;
    int tx = tid & 15, ty = tid >> 4;
    int row0 = blockIdx.y * 64, col0 = blockIdx.x * 64;
    float acc[4][4] = {};
    for (int k0 = 0; k0 < K; k0 += 16) {
        for (int i = tid; i < 64 * 16; i += 256) {
            int r = i >> 4, c = i & 15;
            int rr = row0 + r;
            float v = 0.f;
            if (rr < M) {
                size_t idx = (size_t)rr * K + k0 + c;
                v = a_f32 ? ((const float*)A)[idx] : b2f(((const bf16*)A)[idx]);
            }
            As[c][r] = v;
        }
        for (int i = tid; i < 16 * 64; i += 256) {
            int r = i >> 6, c = i & 63;
            Bs[r][c] = W[(size_t)(k0 + r) * N + col0 + c];
        }
        __syncthreads();
#pragma unroll
        for (int kk = 0; kk < 16; ++kk) {
            float a[4], b[4];
#pragma unroll
            for (int i = 0; i < 4; ++i) a[i] = As[kk][ty * 4 + i];
#pragma unroll
            for (int j = 0; j < 4; ++j) b[j] = Bs[kk][tx * 4 + j];
#pragma unroll
            for (int i = 0; i < 4; ++i)
#pragma unroll
                for (int j = 0; j < 4; ++j) acc[i][j] += a[i] * b[j];
        }
        __syncthreads();
    }
#pragma unroll
    for (int i = 0; i < 4; ++i) {
        int r = row0 + ty * 4 + i;
        if (r >= M) continue;
#pragma unroll
        for (int j = 0; j < 4; ++j) {
            int c = col0 + tx * 4 + j;
            float h = acc[i][j];
            if (bias) h += bias[c];
            if (act == ACT_SILU) h = h / (1.f + __expf(-h));
            h *= scale;
            size_t idx = (size_t)r * N + c;
            if (residual) h += residual[idx];
            if (outf) outf[idx] = h;
            if (outb) outb[idx] = f2b(h);
        }
    }
}

// ---------------------------------------------------------------- MFMA RPE attention (single-buffer, best measured)
// Q(+u)/Q(+v) fragments in registers; K/Vt/R staged via async gload16 into
// XOR-swizzled unpadded tiles; Bp trimmed to wave-local j window. 43 KB LDS.
__global__ __launch_bounds__(256, 3) void attn_mfma(
    const bf16* __restrict__ Qg, const bf16* __restrict__ Kg,
    const bf16* __restrict__ Vtg, const bf16* __restrict__ Rg,
    const float* __restrict__ uu, const float* __restrict__ vvp,
    bf16* __restrict__ outb) {
    __shared__ short KsL[4096];    // 64x64 swizzled
    __shared__ short VtL[4096];    // 64x64 swizzled
    __shared__ short RwL[8192];    // 128x64 swizzled
    __shared__ short Bp[64][88];   // Braw (cols 0..79 = j-wm), then P (cols 0..63)

    int tid = threadIdx.x;
    int qb = blockIdx.x, h = blockIdx.y, n = blockIdx.z;
    int t0 = qb * 64;
    size_t baseq = ((size_t)n * kT) * 512 + (size_t)h * kDH;
    size_t basev = ((size_t)(n * 8 + h) * 64) * 1024;
    size_t baseo = ((size_t)n * kT) * kD + (size_t)h * kDH;

    int wid = tid >> 6, lane = tid & 63;
    int q = lane >> 4, c16 = lane & 15;
    int wm = wid * 16;
    int trow = wm + q * 4;

    // ---- Q fragments with u,v folded, in registers (constant across kt)
    short8 qu[2], qvv[2];
    {
        const short* qp = (const short*)Qg + baseq + (size_t)(t0 + wm + c16) * 512;
#pragma unroll
        for (int ks = 0; ks < 2; ++ks) {
            short8 q8 = *(const short8*)(qp + ks * 32 + q * 8);
            const float* up = uu + h * 64 + ks * 32 + q * 8;
            const float* vp = vvp + h * 64 + ks * 32 + q * 8;
#pragma unroll
            for (int i = 0; i < 8; ++i) {
                float xq = bs2f(q8[i]);
                qu[ks][i]  = f2bs(xq + up[i]);
                qvv[ks][i] = f2bs(xq + vp[i]);
            }
        }
    }

    int arow = lane >> 3;
    int aseg = (lane & 7) ^ arow;

    f32x4 zero4 = {0.f, 0.f, 0.f, 0.f};
    f32x4 acc_o[4] = {zero4, zero4, zero4, zero4};
    float m_i[4] = {-1e30f, -1e30f, -1e30f, -1e30f};
    float l_i[4] = {0.f, 0.f, 0.f, 0.f};

    for (int kt = 0; kt < 16; ++kt) {
        int s0 = kt * 64;
        __syncthreads();   // prev iter's LDS reads done
        // ---- async staging: K (2/wave), Vt (2/wave), R (4/wave)
#pragma unroll
        for (int it = 0; it < 2; ++it) {
            int g = wid * 2 + it;
            gload16((const short*)Kg + baseq + (size_t)(s0 + g * 8 + arow) * 512 + aseg * 8,
                    KsL + g * 512);
            gload16((const short*)Vtg + basev + (size_t)(g * 8 + arow) * 1024 + s0 + aseg * 8,
                    VtL + g * 512);
        }
        int p_base = t0 - s0 + 960;
#pragma unroll
        for (int it = 0; it < 4; ++it) {
            int g = wid * 4 + it;
            int j = g * 8 + arow;
            int p = p_base + j;
            p = p < 0 ? 0 : (p > 2046 ? 2046 : p);
            gload16((const short*)Rg + (size_t)p * kD + h * kDH + aseg * 8,
                    RwL + g * 512);
        }
        __syncthreads();   // drain

        // ---- MFMA: S_qk = Qu K^T (4), Braw = Qv Rw^T (5, B-trim), per ks
        f32x4 acc_s[4] = {zero4, zero4, zero4, zero4};
        f32x4 acc_b[5] = {zero4, zero4, zero4, zero4, zero4};
#pragma unroll
        for (int ks = 0; ks < 2; ++ks) {
            int pq = c16 & 7;
#pragma unroll
            for (int nt = 0; nt < 4; ++nt) {
                int row = nt * 16 + c16;
                short8 bk_ = *(const short8*)&KsL[(row * 8 + ((ks * 4 + q) ^ pq)) * 8];
                acc_s[nt] = __builtin_amdgcn_mfma_f32_16x16x32_bf16(qu[ks], bk_, acc_s[nt], 0, 0, 0);
            }
#pragma unroll
            for (int jt = 0; jt < 5; ++jt) {
                int row = wm + jt * 16 + c16;
                short8 br_ = *(const short8*)&RwL[(row * 8 + ((ks * 4 + q) ^ pq)) * 8];
                acc_b[jt] = __builtin_amdgcn_mfma_f32_16x16x32_bf16(qvv[ks], br_, acc_b[jt], 0, 0, 0);
            }
        }
        // ---- store Braw at col j-wm (wave-private rows; no barrier)
#pragma unroll
        for (int jt = 0; jt < 5; ++jt)
#pragma unroll
            for (int reg = 0; reg < 4; ++reg)
                Bp[trow + reg][jt * 16 + c16] = f2bs(acc_b[jt][reg]);

        // ---- rel-shift gather + online softmax
        float pmat[4][4];
        float alpha[4];
#pragma unroll
        for (int reg = 0; reg < 4; ++reg) {
            int t = trow + reg;
            float mrow = -1e30f;
#pragma unroll
            for (int nt = 0; nt < 4; ++nt) {
                int s = nt * 16 + c16;
                int jc = t - s + 63 - wm;   // [0,78]
                float sv = (acc_s[nt][reg] + bs2f(Bp[t][jc])) * 0.125f;
                pmat[nt][reg] = sv;
                mrow = fmaxf(mrow, sv);
            }
            mrow = fmaxf(mrow, __shfl_xor(mrow, 1));
            mrow = fmaxf(mrow, __shfl_xor(mrow, 2));
            mrow = fmaxf(mrow, __shfl_xor(mrow, 4));
            mrow = fmaxf(mrow, __shfl_xor(mrow, 8));
            float m_new = fmaxf(m_i[reg], mrow);
            alpha[reg] = __expf(m_i[reg] - m_new);
            float ps = 0.f;
#pragma unroll
            for (int nt = 0; nt < 4; ++nt) {
                float pe = __expf(pmat[nt][reg] - m_new);
                pmat[nt][reg] = pe;
                ps += pe;
            }
            ps += __shfl_xor(ps, 1);
            ps += __shfl_xor(ps, 2);
            ps += __shfl_xor(ps, 4);
            ps += __shfl_xor(ps, 8);
            l_i[reg] = l_i[reg] * alpha[reg] + ps;
            m_i[reg] = m_new;
        }
        // ---- write P over Bp cols 0..63 (wave-lockstep)
#pragma unroll
        for (int nt = 0; nt < 4; ++nt)
#pragma unroll
            for (int reg = 0; reg < 4; ++reg)
                Bp[trow + reg][nt * 16 + c16] = f2bs(pmat[nt][reg]);
#pragma unroll
        for (int dt = 0; dt < 4; ++dt)
#pragma unroll
            for (int reg = 0; reg < 4; ++reg)
                acc_o[dt][reg] *= alpha[reg];
        // ---- PV
#pragma unroll
        for (int ks = 0; ks < 2; ++ks) {
            int pq = c16 & 7;
            short8 ap = *(const short8*)&Bp[wm + c16][ks * 32 + q * 8];
#pragma unroll
            for (int dt = 0; dt < 4; ++dt) {
                int row = dt * 16 + c16;
                short8 bv_ = *(const short8*)&VtL[(row * 8 + ((ks * 4 + q) ^ pq)) * 8];
                acc_o[dt] = __builtin_amdgcn_mfma_f32_16x16x32_bf16(ap, bv_, acc_o[dt], 0, 0, 0);
            }
        }
    }
#pragma unroll
    for (int reg = 0; reg < 4; ++reg) {
        float inv = 1.f / l_i[reg];
        int t = trow + reg;
#pragma unroll
        for (int dt = 0; dt < 4; ++dt)
            outb[baseo + (size_t)(t0 + t) * kD + dt * 16 + c16] = f2b(acc_o[dt][reg] * inv);
    }
}

// ---------------------------------------------------------------- scalar attention (slow path)
__global__ __launch_bounds__(256) void attn_kernel(
    const bf16* __restrict__ Qg, const bf16* __restrict__ Kg,
    const bf16* __restrict__ Vg, const bf16* __restrict__ Rg,
    const float* __restrict__ uu, const float* __restrict__ vvp,
    bf16* __restrict__ outb) {
    __shared__ float Qs[64][65];
    __shared__ bf16 Ps[64][66];
    __shared__ bf16 Ks[64][66];
    __shared__ bf16 Vs[64][66];
    __shared__ bf16 Rs[127][66];
    __shared__ float uf[64], vf[64];
    __shared__ float uK[64], vR[127];

    int tid = threadIdx.x;
    int qb = blockIdx.x, h = blockIdx.y, n = blockIdx.z;
    int t0 = qb * 64;
    size_t base = ((size_t)n * kT) * kD + (size_t)h * kDH;

    if (tid < 64) {
        uf[tid] = uu[h * 64 + tid];
        vf[tid] = vvp[h * 64 + tid];
    }
    for (int i = tid; i < 64 * 64; i += 256) {
        int r = i >> 6, d = i & 63;
        Qs[r][d] = b2f(Qg[base + (size_t)(t0 + r) * kD + d]);
    }
    int r = tid >> 2, seg = tid & 3;
    float m_i = -1e30f, l_i = 0.f;
    float Oa[16];
#pragma unroll
    for (int i = 0; i < 16; ++i) Oa[i] = 0.f;

    for (int kt = 0; kt < 16; ++kt) {
        int s0 = kt * 64;
        __syncthreads();
        for (int i = tid; i < 64 * 64; i += 256) {
            int s = i >> 6, d = i & 63;
            Ks[s][d] = Kg[base + (size_t)(s0 + s) * kD + d];
            Vs[s][d] = Vg[base + (size_t)(s0 + s) * kD + d];
        }
        int p_base = t0 - s0 + 960;
        for (int i = tid; i < 127 * 64; i += 256) {
            int j = i >> 6, d = i & 63;
            int p = p_base + j;
            p = p < 0 ? 0 : (p > 2046 ? 2046 : p);
            Rs[j][d] = Rg[(size_t)p * kD + h * kDH + d];
        }
        __syncthreads();
        if (tid < 64) {
            float s_ = 0.f;
            for (int d = 0; d < 64; ++d) s_ += uf[d] * b2f(Ks[tid][d]);
            uK[tid] = s_;
        } else if (tid < 64 + 127) {
            int j = tid - 64;
            float s_ = 0.f;
            for (int d = 0; d < 64; ++d) s_ += vf[d] * b2f(Rs[j][d]);
            vR[j] = s_;
        }
        __syncthreads();
        float sv[16];
        float smax = -1e30f;
#pragma unroll
        for (int jj = 0; jj < 16; ++jj) {
            int s = seg * 16 + jj;
            int j = r - s + 63;
            float acc = 0.f;
            for (int d = 0; d < 64; ++d)
                acc += Qs[r][d] * (b2f(Ks[s][d]) + b2f(Rs[j][d]));
            acc = (acc + uK[s] + vR[j]) * 0.125f;
            sv[jj] = acc;
            smax = fmaxf(smax, acc);
        }
        smax = fmaxf(smax, __shfl_xor(smax, 1));
        smax = fmaxf(smax, __shfl_xor(smax, 2));
        float m_new = fmaxf(m_i, smax);
        float alpha = __expf(m_i - m_new);
        float psum = 0.f;
#pragma unroll
        for (int jj = 0; jj < 16; ++jj) {
            float p = __expf(sv[jj] - m_new);
            Ps[r][seg * 16 + jj] = f2b(p);
            psum += p;
        }
        psum += __shfl_xor(psum, 1);
        psum += __shfl_xor(psum, 2);
        l_i = l_i * alpha + psum;
        m_i = m_new;
#pragma unroll
        for (int i = 0; i < 16; ++i) Oa[i] *= alpha;
        __syncthreads();
        for (int s = 0; s < 64; ++s) {
            float p = b2f(Ps[r][s]);
#pragma unroll
            for (int dd = 0; dd < 16; ++dd)
                Oa[dd] += p * b2f(Vs[s][seg * 16 + dd]);
        }
    }
    float inv = 1.f / l_i;
#pragma unroll
    for (int dd = 0; dd < 16; ++dd)
        outb[base + (size_t)(t0 + r) * kD + seg * 16 + dd] = f2b(Oa[dd] * inv);
}

// ---------------------------------------------------------------- GLU (slow path)
__global__ __launch_bounds__(256) void glu_kernel_v(const bf16* __restrict__ c,
                                                    bf16* __restrict__ out) {
    int i8 = (blockIdx.x * 256 + threadIdx.x) * 8;
    int row = i8 >> 9, d = i8 & 511;
    const short* cp = (const short*)c + (size_t)row * 1024;
    short8 a8 = *(const short8*)(cp + d);
    short8 g8 = *(const short8*)(cp + 512 + d);
    short8 o;
#pragma unroll
    for (int i = 0; i < 8; ++i) {
        float a = bs2f(a8[i]), g = bs2f(g8[i]);
        o[i] = f2bs(a / (1.f + __expf(-g)));
    }
    *(short8*)((short*)out + i8) = o;
}

// ---------------------------------------------------------------- fused GLU + depthwise conv + BN + SiLU
__global__ __launch_bounds__(256) void gluconv_kernel(
    const bf16* __restrict__ cbuf, const float* __restrict__ wt,
    const float* __restrict__ beff, bf16* __restrict__ outb) {
    __shared__ short gsm[94][72];
    __shared__ float wsm[31][64];
    __shared__ float bsm[64];
    int tid = threadIdx.x;
    int dg0 = blockIdx.x * 64;
    int t0  = blockIdx.y * 64;
    int n   = blockIdx.z;

#pragma unroll
    for (int it = 0; it < 3; ++it) {
        int idx = tid + it * 256;
        if (idx < 94 * 8) {
            int row = idx >> 3, cg = (idx & 7) * 8;
            int t = t0 - 15 + row;
            short8 o = {0, 0, 0, 0, 0, 0, 0, 0};
            if ((unsigned)t < (unsigned)kT) {
                const short* cp = (const short*)cbuf + ((size_t)n * kT + t) * 1024 + dg0 + cg;
                short8 a8 = *(const short8*)cp;
                short8 g8 = *(const short8*)(cp + 512);
#pragma unroll
                for (int i = 0; i < 8; ++i)
                    o[i] = f2bs(bs2f(a8[i]) / (1.f + __expf(-bs2f(g8[i]))));
            }
            *(short8*)&gsm[row][cg] = o;
        }
    }
#pragma unroll
    for (int it = 0; it < 8; ++it) {
        int i = tid + it * 256;
        if (i < 31 * 64) wsm[i >> 6][i & 63] = wt[(i >> 6) * kD + dg0 + (i & 63)];
    }
    if (tid < 64) bsm[tid] = beff[dg0 + tid];
    __syncthreads();

    int tl = tid >> 2, dgl = (tid & 3) * 16;
    float acc[16] = {};
#pragma unroll
    for (int k = 0; k < 31; ++k) {
        short8 g0 = *(const short8*)&gsm[tl + k][dgl];
        short8 g1 = *(const short8*)&gsm[tl + k][dgl + 8];
#pragma unroll
        for (int i = 0; i < 8; ++i) {
            acc[i]     += bs2f(g0[i]) * wsm[k][dgl + i];
            acc[8 + i] += bs2f(g1[i]) * wsm[k][dgl + 8 + i];
        }
    }
    short8 o0, o1;
#pragma unroll
    for (int i = 0; i < 8; ++i) {
        float h = acc[i] + bsm[dgl + i];
        o0[i] = f2bs(h / (1.f + __expf(-h)));
        h = acc[8 + i] + bsm[dgl + 8 + i];
        o1[i] = f2bs(h / (1.f + __expf(-h)));
    }
    short* op = (short*)outb + ((size_t)n * kT + t0 + tl) * kD + dg0 + dgl;
    *(short8*)op = o0;
    *(short8*)(op + 8) = o1;
}

// ---------------------------------------------------------------- scalar conv (slow path)
__global__ __launch_bounds__(256) void conv_kernel(
    const bf16* __restrict__ glu, const float* __restrict__ dw_w,
    const float* __restrict__ dw_b, const float* __restrict__ bn_g,
    const float* __restrict__ bn_b, bf16* __restrict__ outb) {
    int idx = blockIdx.x * 256 + threadIdx.x;
    int d = idx & 511;
    int t = (idx >> 9) & 1023;
    int n = idx >> 19;
    const bf16* gp = glu + ((size_t)n * kT) * kD + d;
    float acc = 0.f;
#pragma unroll
    for (int k = 0; k < 31; ++k) {
        int tt = t + k - 15;
        if ((unsigned)tt < (unsigned)kT)
            acc += b2f(gp[(size_t)tt * kD]) * dw_w[d * 31 + k];
    }
    acc += dw_b[d];
    acc = acc * bn_g[d] + bn_b[d];
    acc = acc / (1.f + __expf(-acc));
    outb[idx] = f2b(acc);
}

// ================================================================ launch
extern "C" void kernel_launch(void* const* d_in, const int* in_sizes, int n_in,
                              void* d_out, int out_size, void* d_ws, size_t ws_size,
                              hipStream_t stream) {
    const float* x      = (const float*)d_in[0];
    const float* rel_pe = (const float*)d_in[1];
    const float* ln1_g  = (const float*)d_in[2];
    const float* ln1_b  = (const float*)d_in[3];
    const float* ff1_w1 = (const float*)d_in[4];
    const float* ff1_b1 = (const float*)d_in[5];
    const float* ff1_w2 = (const float*)d_in[6];
    const float* ff1_b2 = (const float*)d_in[7];
    const float* an_g   = (const float*)d_in[8];
    const float* an_b   = (const float*)d_in[9];
    const float* wq = (const float*)d_in[10]; const float* bq = (const float*)d_in[11];
    const float* wk = (const float*)d_in[12]; const float* bk = (const float*)d_in[13];
    const float* wv = (const float*)d_in[14]; const float* bv = (const float*)d_in[15];
    const float* wo = (const float*)d_in[16]; const float* bo = (const float*)d_in[17];
    const float* pos_w = (const float*)d_in[18];
    const float* uu = (const float*)d_in[19]; const float* vvp = (const float*)d_in[20];
    const float* cn_g = (const float*)d_in[21]; const float* cn_b = (const float*)d_in[22];
    const float* pe_w = (const float*)d_in[23]; const float* pe_b = (const float*)d_in[24];
    const float* dw_w = (const float*)d_in[25]; const float* dw_b = (const float*)d_in[26];
    const float* bn_g = (const float*)d_in[27]; const float* bn_b = (const float*)d_in[28];
    const float* pc_w = (const float*)d_in[29]; const float* pc_b = (const float*)d_in[30];
    const float* ln2_g = (const float*)d_in[31]; const float* ln2_b = (const float*)d_in[32];
    const float* ff2_w1 = (const float*)d_in[33]; const float* ff2_b1 = (const float*)d_in[34];
    const float* ff2_w2 = (const float*)d_in[35]; const float* ff2_b2 = (const float*)d_in[36];
    const float* fn_g = (const float*)d_in[37]; const float* fn_b = (const float*)d_in[38];
    (void)n_in; (void)in_sizes;

    const int total = kROWS * kD;
    dim3 blk(256);
    const size_t MB = 1ull << 20;
    char* w = (char*)d_ws;

    if (ws_size >= 30 * MB) {
        // ================= FAST PATH (MFMA) =================
        float* xf      = (float*)(w);
        short* ff1_w1t = (short*)(w + 8 * MB);
        short* ff1_w2t = (short*)(w + 10 * MB);
        short* wqt     = (short*)(w + 12 * MB);
        short* wkt     = (short*)(w + 12 * MB + 512 * 1024);
        short* wvt     = (short*)(w + 13 * MB);
        short* wot     = (short*)(w + 13 * MB + 512 * 1024);
        short* poswt   = (short*)(w + 14 * MB);
        short* pewt    = (short*)(w + 14 * MB + 512 * 1024);
        short* pcwt    = (short*)(w + 15 * MB + 512 * 1024);
        short* ff2_w1t = (short*)(w + 16 * MB);
        short* ff2_w2t = (short*)(w + 18 * MB);
        char*  dyn     = w + 20 * MB;
        bf16* hchunk = (bf16*)dyn;
        bf16* Qb     = (bf16*)dyn;
        bf16* Kb     = (bf16*)(dyn + 4 * MB);
        bf16* Rb     = (bf16*)(dyn + 8 * MB);   // attention phase only
        bf16* cbuf   = (bf16*)dyn;
        float* dwt   = (float*)(dyn + 8 * MB);  // conv phase ONLY (aliases Rb!)
        float* beff  = (float*)(dyn + 8 * MB + 256 * 1024);
        bf16* nb     = (bf16*)d_out;
        bf16* Vtg    = (bf16*)d_out;                               // lo 4 MB (after qkv)
        bf16* convb  = (bf16*)d_out;
        bf16* Vb     = (bf16*)d_out + (size_t)kROWS * kD;          // hi 4 MB
        bf16* attnb  = Vb;                                         // hi 4 MB (after vtrans)

        // ---- all weight transposes in ONE launch
        WtArgs wa;
        const float* srcs[11] = {ff1_w1, ff1_w2, wq, wk, wv, wo, pos_w, pe_w, pc_w, ff2_w1, ff2_w2};
        short* dsts[11] = {ff1_w1t, ff1_w2t, wqt, wkt, wvt, wot, poswt, pewt, pcwt, ff2_w1t, ff2_w2t};
        int Ks_[11] = {512, 2048, 512, 512, 512, 512, 512, 512, 512, 512, 2048};
        int Ns_[11] = {2048, 512, 512, 512, 512, 512, 512, 1024, 512, 2048, 512};
        int cum = 0;
        for (int i = 0; i < 11; ++i) {
            wa.d[i].src = srcs[i]; wa.d[i].dst = dsts[i];
            wa.d[i].K = Ks_[i]; wa.d[i].N = Ns_[i]; wa.d[i].tstart = cum;
            cum += (Ns_[i] / 32) * (Ks_[i] / 32);
        }
        wt_all_kernel<<<cum, blk, 0, stream>>>(wa);

        // ---- macaron FF1 (down-proj uses 32-row tiles: 2x grid occupancy)
        ln_kernel_v<<<kROWS / 2, blk, 0, stream>>>(x, ln1_g, ln1_b, nb, 0);
        for (int c = 0; c < 2; ++c) {
            size_t off = (size_t)c * 2048 * kD;
            gemm_mfma64<<<dim3(kFFN / 64, 2048 / 64), blk, 0, stream>>>(
                nb + off, ff1_w1t, ff1_b1, nullptr, nullptr, hchunk,
                2048, kFFN, kD, ACT_SILU, 1.f, 0);
            gemm_mfma32<<<dim3(kD / 64, 2048 / 32), blk, 0, stream>>>(
                hchunk, ff1_w2t, ff1_b2, x + off, xf + off, nullptr,
                2048, kD, kFFN, ACT_NONE, 0.5f);
        }

        // ---- RPE attention
        ln_kernel_v<<<kROWS / 2, blk, 0, stream>>>(xf, an_g, an_b, nb, 0);
        gemm_qkv<<<dim3(24, kROWS / 64), blk, 0, stream>>>(
            nb, wqt, bq, bk, bv, Qb, Kb, Vb);
        vtrans_kernel<<<dim3(16, 8, 4), blk, 0, stream>>>(Vb, Vtg);
        gemm_mfma64<<<dim3(kD / 64, (kP + 63) / 64), blk, 0, stream>>>(
            rel_pe, poswt, nullptr, nullptr, nullptr, Rb, kP, kD, kD, ACT_NONE, 1.f, 1);
        attn_mfma<<<dim3(kT / 64, kH, kN), blk, 0, stream>>>(Qb, Kb, Vtg, Rb, uu, vvp, attnb);
        gemm_mfma64<<<dim3(kD / 64, kROWS / 64), blk, 0, stream>>>(
            attnb, wot, bo, xf, xf, nullptr, kROWS, kD, kD, ACT_NONE, 1.f, 0);

        // ---- conv module (dwt MUST run after attention: dwt/beff alias Rb)
        dwt_kernel<<<62, blk, 0, stream>>>(dw_w, dw_b, bn_g, bn_b, dwt, beff);
        ln_kernel_v<<<kROWS / 2, blk, 0, stream>>>(xf, cn_g, cn_b, nb, 0);
        gemm_mfma64<<<dim3(2 * kD / 64, kROWS / 64), blk, 0, stream>>>(
            nb, pewt, pe_b, nullptr, nullptr, cbuf, kROWS, 2 * kD, kD, ACT_NONE, 1.f, 0);
        gluconv_kernel<<<dim3(8, 16, 4), blk, 0, stream>>>(cbuf, dwt, beff, convb);
        gemm_mfma64<<<dim3(kD / 64, kROWS / 64), blk, 0, stream>>>(
            convb, pcwt, pc_b, xf, xf, nullptr, kROWS, kD, kD, ACT_NONE, 1.f, 0);

        // ---- macaron FF2
        ln_kernel_v<<<kROWS / 2, blk, 0, stream>>>(xf, ln2_g, ln2_b, nb, 0);
        for (int c = 0; c < 2; ++c) {
            size_t off = (size_t)c * 2048 * kD;
            gemm_mfma64<<<dim3(kFFN / 64, 2048 / 64), blk, 0, stream>>>(
                nb + off, ff2_w1t, ff2_b1, nullptr, nullptr, hchunk,
                2048, kFFN, kD, ACT_SILU, 1.f, 0);
            gemm_mfma32<<<dim3(kD / 64, 2048 / 32), blk, 0, stream>>>(
                hchunk, ff2_w2t, ff2_b2, xf + off, xf + off, nullptr,
                2048, kD, kFFN, ACT_NONE, 0.5f);
        }

        ln_kernel_v<<<kROWS / 2, blk, 0, stream>>>(xf, fn_g, fn_b, d_out, 1);
        return;
    }

    if (ws_size < 22 * MB) {
        stamp_kernel<<<(out_size + 255) / 256, blk, 0, stream>>>(
            (float*)d_out, out_size, 1000.f + (float)(ws_size / MB));
        return;
    }

    // ================= SLOW PATH (scalar, known-good) =================
    float* xf    = (float*)(w);
    bf16*  hbch  = (bf16*)(w + 8 * MB);
    bf16*  Qb    = (bf16*)(w + 8 * MB);
    bf16*  cbuf  = (bf16*)(w + 8 * MB);
    bf16*  convb = (bf16*)(w + 8 * MB);
    bf16*  Kb    = (bf16*)(w + 12 * MB);
    bf16*  Vb    = (bf16*)(w + 16 * MB);
    bf16*  glub  = (bf16*)(w + 16 * MB);
    bf16*  Rb    = (bf16*)(w + 20 * MB);
    bf16*  nb    = (bf16*)d_out;
    bf16*  attnb = (bf16*)d_out;

    cvt_kernel<<<total / 1024, blk, 0, stream>>>(x, xf, total / 4);

    ln_kernel<<<kROWS, blk, 0, stream>>>(xf, ln1_g, ln1_b, nb, 0);
    for (int c = 0; c < 4; ++c) {
        size_t off = (size_t)c * 1024 * kD;
        gemm_scalar<<<dim3(kFFN / 64, 1024 / 64), blk, 0, stream>>>(
            nb + off, ff1_w1, ff1_b1, nullptr, nullptr, hbch, 1024, kFFN, kD, ACT_SILU, 1.f, 0);
        gemm_scalar<<<dim3(kD / 64, 1024 / 64), blk, 0, stream>>>(
            hbch, ff1_w2, ff1_b2, xf + off, xf + off, nullptr, 1024, kD, kFFN, ACT_NONE, 0.5f, 0);
    }

    ln_kernel<<<kROWS, blk, 0, stream>>>(xf, an_g, an_b, nb, 0);
    gemm_scalar<<<dim3(kD / 64, kROWS / 64), blk, 0, stream>>>(
        nb, wq, bq, nullptr, nullptr, Qb, kROWS, kD, kD, ACT_NONE, 1.f, 0);
    gemm_scalar<<<dim3(kD / 64, kROWS / 64), blk, 0, stream>>>(
        nb, wk, bk, nullptr, nullptr, Kb, kROWS, kD, kD, ACT_NONE, 1.f, 0);
    gemm_scalar<<<dim3(kD / 64, kROWS / 64), blk, 0, stream>>>(
        nb, wv, bv, nullptr, nullptr, Vb, kROWS, kD, kD, ACT_NONE, 1.f, 0);
    gemm_scalar<<<dim3(kD / 64, (kP + 63) / 64), blk, 0, stream>>>(
        rel_pe, pos_w, nullptr, nullptr, nullptr, Rb, kP, kD, kD, ACT_NONE, 1.f, 1);
    attn_kernel<<<dim3(kT / 64, kH, kN), blk, 0, stream>>>(Qb, Kb, Vb, Rb, uu, vvp, attnb);
    gemm_scalar<<<dim3(kD / 64, kROWS / 64), blk, 0, stream>>>(
        attnb, wo, bo, xf, xf, nullptr, kROWS, kD, kD, ACT_NONE, 1.f, 0);

    ln_kernel<<<kROWS, blk, 0, stream>>>(xf, cn_g, cn_b, nb, 0);
    gemm_scalar<<<dim3(2 * kD / 64, kROWS / 64), blk, 0, stream>>>(
        nb, pe_w, pe_b, nullptr, nullptr, cbuf, kROWS, 2 * kD, kD, ACT_NONE, 1.f, 0);
    glu_kernel_v<<<total / 2048, blk, 0, stream>>>(cbuf, glub);
    conv_kernel<<<total / 256, blk, 0, stream>>>(glub, dw_w, dw_b, bn_g, bn_b, convb);
    gemm_scalar<<<dim3(kD / 64, kROWS / 64), blk, 0, stream>>>(
        convb, pc_w, pc_b, xf, xf, nullptr, kROWS, kD, kD, ACT_NONE, 1.f, 0);

    ln_kernel<<<kROWS, blk, 0, stream>>>(xf, ln2_g, ln2_b, nb, 0);
    for (int c = 0; c < 4; ++c) {
        size_t off = (size_t)c * 1024 * kD;
        gemm_scalar<<<dim3(kFFN / 64, 1024 / 64), blk, 0, stream>>>(
            nb + off, ff2_w1, ff2_b1, nullptr, nullptr, hbch, 1024, kFFN, kD, ACT_SILU, 1.f, 0);
        gemm_scalar<<<dim3(kD / 64, 1024 / 64), blk, 0, stream>>>(
            hbch, ff2_w2, ff2_b2, xf + off, xf + off, nullptr, 1024, kD, kFFN, ACT_NONE, 0.5f, 0);
    }

    ln_kernel<<<kROWS, blk, 0, stream>>>(xf, fn_g, fn_b, d_out, 1);
}

// Round 17
// 460.429 us; speedup vs baseline: 1.1276x; 1.0037x over previous
//
#include <hip/hip_runtime.h>
#include <hip/hip_bf16.h>

using bf16 = __hip_bfloat16;
typedef __attribute__((ext_vector_type(8))) short short8;
typedef __attribute__((ext_vector_type(4))) short short4v;
typedef __attribute__((ext_vector_type(4))) float f32x4;

static __device__ __forceinline__ float b2f(bf16 v) { return __bfloat162float(v); }
static __device__ __forceinline__ bf16  f2b(float v) { return __float2bfloat16(v); }
static __device__ __forceinline__ short f2bs(float x) {
    union { float f; unsigned u; } c; c.f = x;
    unsigned r = (c.u + 0x7FFFu + ((c.u >> 16) & 1u)) >> 16;
    return (short)r;
}
static __device__ __forceinline__ float bs2f(short s) {
    union { unsigned u; float f; } c; c.u = ((unsigned)(unsigned short)s) << 16;
    return c.f;
}
// async global->LDS, 16B per lane; LDS dst = wave-uniform base + lane*16
static __device__ __forceinline__ void gload16(const short* g, short* l) {
    __builtin_amdgcn_global_load_lds(
        (const __attribute__((address_space(1))) void*)g,
        (__attribute__((address_space(3))) void*)l, 16, 0, 0);
}

constexpr int kD   = 512;
constexpr int kT   = 1024;
constexpr int kN   = 4;
constexpr int kH   = 8;
constexpr int kDH  = 64;
constexpr int kFFN = 2048;
constexpr int kROWS = kN * kT;        // 4096
constexpr int kP    = 2 * kT - 1;     // 2047

#define ACT_NONE 0
#define ACT_SILU 1

// ---------------------------------------------------------------- fallback stamp
__global__ __launch_bounds__(256) void stamp_kernel(float* __restrict__ out, int n, float val) {
    int i = blockIdx.x * 256 + threadIdx.x;
    if (i < n) out[i] = (i == 0 ? val : 0.f);
}

// ---------------------------------------------------------------- copy (slow path only)
__global__ __launch_bounds__(256) void cvt_kernel(const float* __restrict__ in,
                                                  float* __restrict__ out, int n4) {
    int i = blockIdx.x * 256 + threadIdx.x;
    if (i < n4) ((f32x4*)out)[i] = ((const f32x4*)in)[i];
}

// ---------------------------------------------------------------- fused weight transpose
struct WtDesc { const float* src; short* dst; int K; int N; int tstart; };
struct WtArgs { WtDesc d[11]; };

__global__ __launch_bounds__(256) void wt_all_kernel(WtArgs a) {
    __shared__ float t[32][33];
    int bid = blockIdx.x;
    int i = 0;
#pragma unroll
    for (int j = 1; j < 11; ++j) if (bid >= a.d[j].tstart) i = j;
    const float* W = a.d[i].src;
    short* Wt = a.d[i].dst;
    int Kd = a.d[i].K, Nd = a.d[i].N;
    int lt = bid - a.d[i].tstart;
    int nx = Nd >> 5;
    int n0 = (lt % nx) * 32, k0 = (lt / nx) * 32;
    int tx = threadIdx.x & 31, ty = threadIdx.x >> 5;
#pragma unroll
    for (int it = 0; it < 4; ++it)
        t[ty + it * 8][tx] = W[(size_t)(k0 + ty + it * 8) * Nd + n0 + tx];
    __syncthreads();
#pragma unroll
    for (int it = 0; it < 4; ++it)
        Wt[(size_t)(n0 + ty + it * 8) * Kd + k0 + tx] = f2bs(t[tx][ty + it * 8]);
}

// ---------------------------------------------------------------- V transpose per (n,h)
__global__ __launch_bounds__(256) void vtrans_kernel(const bf16* __restrict__ V,
                                                     bf16* __restrict__ Vt) {
    __shared__ short ts[64][72];
    int tt = blockIdx.x, h = blockIdx.y, n = blockIdx.z;
    int tid = threadIdx.x;
    int r = tid >> 3, cg = (tid & 7) * 8;
#pragma unroll
    for (int it = 0; it < 2; ++it) {
        int row = it * 32 + r;
        *(short8*)&ts[row][cg] =
            *(const short8*)((const short*)V + ((size_t)n * kT + tt * 64 + row) * 512 + h * 64 + cg);
    }
    __syncthreads();
#pragma unroll
    for (int it = 0; it < 2; ++it) {
        int d = it * 32 + r;
        short8 o;
#pragma unroll
        for (int i = 0; i < 8; ++i) o[i] = ts[cg + i][d];
        *(short8*)((short*)Vt + ((size_t)(n * 8 + h) * 64 + d) * 1024 + tt * 64 + cg) = o;
    }
}

// ---------------------------------------------------------------- depthwise weight prep (fold BN)
__global__ __launch_bounds__(256) void dwt_kernel(const float* __restrict__ dw_w,
                                                  const float* __restrict__ dw_b,
                                                  const float* __restrict__ bn_g,
                                                  const float* __restrict__ bn_b,
                                                  float* __restrict__ wt,
                                                  float* __restrict__ beff) {
    int idx = blockIdx.x * 256 + threadIdx.x;
    if (idx < 31 * kD) {
        int d = idx & 511, k = idx >> 9;
        wt[k * kD + d] = dw_w[d * 31 + k] * bn_g[d];
    }
    if (idx < kD) beff[idx] = dw_b[idx] * bn_g[idx] + bn_b[idx];
}

// ---------------------------------------------------------------- layernorm, vectorized
__global__ __launch_bounds__(256) void ln_kernel_v(const float* __restrict__ xin,
                                                   const float* __restrict__ g,
                                                   const float* __restrict__ b,
                                                   void* __restrict__ outp, int out_f32) {
    int tid = threadIdx.x;
    int rh = tid >> 7;
    int tl = tid & 127;
    int row = blockIdx.x * 2 + rh;
    const float* xr = xin + (size_t)row * kD;
    f32x4 v = *(const f32x4*)(xr + tl * 4);
    float s  = v[0] + v[1] + v[2] + v[3];
    float sq = v[0]*v[0] + v[1]*v[1] + v[2]*v[2] + v[3]*v[3];
    for (int off = 32; off; off >>= 1) {
        s  += __shfl_down(s, off);
        sq += __shfl_down(sq, off);
    }
    __shared__ float ss[4], ssq[4], mean_s[2], rstd_s[2];
    int wid = tid >> 6;
    if ((tid & 63) == 0) { ss[wid] = s; ssq[wid] = sq; }
    __syncthreads();
    if (tid < 2) {
        float S  = ss[tid * 2] + ss[tid * 2 + 1];
        float SQ = ssq[tid * 2] + ssq[tid * 2 + 1];
        float m = S / (float)kD;
        float var = SQ / (float)kD - m * m;
        mean_s[tid] = m;
        rstd_s[tid] = rsqrtf(fmaxf(var, 0.f) + 1e-5f);
    }
    __syncthreads();
    float m = mean_s[rh], rs = rstd_s[rh];
    f32x4 gg = *(const f32x4*)(g + tl * 4);
    f32x4 bb = *(const f32x4*)(b + tl * 4);
    if (out_f32) {
        f32x4 o;
#pragma unroll
        for (int i = 0; i < 4; ++i) o[i] = (v[i] - m) * rs * gg[i] + bb[i];
        *(f32x4*)((float*)outp + (size_t)row * kD + tl * 4) = o;
    } else {
        short4v o;
#pragma unroll
        for (int i = 0; i < 4; ++i) o[i] = f2bs((v[i] - m) * rs * gg[i] + bb[i]);
        *(short4v*)((short*)outp + (size_t)row * kD + tl * 4) = o;
    }
}

// ---------------------------------------------------------------- layernorm (slow path)
__global__ __launch_bounds__(256) void ln_kernel(const float* __restrict__ xin,
                                                 const float* __restrict__ g,
                                                 const float* __restrict__ b,
                                                 void* __restrict__ outp, int out_f32) {
    int row = blockIdx.x;
    const float* xr = xin + (size_t)row * kD;
    int tid = threadIdx.x;
    float v0 = xr[tid], v1 = xr[tid + 256];
    float s = v0 + v1, sq = v0 * v0 + v1 * v1;
    for (int off = 32; off; off >>= 1) {
        s  += __shfl_down(s, off);
        sq += __shfl_down(sq, off);
    }
    __shared__ float ss[4], ssq[4];
    __shared__ float mean_s, rstd_s;
    int wid = tid >> 6, lane = tid & 63;
    if (lane == 0) { ss[wid] = s; ssq[wid] = sq; }
    __syncthreads();
    if (tid == 0) {
        float S  = ss[0] + ss[1] + ss[2] + ss[3];
        float SQ = ssq[0] + ssq[1] + ssq[2] + ssq[3];
        float m = S / (float)kD;
        float var = SQ / (float)kD - m * m;
        mean_s = m;
        rstd_s = rsqrtf(fmaxf(var, 0.f) + 1e-5f);
    }
    __syncthreads();
    float m = mean_s, rs = rstd_s;
    float o0 = (v0 - m) * rs * g[tid]       + b[tid];
    float o1 = (v1 - m) * rs * g[tid + 256] + b[tid + 256];
    size_t i0 = (size_t)row * kD + tid, i1 = i0 + 256;
    if (out_f32) {
        ((float*)outp)[i0] = o0; ((float*)outp)[i1] = o1;
    } else {
        ((bf16*)outp)[i0] = f2b(o0); ((bf16*)outp)[i1] = f2b(o1);
    }
}

// ---------------------------------------------------------------- MFMA GEMM, 64x64 tile (dbuf async)
__global__ __launch_bounds__(256, 4) void gemm_mfma64(
    const void* __restrict__ A, const short* __restrict__ Bt,
    const float* __restrict__ bias, const float* __restrict__ residual,
    float* __restrict__ outf, bf16* __restrict__ outb,
    int M, int N, int K, int act, float scale, int a_f32) {
    __shared__ short As[2][4096];
    __shared__ short Bs[2][4096];
    int tid = threadIdx.x;
    int m0 = blockIdx.y * 64, n0 = blockIdx.x * 64;
    int wid = tid >> 6, lane = tid & 63;
    int wm = (wid >> 1) * 32, wn = (wid & 1) * 32;
    int q = lane >> 4, c16 = lane & 15;

    f32x4 zero4 = {0.f, 0.f, 0.f, 0.f};
    f32x4 acc[2][2] = {{zero4, zero4}, {zero4, zero4}};

    int arow = lane >> 3;
    int aseg = (lane & 7) ^ arow;

    auto issueA = [&](int buf, int k0) {
        if (!a_f32) {
#pragma unroll
            for (int it = 0; it < 2; ++it) {
                int rbase = (wid * 2 + it) * 8;
                gload16((const short*)A + (size_t)(m0 + rbase + arow) * K + k0 + aseg * 8,
                        &As[buf][(wid * 2 + it) * 512]);
            }
        } else {
            int srow = tid >> 3, sseg = tid & 7;
#pragma unroll
            for (int it = 0; it < 2; ++it) {
                int row = it * 32 + srow;
                int rr = m0 + row;
                short8 v = {0, 0, 0, 0, 0, 0, 0, 0};
                if (rr < M) {
                    const float* ap = (const float*)A + (size_t)rr * K + k0 + sseg * 8;
                    f32x4 x0 = *(const f32x4*)ap;
                    f32x4 x1 = *(const f32x4*)(ap + 4);
                    v[0] = f2bs(x0[0]); v[1] = f2bs(x0[1]); v[2] = f2bs(x0[2]); v[3] = f2bs(x0[3]);
                    v[4] = f2bs(x1[0]); v[5] = f2bs(x1[1]); v[6] = f2bs(x1[2]); v[7] = f2bs(x1[3]);
                }
                *(short8*)&As[buf][(row * 8 + (sseg ^ (row & 7))) * 8] = v;
            }
        }
    };
    auto issueB = [&](int buf, int k0) {
#pragma unroll
        for (int it = 0; it < 2; ++it) {
            int rbase = (wid * 2 + it) * 8;
            gload16(Bt + (size_t)(n0 + rbase + arow) * K + k0 + aseg * 8,
                    &Bs[buf][(wid * 2 + it) * 512]);
        }
    };

    issueA(0, 0);
    issueB(0, 0);
    int cur = 0;
    for (int k0 = 0; k0 < K; k0 += 64) {
        __syncthreads();
        if (k0 + 64 < K) {
            issueA(cur ^ 1, k0 + 64);
            issueB(cur ^ 1, k0 + 64);
        }
#pragma unroll
        for (int ks = 0; ks < 2; ++ks) {
            int p = c16 & 7;
            short8 af[2], bfr[2];
#pragma unroll
            for (int mt = 0; mt < 2; ++mt) {
                int row = wm + mt * 16 + c16;
                af[mt] = *(const short8*)&As[cur][(row * 8 + ((ks * 4 + q) ^ p)) * 8];
            }
#pragma unroll
            for (int nt = 0; nt < 2; ++nt) {
                int row = wn + nt * 16 + c16;
                bfr[nt] = *(const short8*)&Bs[cur][(row * 8 + ((ks * 4 + q) ^ p)) * 8];
            }
#pragma unroll
            for (int mt = 0; mt < 2; ++mt)
#pragma unroll
                for (int nt = 0; nt < 2; ++nt)
                    acc[mt][nt] = __builtin_amdgcn_mfma_f32_16x16x32_bf16(
                        af[mt], bfr[nt], acc[mt][nt], 0, 0, 0);
        }
        cur ^= 1;
    }
#pragma unroll
    for (int mt = 0; mt < 2; ++mt) {
#pragma unroll
        for (int reg = 0; reg < 4; ++reg) {
            int r = m0 + wm + mt * 16 + q * 4 + reg;
            if (r >= M) continue;
#pragma unroll
            for (int nt = 0; nt < 2; ++nt) {
                int c = n0 + wn + nt * 16 + c16;
                float h = acc[mt][nt][reg];
                if (bias) h += bias[c];
                if (act == ACT_SILU) h = h / (1.f + __expf(-h));
                h *= scale;
                size_t idx = (size_t)r * N + c;
                if (residual) h += residual[idx];
                if (outf) outf[idx] = h;
                if (outb) outb[idx] = f2b(h);
            }
        }
    }
}

// ---------------------------------------------------------------- MFMA GEMM, 32x64 tile (dbuf async)
// For M-heavy, N=512 GEMMs: doubles grid vs 64-row tiles (2->4 blocks/CU for
// M=4096; 1->2 for M=2048/2047). 24 KB LDS. a_f32: guarded VGPR staging.
__global__ __launch_bounds__(256, 4) void gemm_mfma32(
    const void* __restrict__ A, const short* __restrict__ Bt,
    const float* __restrict__ bias, const float* __restrict__ residual,
    float* __restrict__ outf, bf16* __restrict__ outb,
    int M, int N, int K, int act, float scale, int a_f32) {
    __shared__ short As[2][2048];   // 32x64 swizzled
    __shared__ short Bs[2][4096];   // 64x64 swizzled
    int tid = threadIdx.x;
    int m0 = blockIdx.y * 32, n0 = blockIdx.x * 64;
    int wid = tid >> 6, lane = tid & 63;
    int wm = (wid >> 1) * 16, wn = (wid & 1) * 32;
    int q = lane >> 4, c16 = lane & 15;

    f32x4 zero4 = {0.f, 0.f, 0.f, 0.f};
    f32x4 acc[2] = {zero4, zero4};

    int arow = lane >> 3;
    int aseg = (lane & 7) ^ arow;

    auto issue = [&](int buf, int k0) {
        if (!a_f32) {
            // A: 4 groups of 8 rows; wave wid loads group wid
            gload16((const short*)A + (size_t)(m0 + wid * 8 + arow) * K + k0 + aseg * 8,
                    &As[buf][wid * 512]);
        } else {
            int srow = tid >> 3, sseg = tid & 7;   // 32 rows x 8 segs
            int rr = m0 + srow;
            short8 v = {0, 0, 0, 0, 0, 0, 0, 0};
            if (rr < M) {
                const float* ap = (const float*)A + (size_t)rr * K + k0 + sseg * 8;
                f32x4 x0 = *(const f32x4*)ap;
                f32x4 x1 = *(const f32x4*)(ap + 4);
                v[0] = f2bs(x0[0]); v[1] = f2bs(x0[1]); v[2] = f2bs(x0[2]); v[3] = f2bs(x0[3]);
                v[4] = f2bs(x1[0]); v[5] = f2bs(x1[1]); v[6] = f2bs(x1[2]); v[7] = f2bs(x1[3]);
            }
            *(short8*)&As[buf][(srow * 8 + (sseg ^ (srow & 7))) * 8] = v;
        }
        // B: 8 groups; wave wid loads groups wid*2, wid*2+1
#pragma unroll
        for (int it = 0; it < 2; ++it) {
            int g = wid * 2 + it;
            gload16(Bt + (size_t)(n0 + g * 8 + arow) * K + k0 + aseg * 8,
                    &Bs[buf][g * 512]);
        }
    };

    issue(0, 0);
    int cur = 0;
    for (int k0 = 0; k0 < K; k0 += 64) {
        __syncthreads();
        if (k0 + 64 < K) issue(cur ^ 1, k0 + 64);
#pragma unroll
        for (int ks = 0; ks < 2; ++ks) {
            int p = c16 & 7;
            int rowA = wm + c16;
            short8 af = *(const short8*)&As[cur][(rowA * 8 + ((ks * 4 + q) ^ p)) * 8];
#pragma unroll
            for (int nt = 0; nt < 2; ++nt) {
                int row = wn + nt * 16 + c16;
                short8 bfr = *(const short8*)&Bs[cur][(row * 8 + ((ks * 4 + q) ^ p)) * 8];
                acc[nt] = __builtin_amdgcn_mfma_f32_16x16x32_bf16(af, bfr, acc[nt], 0, 0, 0);
            }
        }
        cur ^= 1;
    }
#pragma unroll
    for (int reg = 0; reg < 4; ++reg) {
        int r = m0 + wm + q * 4 + reg;
        if (r >= M) continue;
#pragma unroll
        for (int nt = 0; nt < 2; ++nt) {
            int c = n0 + wn + nt * 16 + c16;
            float h = acc[nt][reg];
            if (bias) h += bias[c];
            if (act == ACT_SILU) h = h / (1.f + __expf(-h));
            h *= scale;
            size_t idx = (size_t)r * N + c;
            if (residual) h += residual[idx];
            if (outf) outf[idx] = h;
            if (outb) outb[idx] = f2b(h);
        }
    }
}

// ---------------------------------------------------------------- fused QKV GEMM (dbuf async)
__global__ __launch_bounds__(256, 4) void gemm_qkv(
    const bf16* __restrict__ A, const short* __restrict__ Bt,
    const float* __restrict__ bq, const float* __restrict__ bk,
    const float* __restrict__ bv,
    bf16* __restrict__ Qb, bf16* __restrict__ Kb, bf16* __restrict__ Vb) {
    const int K = kD;
    __shared__ short As[2][4096];
    __shared__ short Bs[2][4096];
    int tid = threadIdx.x;
    int m0 = blockIdx.y * 64, n0 = blockIdx.x * 64;
    int seg = blockIdx.x >> 3;
    const float* bias = seg == 0 ? bq : (seg == 1 ? bk : bv);
    bf16* outb = seg == 0 ? Qb : (seg == 1 ? Kb : Vb);
    int ns0 = n0 & 511;
    int wid = tid >> 6, lane = tid & 63;
    int wm = (wid >> 1) * 32, wn = (wid & 1) * 32;
    int q = lane >> 4, c16 = lane & 15;

    f32x4 zero4 = {0.f, 0.f, 0.f, 0.f};
    f32x4 acc[2][2] = {{zero4, zero4}, {zero4, zero4}};
    int arow = lane >> 3;
    int aseg = (lane & 7) ^ arow;

    auto issue = [&](int buf, int k0) {
#pragma unroll
        for (int it = 0; it < 2; ++it) {
            int rbase = (wid * 2 + it) * 8;
            gload16((const short*)A + (size_t)(m0 + rbase + arow) * K + k0 + aseg * 8,
                    &As[buf][(wid * 2 + it) * 512]);
            gload16(Bt + (size_t)(n0 + rbase + arow) * K + k0 + aseg * 8,
                    &Bs[buf][(wid * 2 + it) * 512]);
        }
    };

    issue(0, 0);
    int cur = 0;
    for (int k0 = 0; k0 < K; k0 += 64) {
        __syncthreads();
        if (k0 + 64 < K) issue(cur ^ 1, k0 + 64);
#pragma unroll
        for (int ks = 0; ks < 2; ++ks) {
            int p = c16 & 7;
            short8 af[2], bfr[2];
#pragma unroll
            for (int mt = 0; mt < 2; ++mt) {
                int row = wm + mt * 16 + c16;
                af[mt] = *(const short8*)&As[cur][(row * 8 + ((ks * 4 + q) ^ p)) * 8];
            }
#pragma unroll
            for (int nt = 0; nt < 2; ++nt) {
                int row = wn + nt * 16 + c16;
                bfr[nt] = *(const short8*)&Bs[cur][(row * 8 + ((ks * 4 + q) ^ p)) * 8];
            }
#pragma unroll
            for (int mt = 0; mt < 2; ++mt)
#pragma unroll
                for (int nt = 0; nt < 2; ++nt)
                    acc[mt][nt] = __builtin_amdgcn_mfma_f32_16x16x32_bf16(
                        af[mt], bfr[nt], acc[mt][nt], 0, 0, 0);
        }
        cur ^= 1;
    }
#pragma unroll
    for (int mt = 0; mt < 2; ++mt)
#pragma unroll
        for (int reg = 0; reg < 4; ++reg) {
            int r = m0 + wm + mt * 16 + q * 4 + reg;
#pragma unroll
            for (int nt = 0; nt < 2; ++nt) {
                int c = ns0 + wn + nt * 16 + c16;
                outb[(size_t)r * 512 + c] = f2b(acc[mt][nt][reg] + bias[c]);
            }
        }
}

// ---------------------------------------------------------------- scalar GEMM (slow fallback)
__global__ __launch_bounds__(256) void gemm_scalar(
    const void* __restrict__ A, const float* __restrict__ W,
    const float* __restrict__ bias, const float* __restrict__ residual,
    float* __restrict__ outf, bf16* __restrict__ outb,
    int M, int N, int K, int act, float scale, int a_f32) {
    __shared__ float As[16][65];
    __shared__ float Bs[16][65];
    int tid = threadIdx.x;
    int tx = tid & 15, ty = tid >> 4;
    int row0 = blockIdx.y * 64, col0 = blockIdx.x * 64;
    float acc[4][4] = {};
    for (int k0 = 0; k0 < K; k0 += 16) {
        for (int i = tid; i < 64 * 16; i += 256) {
            int r = i >> 4, c = i & 15;
            int rr = row0 + r;
            float v = 0.f;
            if (rr < M) {
                size_t idx = (size_t)rr * K + k0 + c;
                v = a_f32 ? ((const float*)A)[idx] : b2f(((const bf16*)A)[idx]);
            }
            As[c][r] = v;
        }
        for (int i = tid; i < 16 * 64; i += 256) {
            int r = i >> 6, c = i & 63;
            Bs[r][c] = W[(size_t)(k0 + r) * N + col0 + c];
        }
        __syncthreads();
#pragma unroll
        for (int kk = 0; kk < 16; ++kk) {
            float a[4], b[4];
#pragma unroll
            for (int i = 0; i < 4; ++i) a[i] = As[kk][ty * 4 + i];
#pragma unroll
            for (int j = 0; j < 4; ++j) b[j] = Bs[kk][tx * 4 + j];
#pragma unroll
            for (int i = 0; i < 4; ++i)
#pragma unroll
                for (int j = 0; j < 4; ++j) acc[i][j] += a[i] * b[j];
        }
        __syncthreads();
    }
#pragma unroll
    for (int i = 0; i < 4; ++i) {
        int r = row0 + ty * 4 + i;
        if (r >= M) continue;
#pragma unroll
        for (int j = 0; j < 4; ++j) {
            int c = col0 + tx * 4 + j;
            float h = acc[i][j];
            if (bias) h += bias[c];
            if (act == ACT_SILU) h = h / (1.f + __expf(-h));
            h *= scale;
            size_t idx = (size_t)r * N + c;
            if (residual) h += residual[idx];
            if (outf) outf[idx] = h;
            if (outb) outb[idx] = f2b(h);
        }
    }
}

// ---------------------------------------------------------------- MFMA RPE attention (single-buffer, best measured)
__global__ __launch_bounds__(256, 3) void attn_mfma(
    const bf16* __restrict__ Qg, const bf16* __restrict__ Kg,
    const bf16* __restrict__ Vtg, const bf16* __restrict__ Rg,
    const float* __restrict__ uu, const float* __restrict__ vvp,
    bf16* __restrict__ outb) {
    __shared__ short KsL[4096];    // 64x64 swizzled
    __shared__ short VtL[4096];    // 64x64 swizzled
    __shared__ short RwL[8192];    // 128x64 swizzled
    __shared__ short Bp[64][88];   // Braw (cols 0..79 = j-wm), then P (cols 0..63)

    int tid = threadIdx.x;
    int qb = blockIdx.x, h = blockIdx.y, n = blockIdx.z;
    int t0 = qb * 64;
    size_t baseq = ((size_t)n * kT) * 512 + (size_t)h * kDH;
    size_t basev = ((size_t)(n * 8 + h) * 64) * 1024;
    size_t baseo = ((size_t)n * kT) * kD + (size_t)h * kDH;

    int wid = tid >> 6, lane = tid & 63;
    int q = lane >> 4, c16 = lane & 15;
    int wm = wid * 16;
    int trow = wm + q * 4;

    // ---- Q fragments with u,v folded, in registers (constant across kt)
    short8 qu[2], qvv[2];
    {
        const short* qp = (const short*)Qg + baseq + (size_t)(t0 + wm + c16) * 512;
#pragma unroll
        for (int ks = 0; ks < 2; ++ks) {
            short8 q8 = *(const short8*)(qp + ks * 32 + q * 8);
            const float* up = uu + h * 64 + ks * 32 + q * 8;
            const float* vp = vvp + h * 64 + ks * 32 + q * 8;
#pragma unroll
            for (int i = 0; i < 8; ++i) {
                float xq = bs2f(q8[i]);
                qu[ks][i]  = f2bs(xq + up[i]);
                qvv[ks][i] = f2bs(xq + vp[i]);
            }
        }
    }

    int arow = lane >> 3;
    int aseg = (lane & 7) ^ arow;

    f32x4 zero4 = {0.f, 0.f, 0.f, 0.f};
    f32x4 acc_o[4] = {zero4, zero4, zero4, zero4};
    float m_i[4] = {-1e30f, -1e30f, -1e30f, -1e30f};
    float l_i[4] = {0.f, 0.f, 0.f, 0.f};

    for (int kt = 0; kt < 16; ++kt) {
        int s0 = kt * 64;
        __syncthreads();   // prev iter's LDS reads done
#pragma unroll
        for (int it = 0; it < 2; ++it) {
            int g = wid * 2 + it;
            gload16((const short*)Kg + baseq + (size_t)(s0 + g * 8 + arow) * 512 + aseg * 8,
                    KsL + g * 512);
            gload16((const short*)Vtg + basev + (size_t)(g * 8 + arow) * 1024 + s0 + aseg * 8,
                    VtL + g * 512);
        }
        int p_base = t0 - s0 + 960;
#pragma unroll
        for (int it = 0; it < 4; ++it) {
            int g = wid * 4 + it;
            int j = g * 8 + arow;
            int p = p_base + j;
            p = p < 0 ? 0 : (p > 2046 ? 2046 : p);
            gload16((const short*)Rg + (size_t)p * kD + h * kDH + aseg * 8,
                    RwL + g * 512);
        }
        __syncthreads();   // drain

        f32x4 acc_s[4] = {zero4, zero4, zero4, zero4};
        f32x4 acc_b[5] = {zero4, zero4, zero4, zero4, zero4};
#pragma unroll
        for (int ks = 0; ks < 2; ++ks) {
            int pq = c16 & 7;
#pragma unroll
            for (int nt = 0; nt < 4; ++nt) {
                int row = nt * 16 + c16;
                short8 bk_ = *(const short8*)&KsL[(row * 8 + ((ks * 4 + q) ^ pq)) * 8];
                acc_s[nt] = __builtin_amdgcn_mfma_f32_16x16x32_bf16(qu[ks], bk_, acc_s[nt], 0, 0, 0);
            }
#pragma unroll
            for (int jt = 0; jt < 5; ++jt) {
                int row = wm + jt * 16 + c16;
                short8 br_ = *(const short8*)&RwL[(row * 8 + ((ks * 4 + q) ^ pq)) * 8];
                acc_b[jt] = __builtin_amdgcn_mfma_f32_16x16x32_bf16(qvv[ks], br_, acc_b[jt], 0, 0, 0);
            }
        }
#pragma unroll
        for (int jt = 0; jt < 5; ++jt)
#pragma unroll
            for (int reg = 0; reg < 4; ++reg)
                Bp[trow + reg][jt * 16 + c16] = f2bs(acc_b[jt][reg]);

        float pmat[4][4];
        float alpha[4];
#pragma unroll
        for (int reg = 0; reg < 4; ++reg) {
            int t = trow + reg;
            float mrow = -1e30f;
#pragma unroll
            for (int nt = 0; nt < 4; ++nt) {
                int s = nt * 16 + c16;
                int jc = t - s + 63 - wm;   // [0,78]
                float sv = (acc_s[nt][reg] + bs2f(Bp[t][jc])) * 0.125f;
                pmat[nt][reg] = sv;
                mrow = fmaxf(mrow, sv);
            }
            mrow = fmaxf(mrow, __shfl_xor(mrow, 1));
            mrow = fmaxf(mrow, __shfl_xor(mrow, 2));
            mrow = fmaxf(mrow, __shfl_xor(mrow, 4));
            mrow = fmaxf(mrow, __shfl_xor(mrow, 8));
            float m_new = fmaxf(m_i[reg], mrow);
            alpha[reg] = __expf(m_i[reg] - m_new);
            float ps = 0.f;
#pragma unroll
            for (int nt = 0; nt < 4; ++nt) {
                float pe = __expf(pmat[nt][reg] - m_new);
                pmat[nt][reg] = pe;
                ps += pe;
            }
            ps += __shfl_xor(ps, 1);
            ps += __shfl_xor(ps, 2);
            ps += __shfl_xor(ps, 4);
            ps += __shfl_xor(ps, 8);
            l_i[reg] = l_i[reg] * alpha[reg] + ps;
            m_i[reg] = m_new;
        }
#pragma unroll
        for (int nt = 0; nt < 4; ++nt)
#pragma unroll
            for (int reg = 0; reg < 4; ++reg)
                Bp[trow + reg][nt * 16 + c16] = f2bs(pmat[nt][reg]);
#pragma unroll
        for (int dt = 0; dt < 4; ++dt)
#pragma unroll
            for (int reg = 0; reg < 4; ++reg)
                acc_o[dt][reg] *= alpha[reg];
#pragma unroll
        for (int ks = 0; ks < 2; ++ks) {
            int pq = c16 & 7;
            short8 ap = *(const short8*)&Bp[wm + c16][ks * 32 + q * 8];
#pragma unroll
            for (int dt = 0; dt < 4; ++dt) {
                int row = dt * 16 + c16;
                short8 bv_ = *(const short8*)&VtL[(row * 8 + ((ks * 4 + q) ^ pq)) * 8];
                acc_o[dt] = __builtin_amdgcn_mfma_f32_16x16x32_bf16(ap, bv_, acc_o[dt], 0, 0, 0);
            }
        }
    }
#pragma unroll
    for (int reg = 0; reg < 4; ++reg) {
        float inv = 1.f / l_i[reg];
        int t = trow + reg;
#pragma unroll
        for (int dt = 0; dt < 4; ++dt)
            outb[baseo + (size_t)(t0 + t) * kD + dt * 16 + c16] = f2b(acc_o[dt][reg] * inv);
    }
}

// ---------------------------------------------------------------- scalar attention (slow path)
__global__ __launch_bounds__(256) void attn_kernel(
    const bf16* __restrict__ Qg, const bf16* __restrict__ Kg,
    const bf16* __restrict__ Vg, const bf16* __restrict__ Rg,
    const float* __restrict__ uu, const float* __restrict__ vvp,
    bf16* __restrict__ outb) {
    __shared__ float Qs[64][65];
    __shared__ bf16 Ps[64][66];
    __shared__ bf16 Ks[64][66];
    __shared__ bf16 Vs[64][66];
    __shared__ bf16 Rs[127][66];
    __shared__ float uf[64], vf[64];
    __shared__ float uK[64], vR[127];

    int tid = threadIdx.x;
    int qb = blockIdx.x, h = blockIdx.y, n = blockIdx.z;
    int t0 = qb * 64;
    size_t base = ((size_t)n * kT) * kD + (size_t)h * kDH;

    if (tid < 64) {
        uf[tid] = uu[h * 64 + tid];
        vf[tid] = vvp[h * 64 + tid];
    }
    for (int i = tid; i < 64 * 64; i += 256) {
        int r = i >> 6, d = i & 63;
        Qs[r][d] = b2f(Qg[base + (size_t)(t0 + r) * kD + d]);
    }
    int r = tid >> 2, seg = tid & 3;
    float m_i = -1e30f, l_i = 0.f;
    float Oa[16];
#pragma unroll
    for (int i = 0; i < 16; ++i) Oa[i] = 0.f;

    for (int kt = 0; kt < 16; ++kt) {
        int s0 = kt * 64;
        __syncthreads();
        for (int i = tid; i < 64 * 64; i += 256) {
            int s = i >> 6, d = i & 63;
            Ks[s][d] = Kg[base + (size_t)(s0 + s) * kD + d];
            Vs[s][d] = Vg[base + (size_t)(s0 + s) * kD + d];
        }
        int p_base = t0 - s0 + 960;
        for (int i = tid; i < 127 * 64; i += 256) {
            int j = i >> 6, d = i & 63;
            int p = p_base + j;
            p = p < 0 ? 0 : (p > 2046 ? 2046 : p);
            Rs[j][d] = Rg[(size_t)p * kD + h * kDH + d];
        }
        __syncthreads();
        if (tid < 64) {
            float s_ = 0.f;
            for (int d = 0; d < 64; ++d) s_ += uf[d] * b2f(Ks[tid][d]);
            uK[tid] = s_;
        } else if (tid < 64 + 127) {
            int j = tid - 64;
            float s_ = 0.f;
            for (int d = 0; d < 64; ++d) s_ += vf[d] * b2f(Rs[j][d]);
            vR[j] = s_;
        }
        __syncthreads();
        float sv[16];
        float smax = -1e30f;
#pragma unroll
        for (int jj = 0; jj < 16; ++jj) {
            int s = seg * 16 + jj;
            int j = r - s + 63;
            float acc = 0.f;
            for (int d = 0; d < 64; ++d)
                acc += Qs[r][d] * (b2f(Ks[s][d]) + b2f(Rs[j][d]));
            acc = (acc + uK[s] + vR[j]) * 0.125f;
            sv[jj] = acc;
            smax = fmaxf(smax, acc);
        }
        smax = fmaxf(smax, __shfl_xor(smax, 1));
        smax = fmaxf(smax, __shfl_xor(smax, 2));
        float m_new = fmaxf(m_i, smax);
        float alpha = __expf(m_i - m_new);
        float psum = 0.f;
#pragma unroll
        for (int jj = 0; jj < 16; ++jj) {
            float p = __expf(sv[jj] - m_new);
            Ps[r][seg * 16 + jj] = f2b(p);
            psum += p;
        }
        psum += __shfl_xor(psum, 1);
        psum += __shfl_xor(psum, 2);
        l_i = l_i * alpha + psum;
        m_i = m_new;
#pragma unroll
        for (int i = 0; i < 16; ++i) Oa[i] *= alpha;
        __syncthreads();
        for (int s = 0; s < 64; ++s) {
            float p = b2f(Ps[r][s]);
#pragma unroll
            for (int dd = 0; dd < 16; ++dd)
                Oa[dd] += p * b2f(Vs[s][seg * 16 + dd]);
        }
    }
    float inv = 1.f / l_i;
#pragma unroll
    for (int dd = 0; dd < 16; ++dd)
        outb[base + (size_t)(t0 + r) * kD + seg * 16 + dd] = f2b(Oa[dd] * inv);
}

// ---------------------------------------------------------------- GLU (slow path)
__global__ __launch_bounds__(256) void glu_kernel_v(const bf16* __restrict__ c,
                                                    bf16* __restrict__ out) {
    int i8 = (blockIdx.x * 256 + threadIdx.x) * 8;
    int row = i8 >> 9, d = i8 & 511;
    const short* cp = (const short*)c + (size_t)row * 1024;
    short8 a8 = *(const short8*)(cp + d);
    short8 g8 = *(const short8*)(cp + 512 + d);
    short8 o;
#pragma unroll
    for (int i = 0; i < 8; ++i) {
        float a = bs2f(a8[i]), g = bs2f(g8[i]);
        o[i] = f2bs(a / (1.f + __expf(-g)));
    }
    *(short8*)((short*)out + i8) = o;
}

// ---------------------------------------------------------------- fused GLU + depthwise conv + BN + SiLU
__global__ __launch_bounds__(256) void gluconv_kernel(
    const bf16* __restrict__ cbuf, const float* __restrict__ wt,
    const float* __restrict__ beff, bf16* __restrict__ outb) {
    __shared__ short gsm[94][72];
    __shared__ float wsm[31][64];
    __shared__ float bsm[64];
    int tid = threadIdx.x;
    int dg0 = blockIdx.x * 64;
    int t0  = blockIdx.y * 64;
    int n   = blockIdx.z;

#pragma unroll
    for (int it = 0; it < 3; ++it) {
        int idx = tid + it * 256;
        if (idx < 94 * 8) {
            int row = idx >> 3, cg = (idx & 7) * 8;
            int t = t0 - 15 + row;
            short8 o = {0, 0, 0, 0, 0, 0, 0, 0};
            if ((unsigned)t < (unsigned)kT) {
                const short* cp = (const short*)cbuf + ((size_t)n * kT + t) * 1024 + dg0 + cg;
                short8 a8 = *(const short8*)cp;
                short8 g8 = *(const short8*)(cp + 512);
#pragma unroll
                for (int i = 0; i < 8; ++i)
                    o[i] = f2bs(bs2f(a8[i]) / (1.f + __expf(-bs2f(g8[i]))));
            }
            *(short8*)&gsm[row][cg] = o;
        }
    }
#pragma unroll
    for (int it = 0; it < 8; ++it) {
        int i = tid + it * 256;
        if (i < 31 * 64) wsm[i >> 6][i & 63] = wt[(i >> 6) * kD + dg0 + (i & 63)];
    }
    if (tid < 64) bsm[tid] = beff[dg0 + tid];
    __syncthreads();

    int tl = tid >> 2, dgl = (tid & 3) * 16;
    float acc[16] = {};
#pragma unroll
    for (int k = 0; k < 31; ++k) {
        short8 g0 = *(const short8*)&gsm[tl + k][dgl];
        short8 g1 = *(const short8*)&gsm[tl + k][dgl + 8];
#pragma unroll
        for (int i = 0; i < 8; ++i) {
            acc[i]     += bs2f(g0[i]) * wsm[k][dgl + i];
            acc[8 + i] += bs2f(g1[i]) * wsm[k][dgl + 8 + i];
        }
    }
    short8 o0, o1;
#pragma unroll
    for (int i = 0; i < 8; ++i) {
        float h = acc[i] + bsm[dgl + i];
        o0[i] = f2bs(h / (1.f + __expf(-h)));
        h = acc[8 + i] + bsm[dgl + 8 + i];
        o1[i] = f2bs(h / (1.f + __expf(-h)));
    }
    short* op = (short*)outb + ((size_t)n * kT + t0 + tl) * kD + dg0 + dgl;
    *(short8*)op = o0;
    *(short8*)(op + 8) = o1;
}

// ---------------------------------------------------------------- scalar conv (slow path)
__global__ __launch_bounds__(256) void conv_kernel(
    const bf16* __restrict__ glu, const float* __restrict__ dw_w,
    const float* __restrict__ dw_b, const float* __restrict__ bn_g,
    const float* __restrict__ bn_b, bf16* __restrict__ outb) {
    int idx = blockIdx.x * 256 + threadIdx.x;
    int d = idx & 511;
    int t = (idx >> 9) & 1023;
    int n = idx >> 19;
    const bf16* gp = glu + ((size_t)n * kT) * kD + d;
    float acc = 0.f;
#pragma unroll
    for (int k = 0; k < 31; ++k) {
        int tt = t + k - 15;
        if ((unsigned)tt < (unsigned)kT)
            acc += b2f(gp[(size_t)tt * kD]) * dw_w[d * 31 + k];
    }
    acc += dw_b[d];
    acc = acc * bn_g[d] + bn_b[d];
    acc = acc / (1.f + __expf(-acc));
    outb[idx] = f2b(acc);
}

// ================================================================ launch
extern "C" void kernel_launch(void* const* d_in, const int* in_sizes, int n_in,
                              void* d_out, int out_size, void* d_ws, size_t ws_size,
                              hipStream_t stream) {
    const float* x      = (const float*)d_in[0];
    const float* rel_pe = (const float*)d_in[1];
    const float* ln1_g  = (const float*)d_in[2];
    const float* ln1_b  = (const float*)d_in[3];
    const float* ff1_w1 = (const float*)d_in[4];
    const float* ff1_b1 = (const float*)d_in[5];
    const float* ff1_w2 = (const float*)d_in[6];
    const float* ff1_b2 = (const float*)d_in[7];
    const float* an_g   = (const float*)d_in[8];
    const float* an_b   = (const float*)d_in[9];
    const float* wq = (const float*)d_in[10]; const float* bq = (const float*)d_in[11];
    const float* wk = (const float*)d_in[12]; const float* bk = (const float*)d_in[13];
    const float* wv = (const float*)d_in[14]; const float* bv = (const float*)d_in[15];
    const float* wo = (const float*)d_in[16]; const float* bo = (const float*)d_in[17];
    const float* pos_w = (const float*)d_in[18];
    const float* uu = (const float*)d_in[19]; const float* vvp = (const float*)d_in[20];
    const float* cn_g = (const float*)d_in[21]; const float* cn_b = (const float*)d_in[22];
    const float* pe_w = (const float*)d_in[23]; const float* pe_b = (const float*)d_in[24];
    const float* dw_w = (const float*)d_in[25]; const float* dw_b = (const float*)d_in[26];
    const float* bn_g = (const float*)d_in[27]; const float* bn_b = (const float*)d_in[28];
    const float* pc_w = (const float*)d_in[29]; const float* pc_b = (const float*)d_in[30];
    const float* ln2_g = (const float*)d_in[31]; const float* ln2_b = (const float*)d_in[32];
    const float* ff2_w1 = (const float*)d_in[33]; const float* ff2_b1 = (const float*)d_in[34];
    const float* ff2_w2 = (const float*)d_in[35]; const float* ff2_b2 = (const float*)d_in[36];
    const float* fn_g = (const float*)d_in[37]; const float* fn_b = (const float*)d_in[38];
    (void)n_in; (void)in_sizes;

    const int total = kROWS * kD;
    dim3 blk(256);
    const size_t MB = 1ull << 20;
    char* w = (char*)d_ws;

    if (ws_size >= 30 * MB) {
        // ================= FAST PATH (MFMA) =================
        float* xf      = (float*)(w);
        short* ff1_w1t = (short*)(w + 8 * MB);
        short* ff1_w2t = (short*)(w + 10 * MB);
        short* wqt     = (short*)(w + 12 * MB);
        short* wkt     = (short*)(w + 12 * MB + 512 * 1024);
        short* wvt     = (short*)(w + 13 * MB);
        short* wot     = (short*)(w + 13 * MB + 512 * 1024);
        short* poswt   = (short*)(w + 14 * MB);
        short* pewt    = (short*)(w + 14 * MB + 512 * 1024);
        short* pcwt    = (short*)(w + 15 * MB + 512 * 1024);
        short* ff2_w1t = (short*)(w + 16 * MB);
        short* ff2_w2t = (short*)(w + 18 * MB);
        char*  dyn     = w + 20 * MB;
        bf16* hchunk = (bf16*)dyn;
        bf16* Qb     = (bf16*)dyn;
        bf16* Kb     = (bf16*)(dyn + 4 * MB);
        bf16* Rb     = (bf16*)(dyn + 8 * MB);   // attention phase only
        bf16* cbuf   = (bf16*)dyn;
        float* dwt   = (float*)(dyn + 8 * MB);  // conv phase ONLY (aliases Rb!)
        float* beff  = (float*)(dyn + 8 * MB + 256 * 1024);
        bf16* nb     = (bf16*)d_out;
        bf16* Vtg    = (bf16*)d_out;                               // lo 4 MB (after qkv)
        bf16* convb  = (bf16*)d_out;
        bf16* Vb     = (bf16*)d_out + (size_t)kROWS * kD;          // hi 4 MB
        bf16* attnb  = Vb;                                         // hi 4 MB (after vtrans)

        // ---- all weight transposes in ONE launch
        WtArgs wa;
        const float* srcs[11] = {ff1_w1, ff1_w2, wq, wk, wv, wo, pos_w, pe_w, pc_w, ff2_w1, ff2_w2};
        short* dsts[11] = {ff1_w1t, ff1_w2t, wqt, wkt, wvt, wot, poswt, pewt, pcwt, ff2_w1t, ff2_w2t};
        int Ks_[11] = {512, 2048, 512, 512, 512, 512, 512, 512, 512, 512, 2048};
        int Ns_[11] = {2048, 512, 512, 512, 512, 512, 512, 1024, 512, 2048, 512};
        int cum = 0;
        for (int i = 0; i < 11; ++i) {
            wa.d[i].src = srcs[i]; wa.d[i].dst = dsts[i];
            wa.d[i].K = Ks_[i]; wa.d[i].N = Ns_[i]; wa.d[i].tstart = cum;
            cum += (Ns_[i] / 32) * (Ks_[i] / 32);
        }
        wt_all_kernel<<<cum, blk, 0, stream>>>(wa);

        // ---- macaron FF1 (down-proj: 32-row tiles, 2 blocks/CU)
        ln_kernel_v<<<kROWS / 2, blk, 0, stream>>>(x, ln1_g, ln1_b, nb, 0);
        for (int c = 0; c < 2; ++c) {
            size_t off = (size_t)c * 2048 * kD;
            gemm_mfma64<<<dim3(kFFN / 64, 2048 / 64), blk, 0, stream>>>(
                nb + off, ff1_w1t, ff1_b1, nullptr, nullptr, hchunk,
                2048, kFFN, kD, ACT_SILU, 1.f, 0);
            gemm_mfma32<<<dim3(kD / 64, 2048 / 32), blk, 0, stream>>>(
                hchunk, ff1_w2t, ff1_b2, x + off, xf + off, nullptr,
                2048, kD, kFFN, ACT_NONE, 0.5f, 0);
        }

        // ---- RPE attention (R GEMM: 32-row tiles + fp32 A, 2 blocks/CU)
        ln_kernel_v<<<kROWS / 2, blk, 0, stream>>>(xf, an_g, an_b, nb, 0);
        gemm_qkv<<<dim3(24, kROWS / 64), blk, 0, stream>>>(
            nb, wqt, bq, bk, bv, Qb, Kb, Vb);
        vtrans_kernel<<<dim3(16, 8, 4), blk, 0, stream>>>(Vb, Vtg);
        gemm_mfma32<<<dim3(kD / 64, (kP + 31) / 32), blk, 0, stream>>>(
            rel_pe, poswt, nullptr, nullptr, nullptr, Rb, kP, kD, kD, ACT_NONE, 1.f, 1);
        attn_mfma<<<dim3(kT / 64, kH, kN), blk, 0, stream>>>(Qb, Kb, Vtg, Rb, uu, vvp, attnb);
        gemm_mfma32<<<dim3(kD / 64, kROWS / 32), blk, 0, stream>>>(
            attnb, wot, bo, xf, xf, nullptr, kROWS, kD, kD, ACT_NONE, 1.f, 0);

        // ---- conv module (dwt MUST run after attention: dwt/beff alias Rb)
        dwt_kernel<<<62, blk, 0, stream>>>(dw_w, dw_b, bn_g, bn_b, dwt, beff);
        ln_kernel_v<<<kROWS / 2, blk, 0, stream>>>(xf, cn_g, cn_b, nb, 0);
        gemm_mfma64<<<dim3(2 * kD / 64, kROWS / 64), blk, 0, stream>>>(
            nb, pewt, pe_b, nullptr, nullptr, cbuf, kROWS, 2 * kD, kD, ACT_NONE, 1.f, 0);
        gluconv_kernel<<<dim3(8, 16, 4), blk, 0, stream>>>(cbuf, dwt, beff, convb);
        gemm_mfma32<<<dim3(kD / 64, kROWS / 32), blk, 0, stream>>>(
            convb, pcwt, pc_b, xf, xf, nullptr, kROWS, kD, kD, ACT_NONE, 1.f, 0);

        // ---- macaron FF2
        ln_kernel_v<<<kROWS / 2, blk, 0, stream>>>(xf, ln2_g, ln2_b, nb, 0);
        for (int c = 0; c < 2; ++c) {
            size_t off = (size_t)c * 2048 * kD;
            gemm_mfma64<<<dim3(kFFN / 64, 2048 / 64), blk, 0, stream>>>(
                nb + off, ff2_w1t, ff2_b1, nullptr, nullptr, hchunk,
                2048, kFFN, kD, ACT_SILU, 1.f, 0);
            gemm_mfma32<<<dim3(kD / 64, 2048 / 32), blk, 0, stream>>>(
                hchunk, ff2_w2t, ff2_b2, xf + off, xf + off, nullptr,
                2048, kD, kFFN, ACT_NONE, 0.5f, 0);
        }

        ln_kernel_v<<<kROWS / 2, blk, 0, stream>>>(xf, fn_g, fn_b, d_out, 1);
        return;
    }

    if (ws_size < 22 * MB) {
        stamp_kernel<<<(out_size + 255) / 256, blk, 0, stream>>>(
            (float*)d_out, out_size, 1000.f + (float)(ws_size / MB));
        return;
    }

    // ================= SLOW PATH (scalar, known-good) =================
    float* xf    = (float*)(w);
    bf16*  hbch  = (bf16*)(w + 8 * MB);
    bf16*  Qb    = (bf16*)(w + 8 * MB);
    bf16*  cbuf  = (bf16*)(w + 8 * MB);
    bf16*  convb = (bf16*)(w + 8 * MB);
    bf16*  Kb    = (bf16*)(w + 12 * MB);
    bf16*  Vb    = (bf16*)(w + 16 * MB);
    bf16*  glub  = (bf16*)(w + 16 * MB);
    bf16*  Rb    = (bf16*)(w + 20 * MB);
    bf16*  nb    = (bf16*)d_out;
    bf16*  attnb = (bf16*)d_out;

    cvt_kernel<<<total / 1024, blk, 0, stream>>>(x, xf, total / 4);

    ln_kernel<<<kROWS, blk, 0, stream>>>(xf, ln1_g, ln1_b, nb, 0);
    for (int c = 0; c < 4; ++c) {
        size_t off = (size_t)c * 1024 * kD;
        gemm_scalar<<<dim3(kFFN / 64, 1024 / 64), blk, 0, stream>>>(
            nb + off, ff1_w1, ff1_b1, nullptr, nullptr, hbch, 1024, kFFN, kD, ACT_SILU, 1.f, 0);
        gemm_scalar<<<dim3(kD / 64, 1024 / 64), blk, 0, stream>>>(
            hbch, ff1_w2, ff1_b2, xf + off, xf + off, nullptr, 1024, kD, kFFN, ACT_NONE, 0.5f, 0);
    }

    ln_kernel<<<kROWS, blk, 0, stream>>>(xf, an_g, an_b, nb, 0);
    gemm_scalar<<<dim3(kD / 64, kROWS / 64), blk, 0, stream>>>(
        nb, wq, bq, nullptr, nullptr, Qb, kROWS, kD, kD, ACT_NONE, 1.f, 0);
    gemm_scalar<<<dim3(kD / 64, kROWS / 64), blk, 0, stream>>>(
        nb, wk, bk, nullptr, nullptr, Kb, kROWS, kD, kD, ACT_NONE, 1.f, 0);
    gemm_scalar<<<dim3(kD / 64, kROWS / 64), blk, 0, stream>>>(
        nb, wv, bv, nullptr, nullptr, Vb, kROWS, kD, kD, ACT_NONE, 1.f, 0);
    gemm_scalar<<<dim3(kD / 64, (kP + 63) / 64), blk, 0, stream>>>(
        rel_pe, pos_w, nullptr, nullptr, nullptr, Rb, kP, kD, kD, ACT_NONE, 1.f, 1);
    attn_kernel<<<dim3(kT / 64, kH, kN), blk, 0, stream>>>(Qb, Kb, Vb, Rb, uu, vvp, attnb);
    gemm_scalar<<<dim3(kD / 64, kROWS / 64), blk, 0, stream>>>(
        attnb, wo, bo, xf, xf, nullptr, kROWS, kD, kD, ACT_NONE, 1.f, 0);

    ln_kernel<<<kROWS, blk, 0, stream>>>(xf, cn_g, cn_b, nb, 0);
    gemm_scalar<<<dim3(2 * kD / 64, kROWS / 64), blk, 0, stream>>>(
        nb, pe_w, pe_b, nullptr, nullptr, cbuf, kROWS, 2 * kD, kD, ACT_NONE, 1.f, 0);
    glu_kernel_v<<<total / 2048, blk, 0, stream>>>(cbuf, glub);
    conv_kernel<<<total / 256, blk, 0, stream>>>(glub, dw_w, dw_b, bn_g, bn_b, convb);
    gemm_scalar<<<dim3(kD / 64, kROWS / 64), blk, 0, stream>>>(
        convb, pc_w, pc_b, xf, xf, nullptr, kROWS, kD, kD, ACT_NONE, 1.f, 0);

    ln_kernel<<<kROWS, blk, 0, stream>>>(xf, ln2_g, ln2_b, nb, 0);
    for (int c = 0; c < 4; ++c) {
        size_t off = (size_t)c * 1024 * kD;
        gemm_scalar<<<dim3(kFFN / 64, 1024 / 64), blk, 0, stream>>>(
            nb + off, ff2_w1, ff2_b1, nullptr, nullptr, hbch, 1024, kFFN, kD, ACT_SILU, 1.f, 0);
        gemm_scalar<<<dim3(kD / 64, 1024 / 64), blk, 0, stream>>>(
            hbch, ff2_w2, ff2_b2, xf + off, xf + off, nullptr, 1024, kD, kFFN, ACT_NONE, 0.5f, 0);
    }

    ln_kernel<<<kROWS, blk, 0, stream>>>(xf, fn_g, fn_b, d_out, 1);
}